// Round 1
// baseline (1239.620 us; speedup 1.0000x reference)
//
#include <hip/hip_runtime.h>
#include <hip/hip_bf16.h>
#include <math.h>

#define Bc 2
#define Lc 2048
#define Mc 2048
#define Dc 1024
#define Hc 16
#define FFc 4096
#define DHc 64
#define Wc 64

typedef __bf16 bf16;
typedef float f32x4 __attribute__((ext_vector_type(4)));
typedef __bf16 bf16x8 __attribute__((ext_vector_type(8)));
typedef __bf16 bf16x4 __attribute__((ext_vector_type(4)));

// ---------------- fp32 -> bf16 convert (vectorized) ----------------
__global__ __launch_bounds__(256) void k_f2b(const float* __restrict__ in,
                                             bf16* __restrict__ out, long n4) {
  long i = (long)blockIdx.x * 256 + threadIdx.x;
  if (i >= n4) return;
  f32x4 v = *(const f32x4*)(in + i * 4);
  bf16x4 o;
  o[0] = (bf16)v[0]; o[1] = (bf16)v[1]; o[2] = (bf16)v[2]; o[3] = (bf16)v[3];
  *(bf16x4*)(out + i * 4) = o;
}

// ---------------- weight transpose+convert: out[n*K+k] = bf16(in[k*N+n]) ----
__global__ __launch_bounds__(256) void k_transpose_w(const float* __restrict__ in,
                                                     bf16* __restrict__ out,
                                                     int K, int N) {
  __shared__ float tile[64][65];
  int n0 = blockIdx.x * 64, k0 = blockIdx.y * 64;
  int t = threadIdx.x;
  int tr = t >> 4, tc = (t & 15) * 4;
#pragma unroll
  for (int p = 0; p < 4; p++) {
    int r = p * 16 + tr;
    f32x4 v = *(const f32x4*)(in + (long)(k0 + r) * N + n0 + tc);
    tile[r][tc] = v[0]; tile[r][tc + 1] = v[1];
    tile[r][tc + 2] = v[2]; tile[r][tc + 3] = v[3];
  }
  __syncthreads();
#pragma unroll
  for (int p = 0; p < 4; p++) {
    int rn = p * 16 + tr;
    bf16x4 o;
    o[0] = (bf16)tile[tc + 0][rn]; o[1] = (bf16)tile[tc + 1][rn];
    o[2] = (bf16)tile[tc + 2][rn]; o[3] = (bf16)tile[tc + 3][rn];
    *(bf16x4*)(out + (long)(n0 + rn) * K + k0 + tc) = o;
  }
}

// ---------------- V transpose: vt[(b*H+h)*DH+d][j] = vb[b][j][h*DH+d] -------
__global__ __launch_bounds__(256) void k_transpose_v(const bf16* __restrict__ vb,
                                                     bf16* __restrict__ vt) {
  __shared__ bf16 tile[64][72];
  int j0 = blockIdx.x * 64;
  int bh = blockIdx.y; int b = bh >> 4; int h = bh & 15;
  int t = threadIdx.x;
#pragma unroll
  for (int c = 0; c < 2; c++) {
    int id = t + c * 256;
    int r = id >> 3, c8 = (id & 7) * 8;
    *(bf16x8*)&tile[r][c8] =
        *(const bf16x8*)(vb + ((long)(b * Mc + j0 + r)) * Dc + h * DHc + c8);
  }
  __syncthreads();
#pragma unroll
  for (int c = 0; c < 2; c++) {
    int id = t + c * 256;
    int d = id >> 3, j8 = (id & 7) * 8;
    bf16x8 o;
#pragma unroll
    for (int e = 0; e < 8; e++) o[e] = tile[j8 + e][d];
    *(bf16x8*)(vt + ((long)bh * DHc + d) * Mc + j0 + j8) = o;
  }
}

// ---------------- generic bf16 MFMA GEMM: C = act(scale*A.Bt^T + bias + add)
// A: [M,K] row-major (lda), Bt: [N,K] row-major (ldb).
// batch z: base = x0 + (z%zin)*xi + (z/zin)*xo for A/B/C.
__global__ __launch_bounds__(256) void k_gemm(
    const bf16* __restrict__ A, long lda, long a0, long ai, long ao,
    const bf16* __restrict__ Bt, long ldb, long b0, long bi, long bo,
    float* __restrict__ outF, bf16* __restrict__ outB, long ldc, long c0,
    long ci, long co, const float* __restrict__ bias,
    const float* __restrict__ addsrc, int Kdim, int zin, float scale, int act) {
  __shared__ bf16 As[64][72];
  __shared__ bf16 Bs[64][72];
  int z = blockIdx.z; int zi = z % zin; int zo = z / zin;
  long abase = a0 + zi * ai + zo * ao;
  long bbase = b0 + zi * bi + zo * bo;
  long cbase = c0 + zi * ci + zo * co;
  int bm = blockIdx.y * 64, bn = blockIdx.x * 64;
  int t = threadIdx.x;
  int w = t >> 6, l = t & 63;
  int lr = l & 15, lk = (l >> 4) * 8;
  f32x4 acc[4] = {};
  int nk = Kdim >> 6;
  for (int kt = 0; kt < nk; ++kt) {
#pragma unroll
    for (int c = 0; c < 2; c++) {
      int id = t + c * 256;
      int r = id >> 3, c8 = (id & 7) * 8;
      *(bf16x8*)&As[r][c8] =
          *(const bf16x8*)(A + abase + (long)(bm + r) * lda + kt * 64 + c8);
      *(bf16x8*)&Bs[r][c8] =
          *(const bf16x8*)(Bt + bbase + (long)(bn + r) * ldb + kt * 64 + c8);
    }
    __syncthreads();
#pragma unroll
    for (int kk = 0; kk < 2; ++kk) {
      bf16x8 af = *(const bf16x8*)&As[w * 16 + lr][kk * 32 + lk];
#pragma unroll
      for (int j = 0; j < 4; j++) {
        bf16x8 bfr = *(const bf16x8*)&Bs[j * 16 + lr][kk * 32 + lk];
        acc[j] = __builtin_amdgcn_mfma_f32_16x16x32_bf16(af, bfr, acc[j], 0, 0, 0);
      }
    }
    __syncthreads();
  }
#pragma unroll
  for (int j = 0; j < 4; j++) {
    int colg = bn + j * 16 + lr;
    float bv = bias ? bias[colg] : 0.0f;
#pragma unroll
    for (int r = 0; r < 4; r++) {
      int rowg = bm + w * 16 + (l >> 4) * 4 + r;
      long cidx = cbase + (long)rowg * ldc + colg;
      float v = acc[j][r] * scale + bv;
      if (addsrc) v += addsrc[cidx];
      if (act == 1) v = 0.5f * v * (1.0f + erff(v * 0.70710678f));
      if (outF) outF[cidx] = v;
      else outB[cidx] = (bf16)v;
    }
  }
}

// ---------------- local-window causal self-attn with ALiBi ------------------
// one wave per (b,h,i); lane = head dim element
__global__ __launch_bounds__(64) void k_self_attn(const bf16* __restrict__ q,
                                                  const bf16* __restrict__ k,
                                                  const bf16* __restrict__ v,
                                                  bf16* __restrict__ o) {
  int i = blockIdx.x;
  int bh = blockIdx.y; int b = bh >> 4; int h = bh & 15;
  int lane = threadIdx.x;
  long base = ((long)b * Lc) * Dc + h * DHc + lane;
  float qd = (float)q[base + (long)i * Dc];
  float slope = exp2f(-0.5f * (float)(h + 1));
  int jlo = i > (Wc - 1) ? i - (Wc - 1) : 0;
  float m = -3.4e38f, ssum = 0.f, acc = 0.f;
  for (int j = jlo; j <= i; ++j) {
    float kd = (float)k[base + (long)j * Dc];
    float p = qd * kd;
#pragma unroll
    for (int off = 1; off < 64; off <<= 1) p += __shfl_xor(p, off);
    float sc = 0.125f * p + slope * (float)(j - i);
    float mn = fmaxf(m, sc);
    float corr = __expf(m - mn);
    float wgt = __expf(sc - mn);
    float vd = (float)v[base + (long)j * Dc];
    acc = acc * corr + wgt * vd;
    ssum = ssum * corr + wgt;
    m = mn;
  }
  o[base + (long)i * Dc] = (bf16)(acc / ssum);
}

// ---------------- row softmax over 2048 cols (in place, bf16) ---------------
__global__ __launch_bounds__(256) void k_softmax2048(bf16* __restrict__ S) {
  long row = blockIdx.x;
  bf16* p = S + row * 2048;
  int t = threadIdx.x; int lane = t & 63; int wid = t >> 6;
  __shared__ float red[4];
  bf16x8 v8 = *(bf16x8*)(p + t * 8);
  float v[8]; float mx = -3.4e38f;
#pragma unroll
  for (int e = 0; e < 8; e++) { v[e] = (float)v8[e]; mx = fmaxf(mx, v[e]); }
#pragma unroll
  for (int off = 1; off < 64; off <<= 1) mx = fmaxf(mx, __shfl_xor(mx, off));
  if (lane == 0) red[wid] = mx;
  __syncthreads();
  mx = fmaxf(fmaxf(red[0], red[1]), fmaxf(red[2], red[3]));
  __syncthreads();
  float s = 0.f;
#pragma unroll
  for (int e = 0; e < 8; e++) { v[e] = __expf(v[e] - mx); s += v[e]; }
#pragma unroll
  for (int off = 1; off < 64; off <<= 1) s += __shfl_xor(s, off);
  if (lane == 0) red[wid] = s;
  __syncthreads();
  s = red[0] + red[1] + red[2] + red[3];
  float inv = 1.0f / s;
  bf16x8 o8;
#pragma unroll
  for (int e = 0; e < 8; e++) o8[e] = (bf16)(v[e] * inv);
  *(bf16x8*)(p + t * 8) = o8;
}

// ---------------- LayerNorm over D=1024; fp32 out + optional bf16 copy ------
__global__ __launch_bounds__(256) void k_layernorm(const float* __restrict__ in,
                                                   const float* __restrict__ g,
                                                   const float* __restrict__ bb,
                                                   float* __restrict__ outF,
                                                   bf16* __restrict__ outB) {
  long row = blockIdx.x;
  const float* p = in + row * Dc;
  int t = threadIdx.x; int lane = t & 63; int wid = t >> 6;
  __shared__ float red[8];
  f32x4 v = *(const f32x4*)(p + t * 4);
  float s = v[0] + v[1] + v[2] + v[3];
  float s2 = v[0] * v[0] + v[1] * v[1] + v[2] * v[2] + v[3] * v[3];
#pragma unroll
  for (int off = 1; off < 64; off <<= 1) {
    s += __shfl_xor(s, off);
    s2 += __shfl_xor(s2, off);
  }
  if (lane == 0) { red[wid] = s; red[4 + wid] = s2; }
  __syncthreads();
  s = red[0] + red[1] + red[2] + red[3];
  s2 = red[4] + red[5] + red[6] + red[7];
  float mu = s * (1.0f / Dc);
  float var = s2 * (1.0f / Dc) - mu * mu;
  float rs = rsqrtf(var + 1e-5f);
#pragma unroll
  for (int e = 0; e < 4; e++) {
    int c = t * 4 + e;
    float y = (v[e] - mu) * rs * g[c] + bb[c];
    outF[row * Dc + c] = y;
    if (outB) outB[row * Dc + c] = (bf16)y;
  }
}

extern "C" void kernel_launch(void* const* d_in, const int* in_sizes, int n_in,
                              void* d_out, int out_size, void* d_ws,
                              size_t ws_size, hipStream_t stream) {
  (void)in_sizes; (void)n_in; (void)out_size; (void)ws_size;
  const float* x = (const float*)d_in[0];
  const float* mem = (const float*)d_in[1];
  const float* swq = (const float*)d_in[2];
  const float* swk = (const float*)d_in[3];
  const float* swv = (const float*)d_in[4];
  const float* swo = (const float*)d_in[5];
  const float* sbq = (const float*)d_in[6];
  const float* sbk = (const float*)d_in[7];
  const float* sbv = (const float*)d_in[8];
  const float* sbo = (const float*)d_in[9];
  const float* cwq = (const float*)d_in[10];
  const float* cwk = (const float*)d_in[11];
  const float* cwv = (const float*)d_in[12];
  const float* cwo = (const float*)d_in[13];
  const float* cbq = (const float*)d_in[14];
  const float* cbk = (const float*)d_in[15];
  const float* cbv = (const float*)d_in[16];
  const float* cbo = (const float*)d_in[17];
  const float* w1 = (const float*)d_in[18];
  const float* b1 = (const float*)d_in[19];
  const float* w2 = (const float*)d_in[20];
  const float* b2 = (const float*)d_in[21];
  const float* g1 = (const float*)d_in[22];
  const float* g2 = (const float*)d_in[23];
  const float* g3 = (const float*)d_in[24];
  const float* be1 = (const float*)d_in[25];
  const float* be2 = (const float*)d_in[26];
  const float* be3 = (const float*)d_in[27];
  float* out = (float*)d_out;

  char* ws = (char*)d_ws;
  size_t off = 0;
  auto alloc = [&](size_t bytes) -> char* {
    char* p = ws + off;
    off = (off + bytes + 255) & ~(size_t)255;
    return p;
  };

  const long BL = (long)Bc * Lc;    // 4096
  const long BM = (long)Bc * Mc;    // 4096
  const int CH = 8;                 // heads per cross-attn chunk

  bf16* wT[8];
  for (int i = 0; i < 8; i++) wT[i] = (bf16*)alloc((size_t)Dc * Dc * 2);
  bf16* w1T = (bf16*)alloc((size_t)FFc * Dc * 2);
  bf16* w2T = (bf16*)alloc((size_t)Dc * FFc * 2);
  bf16* xb = (bf16*)alloc((size_t)BL * Dc * 2);
  bf16* memb = (bf16*)alloc((size_t)BM * Dc * 2);
  bf16* x1b = (bf16*)alloc((size_t)BL * Dc * 2);
  bf16* x2b = (bf16*)alloc((size_t)BL * Dc * 2);
  bf16* qb = (bf16*)alloc((size_t)BM * Dc * 2);
  bf16* kb = (bf16*)alloc((size_t)BM * Dc * 2);
  bf16* vb = (bf16*)alloc((size_t)BM * Dc * 2);
  bf16* ob = (bf16*)alloc((size_t)BL * Dc * 2);
  bf16* vt = (bf16*)alloc((size_t)Bc * Hc * DHc * Mc * 2);
  float* rbuf = (float*)alloc((size_t)BL * Dc * 4);
  float* x1f = (float*)alloc((size_t)BL * Dc * 4);
  float* x2f = (float*)alloc((size_t)BL * Dc * 4);
  bf16* ffh = (bf16*)alloc((size_t)BL * FFc * 2);
  bf16* Sbuf = (bf16*)alloc((size_t)CH * Lc * Mc * 2);

  // ---- prep: transpose weights to bf16 [N,K]
  const float* wsrc[8] = {swq, swk, swv, swo, cwq, cwk, cwv, cwo};
  for (int i = 0; i < 8; i++)
    k_transpose_w<<<dim3(Dc / 64, Dc / 64), 256, 0, stream>>>(wsrc[i], wT[i], Dc, Dc);
  k_transpose_w<<<dim3(FFc / 64, Dc / 64), 256, 0, stream>>>(w1, w1T, Dc, FFc);
  k_transpose_w<<<dim3(Dc / 64, FFc / 64), 256, 0, stream>>>(w2, w2T, FFc, Dc);
  k_f2b<<<dim3((unsigned)(BL * Dc / 4 / 256)), 256, 0, stream>>>(x, xb, BL * Dc / 4);
  k_f2b<<<dim3((unsigned)(BM * Dc / 4 / 256)), 256, 0, stream>>>(mem, memb, BM * Dc / 4);

  // ---- self-attn QKV projections
  dim3 gD(Dc / 64, BL / 64, 1);
  k_gemm<<<gD, 256, 0, stream>>>(xb, Dc, 0, 0, 0, wT[0], Dc, 0, 0, 0, nullptr,
                                 qb, Dc, 0, 0, 0, sbq, nullptr, Dc, 1, 1.0f, 0);
  k_gemm<<<gD, 256, 0, stream>>>(xb, Dc, 0, 0, 0, wT[1], Dc, 0, 0, 0, nullptr,
                                 kb, Dc, 0, 0, 0, sbk, nullptr, Dc, 1, 1.0f, 0);
  k_gemm<<<gD, 256, 0, stream>>>(xb, Dc, 0, 0, 0, wT[2], Dc, 0, 0, 0, nullptr,
                                 vb, Dc, 0, 0, 0, sbv, nullptr, Dc, 1, 1.0f, 0);
  // ---- windowed causal self-attn
  k_self_attn<<<dim3(Lc, Bc * Hc), 64, 0, stream>>>(qb, kb, vb, ob);
  // ---- self O-proj + residual(x)
  k_gemm<<<gD, 256, 0, stream>>>(ob, Dc, 0, 0, 0, wT[3], Dc, 0, 0, 0, rbuf,
                                 nullptr, Dc, 0, 0, 0, sbo, x, Dc, 1, 1.0f, 0);
  k_layernorm<<<dim3((unsigned)BL), 256, 0, stream>>>(rbuf, g1, be1, x1f, x1b);

  // ---- cross-attn projections
  k_gemm<<<gD, 256, 0, stream>>>(x1b, Dc, 0, 0, 0, wT[4], Dc, 0, 0, 0, nullptr,
                                 qb, Dc, 0, 0, 0, cbq, nullptr, Dc, 1, 1.0f, 0);
  k_gemm<<<gD, 256, 0, stream>>>(memb, Dc, 0, 0, 0, wT[5], Dc, 0, 0, 0, nullptr,
                                 kb, Dc, 0, 0, 0, cbk, nullptr, Dc, 1, 1.0f, 0);
  k_gemm<<<gD, 256, 0, stream>>>(memb, Dc, 0, 0, 0, wT[6], Dc, 0, 0, 0, nullptr,
                                 vb, Dc, 0, 0, 0, cbv, nullptr, Dc, 1, 1.0f, 0);
  k_transpose_v<<<dim3(Mc / 64, Bc * Hc), 256, 0, stream>>>(vb, vt);

  // ---- cross attention, chunked over (b, 8 heads)
  for (int b = 0; b < Bc; b++) {
    for (int hg = 0; hg < Hc / CH; hg++) {
      int h0 = hg * CH;
      // S = 0.125 * Q K^T   [CH, L, M] bf16
      k_gemm<<<dim3(Mc / 64, Lc / 64, CH), 256, 0, stream>>>(
          qb, Dc, (long)b * Lc * Dc + h0 * DHc, DHc, 0,
          kb, Dc, (long)b * Mc * Dc + h0 * DHc, DHc, 0,
          nullptr, Sbuf, Mc, 0, (long)Lc * Mc, 0,
          nullptr, nullptr, DHc, CH, 0.125f, 0);
      k_softmax2048<<<dim3((unsigned)(CH * Lc)), 256, 0, stream>>>(Sbuf);
      // O = P V   -> ob[b, :, h*DH..]
      k_gemm<<<dim3(1, Lc / 64, CH), 256, 0, stream>>>(
          Sbuf, Mc, 0, (long)Lc * Mc, 0,
          vt, Mc, ((long)b * Hc + h0) * DHc * Mc, (long)DHc * Mc, 0,
          nullptr, ob, Dc, (long)b * Lc * Dc + h0 * DHc, DHc, 0,
          nullptr, nullptr, Mc, CH, 1.0f, 0);
    }
  }
  // ---- cross O-proj + residual(x1)
  k_gemm<<<gD, 256, 0, stream>>>(ob, Dc, 0, 0, 0, wT[7], Dc, 0, 0, 0, rbuf,
                                 nullptr, Dc, 0, 0, 0, cbo, x1f, Dc, 1, 1.0f, 0);
  k_layernorm<<<dim3((unsigned)BL), 256, 0, stream>>>(rbuf, g2, be2, x2f, x2b);

  // ---- FFN
  k_gemm<<<dim3(FFc / 64, BL / 64, 1), 256, 0, stream>>>(
      x2b, Dc, 0, 0, 0, w1T, Dc, 0, 0, 0, nullptr, ffh, FFc, 0, 0, 0, b1,
      nullptr, Dc, 1, 1.0f, 1);
  k_gemm<<<dim3(Dc / 64, BL / 64, 1), 256, 0, stream>>>(
      ffh, FFc, 0, 0, 0, w2T, FFc, 0, 0, 0, rbuf, nullptr, Dc, 0, 0, 0, b2,
      x2f, FFc, 1, 1.0f, 0);
  k_layernorm<<<dim3((unsigned)BL), 256, 0, stream>>>(rbuf, g3, be3, out, nullptr);
}

// Round 2
// 629.198 us; speedup vs baseline: 1.9702x; 1.9702x over previous
//
#include <hip/hip_runtime.h>
#include <hip/hip_bf16.h>
#include <math.h>

#define Bc 2
#define Lc 2048
#define Mc 2048
#define Dc 1024
#define Hc 16
#define FFc 4096
#define DHc 64

typedef __bf16 bf16;
typedef float f32x4 __attribute__((ext_vector_type(4)));
typedef __bf16 bf16x8 __attribute__((ext_vector_type(8)));
typedef __bf16 bf16x4 __attribute__((ext_vector_type(4)));

__device__ inline void gload16(const bf16* g, const bf16* lds_base) {
  __builtin_amdgcn_global_load_lds(
      (const __attribute__((address_space(1))) void*)g,
      (__attribute__((address_space(3))) void*)lds_base, 16, 0, 0);
}

// ---------------- fp32 -> bf16 convert (vectorized) ----------------
__global__ __launch_bounds__(256) void k_f2b(const float* __restrict__ in,
                                             bf16* __restrict__ out, long n4) {
  long i = (long)blockIdx.x * 256 + threadIdx.x;
  if (i >= n4) return;
  f32x4 v = *(const f32x4*)(in + i * 4);
  bf16x4 o;
  o[0] = (bf16)v[0]; o[1] = (bf16)v[1]; o[2] = (bf16)v[2]; o[3] = (bf16)v[3];
  *(bf16x4*)(out + i * 4) = o;
}

// ---------------- weight transpose+convert: out[n*K+k] = bf16(in[k*N+n]) ----
__global__ __launch_bounds__(256) void k_transpose_w(const float* __restrict__ in,
                                                     bf16* __restrict__ out,
                                                     int K, int N) {
  __shared__ float tile[64][65];
  int n0 = blockIdx.x * 64, k0 = blockIdx.y * 64;
  int t = threadIdx.x;
  int tr = t >> 4, tc = (t & 15) * 4;
#pragma unroll
  for (int p = 0; p < 4; p++) {
    int r = p * 16 + tr;
    f32x4 v = *(const f32x4*)(in + (long)(k0 + r) * N + n0 + tc);
    tile[r][tc] = v[0]; tile[r][tc + 1] = v[1];
    tile[r][tc + 2] = v[2]; tile[r][tc + 3] = v[3];
  }
  __syncthreads();
#pragma unroll
  for (int p = 0; p < 4; p++) {
    int rn = p * 16 + tr;
    bf16x4 o;
    o[0] = (bf16)tile[tc + 0][rn]; o[1] = (bf16)tile[tc + 1][rn];
    o[2] = (bf16)tile[tc + 2][rn]; o[3] = (bf16)tile[tc + 3][rn];
    *(bf16x4*)(out + (long)(n0 + rn) * K + k0 + tc) = o;
  }
}

// ---------------- 128x128 MFMA GEMM (m97 structure), BK=64 -----------------
// A: [M,K] rm (lda), Bt: [N,K] rm (ldb=Kdim). z selects B/bias/C-slab.
__global__ __launch_bounds__(256) void k_gemm128(
    const bf16* __restrict__ A, long lda,
    const bf16* __restrict__ B0, long bstride,
    float* __restrict__ outF, bf16* __restrict__ outB, long ldc, long cstride,
    const float* __restrict__ bias0, const float* __restrict__ bias1,
    const float* __restrict__ bias2, const float* __restrict__ addsrc,
    int Kdim, int act) {
  __shared__ __align__(16) bf16 As[128 * 64];
  __shared__ __align__(16) bf16 Bs[128 * 64];
  int z = blockIdx.z;
  const bf16* Bt = B0 + (long)z * bstride;
  const float* bias = (z == 0) ? bias0 : ((z == 1) ? bias1 : bias2);
  long cbase = (long)z * cstride;
  int bm = blockIdx.y * 128, bn = blockIdx.x * 128;
  int t = threadIdx.x, w = t >> 6, lane = t & 63;
  int wm = w >> 1, wn = w & 1;
  int lr = lane & 15, lg = lane >> 4;
  int srow = lane >> 3, scol = (lane & 7) * 8;
  f32x4 acc[4][4] = {};
  int nk = Kdim >> 6;
  for (int kt = 0; kt < nk; ++kt) {
    long k0 = (long)kt * 64;
#pragma unroll
    for (int i = 0; i < 4; i++) {
      int row = (i * 4 + w) * 8 + srow;
      gload16(A + (long)(bm + row) * lda + k0 + scol, &As[(i * 4 + w) * 512]);
      gload16(Bt + (long)(bn + row) * Kdim + k0 + scol, &Bs[(i * 4 + w) * 512]);
    }
    __syncthreads();
#pragma unroll
    for (int kk = 0; kk < 2; kk++) {
      bf16x8 af[4], bfr[4];
#pragma unroll
      for (int m = 0; m < 4; m++)
        af[m] = *(const bf16x8*)&As[(wm * 64 + m * 16 + lr) * 64 + kk * 32 + lg * 8];
#pragma unroll
      for (int n = 0; n < 4; n++)
        bfr[n] = *(const bf16x8*)&Bs[(wn * 64 + n * 16 + lr) * 64 + kk * 32 + lg * 8];
#pragma unroll
      for (int m = 0; m < 4; m++)
#pragma unroll
        for (int n = 0; n < 4; n++)
          acc[m][n] = __builtin_amdgcn_mfma_f32_16x16x32_bf16(af[m], bfr[n],
                                                              acc[m][n], 0, 0, 0);
    }
    __syncthreads();
  }
#pragma unroll
  for (int n = 0; n < 4; n++) {
    int cg = bn + wn * 64 + n * 16 + lr;
    float bv = bias ? bias[cg] : 0.0f;
#pragma unroll
    for (int m = 0; m < 4; m++) {
#pragma unroll
      for (int rr = 0; rr < 4; rr++) {
        int rg = bm + wm * 64 + m * 16 + lg * 4 + rr;
        long ci = cbase + (long)rg * ldc + cg;
        float v = acc[m][n][rr] + bv;
        if (addsrc) v += addsrc[ci];
        if (act == 1) v = 0.5f * v * (1.0f + erff(v * 0.70710678f));
        if (outF) outF[ci] = v;
        else outB[ci] = (bf16)v;
      }
    }
  }
}

// ---------------- flash attention (self: windowed+ALiBi, cross: full) ------
// 64-query tile per block, 4 waves x 16 queries; key chunks of 64.
template <int WINDOWED>
__global__ __launch_bounds__(256) void k_flash(const bf16* __restrict__ Qg,
                                               const bf16* __restrict__ Kg,
                                               const bf16* __restrict__ Vg,
                                               bf16* __restrict__ Og, int nkv) {
  __shared__ __align__(16) bf16 Qs[64][72];
  __shared__ __align__(16) bf16 Ks[64][72];
  __shared__ __align__(16) bf16 Vt[64][72];
  __shared__ __align__(16) bf16 Ps[4][16][72];
  int i0 = blockIdx.x * 64;
  int bh = blockIdx.y; int b = bh >> 4; int h = bh & 15;
  int t = threadIdx.x; int w = t >> 6; int lane = t & 63;
  int lr = lane & 15, lg = lane >> 4;
  long qoff = (long)b * Lc * Dc + h * DHc;
  long kvoff = (long)b * nkv * Dc + h * DHc;
  // stage Q tile (64x64)
#pragma unroll
  for (int c = 0; c < 2; c++) {
    int id = t + c * 256;
    int r = id >> 3, c8 = (id & 7) * 8;
    *(bf16x8*)&Qs[r][c8] = *(const bf16x8*)(Qg + qoff + (long)(i0 + r) * Dc + c8);
  }
  float m[4] = {-1e30f, -1e30f, -1e30f, -1e30f};
  float l[4] = {};
  f32x4 oa[4] = {};
  float slope = WINDOWED ? exp2f(-0.5f * (float)(h + 1)) : 0.0f;
  int kb0 = WINDOWED ? (i0 >= 64 ? i0 - 64 : 0) : 0;
  int kb1 = WINDOWED ? i0 : nkv - 64;
  for (int kbase = kb0; kbase <= kb1; kbase += 64) {
    // stage K (row-major) and V transposed (Vt[d][key])
#pragma unroll
    for (int c = 0; c < 2; c++) {
      int id = t + c * 256;
      int r = id >> 3, c8 = (id & 7) * 8;
      int j = kbase + r;
      int jc = j < 0 ? 0 : (j >= nkv ? nkv - 1 : j);
      *(bf16x8*)&Ks[r][c8] = *(const bf16x8*)(Kg + kvoff + (long)jc * Dc + c8);
      bf16x8 v8 = *(const bf16x8*)(Vg + kvoff + (long)jc * Dc + c8);
#pragma unroll
      for (int e = 0; e < 8; e++) Vt[c8 + e][r] = v8[e];
    }
    __syncthreads();
    // S = Q K^T (per wave: 16q x 64k)
    f32x4 s[4] = {};
#pragma unroll
    for (int ks = 0; ks < 2; ks++) {
      bf16x8 a = *(const bf16x8*)&Qs[w * 16 + lr][ks * 32 + lg * 8];
#pragma unroll
      for (int j = 0; j < 4; j++) {
        bf16x8 bb = *(const bf16x8*)&Ks[j * 16 + lr][ks * 32 + lg * 8];
        s[j] = __builtin_amdgcn_mfma_f32_16x16x32_bf16(a, bb, s[j], 0, 0, 0);
      }
    }
    // online softmax (row = lg*4+rr, col = j*16+lr)
#pragma unroll
    for (int rr = 0; rr < 4; rr++) {
      int iabs = i0 + w * 16 + lg * 4 + rr;
      float sc[4];
      float mx = m[rr];
#pragma unroll
      for (int j = 0; j < 4; j++) {
        int jabs = kbase + j * 16 + lr;
        float v = s[j][rr] * 0.125f;
        if (WINDOWED) {
          v += slope * (float)(jabs - iabs);
          bool valid = (jabs <= iabs) && (iabs - jabs < 64) && (jabs >= 0);
          v = valid ? v : -3.0e38f;
        }
        sc[j] = v;
        mx = fmaxf(mx, v);
      }
#pragma unroll
      for (int off = 1; off < 16; off <<= 1) mx = fmaxf(mx, __shfl_xor(mx, off));
      float corr = __expf(m[rr] - mx);
      m[rr] = mx;
      float ps = 0.0f;
#pragma unroll
      for (int j = 0; j < 4; j++) {
        float pj = __expf(sc[j] - mx);
        ps += pj;
        Ps[w][lg * 4 + rr][j * 16 + lr] = (bf16)pj;
      }
      l[rr] = l[rr] * corr + ps;  // lane-partial row sum; reduced at epilogue
#pragma unroll
      for (int jd = 0; jd < 4; jd++) oa[jd][rr] *= corr;
    }
    __syncthreads();  // Ps visible
    // O += P V   (A=P[16q x 64k], B=Vt[d][k])
#pragma unroll
    for (int ks = 0; ks < 2; ks++) {
      bf16x8 pa = *(const bf16x8*)&Ps[w][lr][ks * 32 + lg * 8];
#pragma unroll
      for (int jd = 0; jd < 4; jd++) {
        bf16x8 vb8 = *(const bf16x8*)&Vt[jd * 16 + lr][ks * 32 + lg * 8];
        oa[jd] = __builtin_amdgcn_mfma_f32_16x16x32_bf16(pa, vb8, oa[jd], 0, 0, 0);
      }
    }
    __syncthreads();  // before restaging K/Vt
  }
  // epilogue: reduce l across the 16-lane group, scale, store
#pragma unroll
  for (int rr = 0; rr < 4; rr++) {
    float ls = l[rr];
#pragma unroll
    for (int off = 1; off < 16; off <<= 1) ls += __shfl_xor(ls, off);
    float inv = 1.0f / ls;
    int iabs = i0 + w * 16 + lg * 4 + rr;
#pragma unroll
    for (int jd = 0; jd < 4; jd++)
      Og[qoff + (long)iabs * Dc + jd * 16 + lr] = (bf16)(oa[jd][rr] * inv);
  }
}

// ---------------- LayerNorm over D=1024; fp32 out + optional bf16 copy ------
__global__ __launch_bounds__(256) void k_layernorm(const float* __restrict__ in,
                                                   const float* __restrict__ g,
                                                   const float* __restrict__ bb,
                                                   float* __restrict__ outF,
                                                   bf16* __restrict__ outB) {
  long row = blockIdx.x;
  const float* p = in + row * Dc;
  int t = threadIdx.x; int lane = t & 63; int wid = t >> 6;
  __shared__ float red[8];
  f32x4 v = *(const f32x4*)(p + t * 4);
  float s = v[0] + v[1] + v[2] + v[3];
  float s2 = v[0] * v[0] + v[1] * v[1] + v[2] * v[2] + v[3] * v[3];
#pragma unroll
  for (int off = 1; off < 64; off <<= 1) {
    s += __shfl_xor(s, off);
    s2 += __shfl_xor(s2, off);
  }
  if (lane == 0) { red[wid] = s; red[4 + wid] = s2; }
  __syncthreads();
  s = red[0] + red[1] + red[2] + red[3];
  s2 = red[4] + red[5] + red[6] + red[7];
  float mu = s * (1.0f / Dc);
  float var = s2 * (1.0f / Dc) - mu * mu;
  float rs = rsqrtf(var + 1e-5f);
#pragma unroll
  for (int e = 0; e < 4; e++) {
    int c = t * 4 + e;
    float y = (v[e] - mu) * rs * g[c] + bb[c];
    outF[row * Dc + c] = y;
    if (outB) outB[row * Dc + c] = (bf16)y;
  }
}

extern "C" void kernel_launch(void* const* d_in, const int* in_sizes, int n_in,
                              void* d_out, int out_size, void* d_ws,
                              size_t ws_size, hipStream_t stream) {
  (void)in_sizes; (void)n_in; (void)out_size; (void)ws_size;
  const float* x = (const float*)d_in[0];
  const float* mem = (const float*)d_in[1];
  const float* swq = (const float*)d_in[2];
  const float* swk = (const float*)d_in[3];
  const float* swv = (const float*)d_in[4];
  const float* swo = (const float*)d_in[5];
  const float* sbq = (const float*)d_in[6];
  const float* sbk = (const float*)d_in[7];
  const float* sbv = (const float*)d_in[8];
  const float* sbo = (const float*)d_in[9];
  const float* cwq = (const float*)d_in[10];
  const float* cwk = (const float*)d_in[11];
  const float* cwv = (const float*)d_in[12];
  const float* cwo = (const float*)d_in[13];
  const float* cbq = (const float*)d_in[14];
  const float* cbk = (const float*)d_in[15];
  const float* cbv = (const float*)d_in[16];
  const float* cbo = (const float*)d_in[17];
  const float* w1 = (const float*)d_in[18];
  const float* b1 = (const float*)d_in[19];
  const float* w2 = (const float*)d_in[20];
  const float* b2 = (const float*)d_in[21];
  const float* g1 = (const float*)d_in[22];
  const float* g2 = (const float*)d_in[23];
  const float* g3 = (const float*)d_in[24];
  const float* be1 = (const float*)d_in[25];
  const float* be2 = (const float*)d_in[26];
  const float* be3 = (const float*)d_in[27];
  float* out = (float*)d_out;

  char* ws = (char*)d_ws;
  size_t off = 0;
  auto alloc = [&](size_t bytes) -> char* {
    char* p = ws + off;
    off = (off + bytes + 255) & ~(size_t)255;
    return p;
  };

  const long BL = (long)Bc * Lc;  // 4096
  const long BM = (long)Bc * Mc;  // 4096
  const long DD = (long)Dc * Dc;

  bf16* wT0 = (bf16*)alloc((size_t)8 * DD * 2);  // 8 weight mats, contiguous
  bf16* w1T = (bf16*)alloc((size_t)FFc * Dc * 2);
  bf16* w2T = (bf16*)alloc((size_t)Dc * FFc * 2);
  bf16* xb = (bf16*)alloc((size_t)BL * Dc * 2);
  bf16* memb = (bf16*)alloc((size_t)BM * Dc * 2);
  bf16* x1b = (bf16*)alloc((size_t)BL * Dc * 2);
  bf16* x2b = (bf16*)alloc((size_t)BL * Dc * 2);
  bf16* qb = (bf16*)alloc((size_t)BL * Dc * 2);  // qb,kb,vb contiguous
  bf16* kb = (bf16*)alloc((size_t)BM * Dc * 2);
  bf16* vb = (bf16*)alloc((size_t)BM * Dc * 2);
  bf16* ob = (bf16*)alloc((size_t)BL * Dc * 2);
  float* rbuf = (float*)alloc((size_t)BL * Dc * 4);
  float* x1f = (float*)alloc((size_t)BL * Dc * 4);
  float* x2f = (float*)alloc((size_t)BL * Dc * 4);
  bf16* ffh = (bf16*)alloc((size_t)BL * FFc * 2);

  // ---- prep: weights -> bf16 [N,K]
  const float* wsrc[8] = {swq, swk, swv, swo, cwq, cwk, cwv, cwo};
  for (int i = 0; i < 8; i++)
    k_transpose_w<<<dim3(Dc / 64, Dc / 64), 256, 0, stream>>>(wsrc[i], wT0 + i * DD, Dc, Dc);
  k_transpose_w<<<dim3(FFc / 64, Dc / 64), 256, 0, stream>>>(w1, w1T, Dc, FFc);
  k_transpose_w<<<dim3(Dc / 64, FFc / 64), 256, 0, stream>>>(w2, w2T, FFc, Dc);
  k_f2b<<<dim3((unsigned)(BL * Dc / 4 / 256)), 256, 0, stream>>>(x, xb, BL * Dc / 4);
  k_f2b<<<dim3((unsigned)(BM * Dc / 4 / 256)), 256, 0, stream>>>(mem, memb, BM * Dc / 4);

  // ---- self-attn QKV projections (z-batched: q,k,v)
  k_gemm128<<<dim3(Dc / 128, BL / 128, 3), 256, 0, stream>>>(
      xb, Dc, wT0, DD, nullptr, qb, Dc, BL * Dc, sbq, sbk, sbv, nullptr, Dc, 0);
  // ---- windowed causal self-attn + ALiBi (fused flash)
  k_flash<1><<<dim3(Lc / 64, Bc * Hc), 256, 0, stream>>>(qb, kb, vb, ob, Lc);
  // ---- self O-proj + residual(x)
  k_gemm128<<<dim3(Dc / 128, BL / 128, 1), 256, 0, stream>>>(
      ob, Dc, wT0 + 3 * DD, 0, rbuf, nullptr, Dc, 0, sbo, sbo, sbo, x, Dc, 0);
  k_layernorm<<<dim3((unsigned)BL), 256, 0, stream>>>(rbuf, g1, be1, x1f, x1b);

  // ---- cross-attn projections
  k_gemm128<<<dim3(Dc / 128, BL / 128, 1), 256, 0, stream>>>(
      x1b, Dc, wT0 + 4 * DD, 0, nullptr, qb, Dc, 0, cbq, cbq, cbq, nullptr, Dc, 0);
  k_gemm128<<<dim3(Dc / 128, BM / 128, 2), 256, 0, stream>>>(
      memb, Dc, wT0 + 5 * DD, DD, nullptr, kb, Dc, BM * Dc, cbk, cbv, cbv, nullptr, Dc, 0);
  // ---- fused flash cross-attention
  k_flash<0><<<dim3(Lc / 64, Bc * Hc), 256, 0, stream>>>(qb, kb, vb, ob, Mc);
  // ---- cross O-proj + residual(x1)
  k_gemm128<<<dim3(Dc / 128, BL / 128, 1), 256, 0, stream>>>(
      ob, Dc, wT0 + 7 * DD, 0, rbuf, nullptr, Dc, 0, cbo, cbo, cbo, x1f, Dc, 0);
  k_layernorm<<<dim3((unsigned)BL), 256, 0, stream>>>(rbuf, g2, be2, x2f, x2b);

  // ---- FFN
  k_gemm128<<<dim3(FFc / 128, BL / 128, 1), 256, 0, stream>>>(
      x2b, Dc, w1T, 0, nullptr, ffh, FFc, 0, b1, b1, b1, nullptr, Dc, 1);
  k_gemm128<<<dim3(Dc / 128, BL / 128, 1), 256, 0, stream>>>(
      ffh, FFc, w2T, 0, rbuf, nullptr, Dc, 0, b2, b2, b2, x2f, FFc, 0);
  k_layernorm<<<dim3((unsigned)BL), 256, 0, stream>>>(rbuf, g3, be3, out, nullptr);
}

// Round 3
// 560.190 us; speedup vs baseline: 2.2129x; 1.1232x over previous
//
#include <hip/hip_runtime.h>
#include <hip/hip_bf16.h>
#include <math.h>

#define Bc 2
#define Lc 2048
#define Mc 2048
#define Dc 1024
#define Hc 16
#define FFc 4096
#define DHc 64

typedef __bf16 bf16;
typedef float f32x4 __attribute__((ext_vector_type(4)));
typedef __bf16 bf16x8 __attribute__((ext_vector_type(8)));
typedef __bf16 bf16x4 __attribute__((ext_vector_type(4)));
typedef __bf16 bf16x2 __attribute__((ext_vector_type(2)));

__device__ inline void gload16(const bf16* g, const bf16* lds_base) {
  __builtin_amdgcn_global_load_lds(
      (const __attribute__((address_space(1))) void*)g,
      (__attribute__((address_space(3))) void*)lds_base, 16, 0, 0);
}

// ---------------- fp32 -> bf16 convert (vectorized) ----------------
__global__ __launch_bounds__(256) void k_f2b(const float* __restrict__ in,
                                             bf16* __restrict__ out, long n4) {
  long i = (long)blockIdx.x * 256 + threadIdx.x;
  if (i >= n4) return;
  f32x4 v = *(const f32x4*)(in + i * 4);
  bf16x4 o;
  o[0] = (bf16)v[0]; o[1] = (bf16)v[1]; o[2] = (bf16)v[2]; o[3] = (bf16)v[3];
  *(bf16x4*)(out + i * 4) = o;
}

// ---------------- weight transpose+convert: out[n*K+k] = bf16(in[k*N+n]) ----
__global__ __launch_bounds__(256) void k_transpose_w(const float* __restrict__ in,
                                                     bf16* __restrict__ out,
                                                     int K, int N) {
  __shared__ float tile[64][65];
  int n0 = blockIdx.x * 64, k0 = blockIdx.y * 64;
  int t = threadIdx.x;
  int tr = t >> 4, tc = (t & 15) * 4;
#pragma unroll
  for (int p = 0; p < 4; p++) {
    int r = p * 16 + tr;
    f32x4 v = *(const f32x4*)(in + (long)(k0 + r) * N + n0 + tc);
    tile[r][tc] = v[0]; tile[r][tc + 1] = v[1];
    tile[r][tc + 2] = v[2]; tile[r][tc + 3] = v[3];
  }
  __syncthreads();
#pragma unroll
  for (int p = 0; p < 4; p++) {
    int rn = p * 16 + tr;
    bf16x4 o;
    o[0] = (bf16)tile[tc + 0][rn]; o[1] = (bf16)tile[tc + 1][rn];
    o[2] = (bf16)tile[tc + 2][rn]; o[3] = (bf16)tile[tc + 3][rn];
    *(bf16x4*)(out + (long)(n0 + rn) * K + k0 + tc) = o;
  }
}

// ---- V transpose: vt[(b*H+h)*DH+d][j] = vb[b][j][h*DH+d], j in [0,N) ------
__global__ __launch_bounds__(256) void k_transpose_v(const bf16* __restrict__ vb,
                                                     bf16* __restrict__ vt, int N) {
  __shared__ bf16 tile[64][72];
  int j0 = blockIdx.x * 64;
  int bh = blockIdx.y; int b = bh >> 4; int h = bh & 15;
  int t = threadIdx.x;
#pragma unroll
  for (int c = 0; c < 2; c++) {
    int id = t + c * 256;
    int r = id >> 3, c8 = (id & 7) * 8;
    *(bf16x8*)&tile[r][c8] =
        *(const bf16x8*)(vb + ((long)(b * N + j0 + r)) * Dc + h * DHc + c8);
  }
  __syncthreads();
#pragma unroll
  for (int c = 0; c < 2; c++) {
    int id = t + c * 256;
    int d = id >> 3, j8 = (id & 7) * 8;
    bf16x8 o;
#pragma unroll
    for (int e = 0; e < 8; e++) o[e] = tile[j8 + e][d];
    *(bf16x8*)(vt + ((long)bh * DHc + d) * N + j0 + j8) = o;
  }
}

// ---------------- 128x128 MFMA GEMM (m97 structure), BK=64 -----------------
__global__ __launch_bounds__(256) void k_gemm128(
    const bf16* __restrict__ A, long lda,
    const bf16* __restrict__ B0, long bstride,
    float* __restrict__ outF, bf16* __restrict__ outB, long ldc, long cstride,
    const float* __restrict__ bias0, const float* __restrict__ bias1,
    const float* __restrict__ bias2, const float* __restrict__ addsrc,
    int Kdim, int act) {
  __shared__ __align__(16) bf16 As[128 * 64];
  __shared__ __align__(16) bf16 Bs[128 * 64];
  int z = blockIdx.z;
  const bf16* Bt = B0 + (long)z * bstride;
  const float* bias = (z == 0) ? bias0 : ((z == 1) ? bias1 : bias2);
  long cbase = (long)z * cstride;
  int bm = blockIdx.y * 128, bn = blockIdx.x * 128;
  int t = threadIdx.x, w = t >> 6, lane = t & 63;
  int wm = w >> 1, wn = w & 1;
  int lr = lane & 15, lg = lane >> 4;
  int srow = lane >> 3, scol = (lane & 7) * 8;
  f32x4 acc[4][4] = {};
  int nk = Kdim >> 6;
  for (int kt = 0; kt < nk; ++kt) {
    long k0 = (long)kt * 64;
#pragma unroll
    for (int i = 0; i < 4; i++) {
      int row = (i * 4 + w) * 8 + srow;
      gload16(A + (long)(bm + row) * lda + k0 + scol, &As[(i * 4 + w) * 512]);
      gload16(Bt + (long)(bn + row) * Kdim + k0 + scol, &Bs[(i * 4 + w) * 512]);
    }
    __syncthreads();
#pragma unroll
    for (int kk = 0; kk < 2; kk++) {
      bf16x8 af[4], bfr[4];
#pragma unroll
      for (int m = 0; m < 4; m++)
        af[m] = *(const bf16x8*)&As[(wm * 64 + m * 16 + lr) * 64 + kk * 32 + lg * 8];
#pragma unroll
      for (int n = 0; n < 4; n++)
        bfr[n] = *(const bf16x8*)&Bs[(wn * 64 + n * 16 + lr) * 64 + kk * 32 + lg * 8];
#pragma unroll
      for (int m = 0; m < 4; m++)
#pragma unroll
        for (int n = 0; n < 4; n++)
          acc[m][n] = __builtin_amdgcn_mfma_f32_16x16x32_bf16(af[m], bfr[n],
                                                              acc[m][n], 0, 0, 0);
    }
    __syncthreads();
  }
#pragma unroll
  for (int n = 0; n < 4; n++) {
    int cg = bn + wn * 64 + n * 16 + lr;
    float bv = bias ? bias[cg] : 0.0f;
#pragma unroll
    for (int m = 0; m < 4; m++) {
#pragma unroll
      for (int rr = 0; rr < 4; rr++) {
        int rg = bm + wm * 64 + m * 16 + lg * 4 + rr;
        long ci = cbase + (long)rg * ldc + cg;
        float v = acc[m][n][rr] + bv;
        if (addsrc) v += addsrc[ci];
        if (act == 1) v = 0.5f * v * (1.0f + erff(v * 0.70710678f));
        if (outF) outF[ci] = v;
        else outB[ci] = (bf16)v;
      }
    }
  }
}

// ---------------- flash attention v2 ---------------------------------------
// 64 q / block (4 waves x 16), key chunks of 64, swapped QK^T, pre-transposed V.
template <int WINDOWED>
__global__ __launch_bounds__(256) void k_flash(const bf16* __restrict__ Qg,
                                               const bf16* __restrict__ Kg,
                                               const bf16* __restrict__ Vtg,
                                               bf16* __restrict__ Og, int nkv) {
  __shared__ __align__(16) bf16 Qs[64 * 64];
  __shared__ __align__(16) bf16 Ks[2][64 * 64];
  __shared__ __align__(16) bf16 Vs[2][64 * 64];
  __shared__ __align__(16) bf16 Pl[4][16 * 72];
  int i0 = blockIdx.x * 64;
  int bh = blockIdx.y; int b = bh >> 4, h = bh & 15;
  int t = threadIdx.x, w = t >> 6, lane = t & 63;
  int lr = lane & 15, lg = lane >> 4;
  long qoff = ((long)b * Lc + i0) * Dc + h * DHc;
  long koff = ((long)b * nkv) * Dc + h * DHc;
  long vtoff = (long)bh * DHc * nkv;
  // staging geometry: LDS byte slot o -> (row=o>>7, swizzled col)
  int o0 = w * 1024 + (lane << 4), o1 = o0 + 4096;
  int r0 = o0 >> 7, c0 = (o0 & 127) ^ ((r0 & 7) << 4);
  int r1 = o1 >> 7, c1 = (o1 & 127) ^ ((r1 & 7) << 4);
  int d0 = c0 >> 1, d1 = c1 >> 1;  // dim/key offset within 64-wide tile
  // stage Q (uniform LDS base per wave; HW adds lane*16)
  gload16(Qg + qoff + (long)r0 * Dc + d0, &Qs[w * 512]);
  gload16(Qg + qoff + (long)r1 * Dc + d1, &Qs[2048 + w * 512]);
  int kb0 = WINDOWED ? (i0 >= 64 ? i0 - 64 : 0) : 0;
  int nt = WINDOWED ? ((i0 - kb0) >> 6) + 1 : (nkv >> 6);
  auto stage = [&](int buf, int kbase) {
    gload16(Kg + koff + (long)(kbase + r0) * Dc + d0, &Ks[buf][w * 512]);
    gload16(Kg + koff + (long)(kbase + r1) * Dc + d1, &Ks[buf][2048 + w * 512]);
    gload16(Vtg + vtoff + (long)r0 * nkv + kbase + d0, &Vs[buf][w * 512]);
    gload16(Vtg + vtoff + (long)r1 * nkv + kbase + d1, &Vs[buf][2048 + w * 512]);
  };
  stage(0, kb0);
  __syncthreads();
  // hoist Q fragments
  bf16x8 bq[2];
#pragma unroll
  for (int ks = 0; ks < 2; ks++) {
    int rq = w * 16 + lr, cb = ks * 64 + lg * 16;
    bq[ks] = *(const bf16x8*)&Qs[((rq << 7) + (cb ^ ((rq & 7) << 4))) >> 1];
  }
  float mrun = -1e30f, lrun = 0.f;
  f32x4 oa[4] = {};
  float slope = WINDOWED ? exp2f(-0.5f * (float)(h + 1)) : 0.0f;
  int qabs = i0 + w * 16 + lr;
  for (int tch = 0; tch < nt; tch++) {
    int cur = tch & 1;
    if (tch + 1 < nt) stage(cur ^ 1, kb0 + (tch + 1) * 64);
    int kbase = kb0 + tch * 64;
    // swapped QK^T: St[k][q], lane holds k = m*16+lg*4+rr, q = lr
    f32x4 st[4] = {};
#pragma unroll
    for (int ks = 0; ks < 2; ks++) {
#pragma unroll
      for (int m = 0; m < 4; m++) {
        int rk = m * 16 + lr, cb = ks * 64 + lg * 16;
        bf16x8 ka = *(const bf16x8*)&Ks[cur][((rk << 7) + (cb ^ ((rk & 7) << 4))) >> 1];
        st[m] = __builtin_amdgcn_mfma_f32_16x16x32_bf16(ka, bq[ks], st[m], 0, 0, 0);
      }
    }
    // softmax: lane-local over 16 k's + 2 shfl across lg groups
    float sc[4][4];
    float mx = mrun;
#pragma unroll
    for (int m = 0; m < 4; m++)
#pragma unroll
      for (int rr = 0; rr < 4; rr++) {
        int kab = kbase + m * 16 + lg * 4 + rr;
        float v = st[m][rr] * 0.125f;
        if (WINDOWED) {
          v += slope * (float)(kab - qabs);
          bool valid = (kab <= qabs) && (qabs - kab < 64);
          v = valid ? v : -3.0e38f;
        }
        sc[m][rr] = v;
        mx = fmaxf(mx, v);
      }
    mx = fmaxf(mx, __shfl_xor(mx, 16));
    mx = fmaxf(mx, __shfl_xor(mx, 32));
    float corr = __expf(mrun - mx);
    mrun = mx;
    float ps = 0.f;
#pragma unroll
    for (int m = 0; m < 4; m++) {
#pragma unroll
      for (int hh = 0; hh < 2; hh++) {
        float p0 = __expf(sc[m][2 * hh] - mx);
        float p1 = __expf(sc[m][2 * hh + 1] - mx);
        ps += p0 + p1;
        bf16x2 pw; pw[0] = (bf16)p0; pw[1] = (bf16)p1;
        *(bf16x2*)&Pl[w][lr * 72 + m * 16 + lg * 4 + 2 * hh] = pw;
      }
    }
    lrun = lrun * corr + ps;
    // rescale O accumulator (rows q = lg*4+rr; corr lives on lane lr=q)
    float cq[4];
#pragma unroll
    for (int rr = 0; rr < 4; rr++) cq[rr] = __shfl(corr, lg * 4 + rr);
#pragma unroll
    for (int jd = 0; jd < 4; jd++) {
      oa[jd][0] *= cq[0]; oa[jd][1] *= cq[1];
      oa[jd][2] *= cq[2]; oa[jd][3] *= cq[3];
    }
    // PV: A = P rows (q=lr), B = Vt rows (d)
#pragma unroll
    for (int ks = 0; ks < 2; ks++) {
      bf16x8 pa = *(const bf16x8*)&Pl[w][lr * 72 + ks * 32 + lg * 8];
#pragma unroll
      for (int jd = 0; jd < 4; jd++) {
        int rv = jd * 16 + lr, cb = ks * 64 + lg * 16;
        bf16x8 vf = *(const bf16x8*)&Vs[cur][((rv << 7) + (cb ^ ((rv & 7) << 4))) >> 1];
        oa[jd] = __builtin_amdgcn_mfma_f32_16x16x32_bf16(pa, vf, oa[jd], 0, 0, 0);
      }
    }
    __syncthreads();
  }
  // epilogue: full row-sum across lg groups, normalize, store
  float ls = lrun + __shfl_xor(lrun, 16);
  ls += __shfl_xor(ls, 32);
  float inv = 1.0f / ls;
  float iq[4];
#pragma unroll
  for (int rr = 0; rr < 4; rr++) iq[rr] = __shfl(inv, lg * 4 + rr);
#pragma unroll
  for (int rr = 0; rr < 4; rr++) {
    int qo = i0 + w * 16 + lg * 4 + rr;
#pragma unroll
    for (int jd = 0; jd < 4; jd++)
      Og[((long)b * Lc + qo) * Dc + h * DHc + jd * 16 + lr] =
          (bf16)(oa[jd][rr] * iq[rr]);
  }
}

// ---------------- LayerNorm over D=1024; fp32 out + optional bf16 copy ------
__global__ __launch_bounds__(256) void k_layernorm(const float* __restrict__ in,
                                                   const float* __restrict__ g,
                                                   const float* __restrict__ bb,
                                                   float* __restrict__ outF,
                                                   bf16* __restrict__ outB) {
  long row = blockIdx.x;
  const float* p = in + row * Dc;
  int t = threadIdx.x; int lane = t & 63; int wid = t >> 6;
  __shared__ float red[8];
  f32x4 v = *(const f32x4*)(p + t * 4);
  float s = v[0] + v[1] + v[2] + v[3];
  float s2 = v[0] * v[0] + v[1] * v[1] + v[2] * v[2] + v[3] * v[3];
#pragma unroll
  for (int off = 1; off < 64; off <<= 1) {
    s += __shfl_xor(s, off);
    s2 += __shfl_xor(s2, off);
  }
  if (lane == 0) { red[wid] = s; red[4 + wid] = s2; }
  __syncthreads();
  s = red[0] + red[1] + red[2] + red[3];
  s2 = red[4] + red[5] + red[6] + red[7];
  float mu = s * (1.0f / Dc);
  float var = s2 * (1.0f / Dc) - mu * mu;
  float rs = rsqrtf(var + 1e-5f);
#pragma unroll
  for (int e = 0; e < 4; e++) {
    int c = t * 4 + e;
    float y = (v[e] - mu) * rs * g[c] + bb[c];
    outF[row * Dc + c] = y;
    if (outB) outB[row * Dc + c] = (bf16)y;
  }
}

extern "C" void kernel_launch(void* const* d_in, const int* in_sizes, int n_in,
                              void* d_out, int out_size, void* d_ws,
                              size_t ws_size, hipStream_t stream) {
  (void)in_sizes; (void)n_in; (void)out_size; (void)ws_size;
  const float* x = (const float*)d_in[0];
  const float* mem = (const float*)d_in[1];
  const float* swq = (const float*)d_in[2];
  const float* swk = (const float*)d_in[3];
  const float* swv = (const float*)d_in[4];
  const float* swo = (const float*)d_in[5];
  const float* sbq = (const float*)d_in[6];
  const float* sbk = (const float*)d_in[7];
  const float* sbv = (const float*)d_in[8];
  const float* sbo = (const float*)d_in[9];
  const float* cwq = (const float*)d_in[10];
  const float* cwk = (const float*)d_in[11];
  const float* cwv = (const float*)d_in[12];
  const float* cwo = (const float*)d_in[13];
  const float* cbq = (const float*)d_in[14];
  const float* cbk = (const float*)d_in[15];
  const float* cbv = (const float*)d_in[16];
  const float* cbo = (const float*)d_in[17];
  const float* w1 = (const float*)d_in[18];
  const float* b1 = (const float*)d_in[19];
  const float* w2 = (const float*)d_in[20];
  const float* b2 = (const float*)d_in[21];
  const float* g1 = (const float*)d_in[22];
  const float* g2 = (const float*)d_in[23];
  const float* g3 = (const float*)d_in[24];
  const float* be1 = (const float*)d_in[25];
  const float* be2 = (const float*)d_in[26];
  const float* be3 = (const float*)d_in[27];
  float* out = (float*)d_out;

  char* ws = (char*)d_ws;
  size_t off = 0;
  auto alloc = [&](size_t bytes) -> char* {
    char* p = ws + off;
    off = (off + bytes + 255) & ~(size_t)255;
    return p;
  };

  const long BL = (long)Bc * Lc;  // 4096
  const long BM = (long)Bc * Mc;  // 4096
  const long DD = (long)Dc * Dc;

  bf16* wT0 = (bf16*)alloc((size_t)8 * DD * 2);
  bf16* w1T = (bf16*)alloc((size_t)FFc * Dc * 2);
  bf16* w2T = (bf16*)alloc((size_t)Dc * FFc * 2);
  bf16* xb = (bf16*)alloc((size_t)BL * Dc * 2);
  bf16* memb = (bf16*)alloc((size_t)BM * Dc * 2);
  bf16* x1b = (bf16*)alloc((size_t)BL * Dc * 2);
  bf16* x2b = (bf16*)alloc((size_t)BL * Dc * 2);
  bf16* qb = (bf16*)alloc((size_t)BL * Dc * 2);  // qb,kb,vb contiguous
  bf16* kb = (bf16*)alloc((size_t)BM * Dc * 2);
  bf16* vb = (bf16*)alloc((size_t)BM * Dc * 2);
  bf16* ob = (bf16*)alloc((size_t)BL * Dc * 2);
  bf16* vtS = (bf16*)alloc((size_t)Bc * Hc * DHc * Lc * 2);
  bf16* vtC = (bf16*)alloc((size_t)Bc * Hc * DHc * Mc * 2);
  float* rbuf = (float*)alloc((size_t)BL * Dc * 4);
  float* x1f = (float*)alloc((size_t)BL * Dc * 4);
  float* x2f = (float*)alloc((size_t)BL * Dc * 4);
  bf16* ffh = (bf16*)alloc((size_t)BL * FFc * 2);

  // ---- prep: weights -> bf16 [N,K]
  const float* wsrc[8] = {swq, swk, swv, swo, cwq, cwk, cwv, cwo};
  for (int i = 0; i < 8; i++)
    k_transpose_w<<<dim3(Dc / 64, Dc / 64), 256, 0, stream>>>(wsrc[i], wT0 + i * DD, Dc, Dc);
  k_transpose_w<<<dim3(FFc / 64, Dc / 64), 256, 0, stream>>>(w1, w1T, Dc, FFc);
  k_transpose_w<<<dim3(Dc / 64, FFc / 64), 256, 0, stream>>>(w2, w2T, FFc, Dc);
  k_f2b<<<dim3((unsigned)(BL * Dc / 4 / 256)), 256, 0, stream>>>(x, xb, BL * Dc / 4);
  k_f2b<<<dim3((unsigned)(BM * Dc / 4 / 256)), 256, 0, stream>>>(mem, memb, BM * Dc / 4);

  // ---- self-attn QKV projections (z-batched: q,k,v)
  k_gemm128<<<dim3(Dc / 128, BL / 128, 3), 256, 0, stream>>>(
      xb, Dc, wT0, DD, nullptr, qb, Dc, BL * Dc, sbq, sbk, sbv, nullptr, Dc, 0);
  k_transpose_v<<<dim3(Lc / 64, Bc * Hc), 256, 0, stream>>>(vb, vtS, Lc);
  // ---- windowed causal self-attn + ALiBi
  k_flash<1><<<dim3(Lc / 64, Bc * Hc), 256, 0, stream>>>(qb, kb, vtS, ob, Lc);
  // ---- self O-proj + residual(x)
  k_gemm128<<<dim3(Dc / 128, BL / 128, 1), 256, 0, stream>>>(
      ob, Dc, wT0 + 3 * DD, 0, rbuf, nullptr, Dc, 0, sbo, sbo, sbo, x, Dc, 0);
  k_layernorm<<<dim3((unsigned)BL), 256, 0, stream>>>(rbuf, g1, be1, x1f, x1b);

  // ---- cross-attn projections
  k_gemm128<<<dim3(Dc / 128, BL / 128, 1), 256, 0, stream>>>(
      x1b, Dc, wT0 + 4 * DD, 0, nullptr, qb, Dc, 0, cbq, cbq, cbq, nullptr, Dc, 0);
  k_gemm128<<<dim3(Dc / 128, BM / 128, 2), 256, 0, stream>>>(
      memb, Dc, wT0 + 5 * DD, DD, nullptr, kb, Dc, BM * Dc, cbk, cbv, cbv, nullptr, Dc, 0);
  k_transpose_v<<<dim3(Mc / 64, Bc * Hc), 256, 0, stream>>>(vb, vtC, Mc);
  // ---- fused flash cross-attention
  k_flash<0><<<dim3(Lc / 64, Bc * Hc), 256, 0, stream>>>(qb, kb, vtC, ob, Mc);
  // ---- cross O-proj + residual(x1)
  k_gemm128<<<dim3(Dc / 128, BL / 128, 1), 256, 0, stream>>>(
      ob, Dc, wT0 + 7 * DD, 0, rbuf, nullptr, Dc, 0, cbo, cbo, cbo, x1f, Dc, 0);
  k_layernorm<<<dim3((unsigned)BL), 256, 0, stream>>>(rbuf, g2, be2, x2f, x2b);

  // ---- FFN
  k_gemm128<<<dim3(FFc / 128, BL / 128, 1), 256, 0, stream>>>(
      x2b, Dc, w1T, 0, nullptr, ffh, FFc, 0, b1, b1, b1, nullptr, Dc, 1);
  k_gemm128<<<dim3(Dc / 128, BL / 128, 1), 256, 0, stream>>>(
      ffh, FFc, w2T, 0, rbuf, nullptr, Dc, 0, b2, b2, b2, x2f, FFc, 0);
  k_layernorm<<<dim3((unsigned)BL), 256, 0, stream>>>(rbuf, g3, be3, out, nullptr);
}

// Round 4
// 479.430 us; speedup vs baseline: 2.5856x; 1.1685x over previous
//
#include <hip/hip_runtime.h>
#include <hip/hip_bf16.h>
#include <math.h>

#define Bc 2
#define Lc 2048
#define Mc 2048
#define Dc 1024
#define Hc 16
#define FFc 4096
#define DHc 64

typedef __bf16 bf16;
typedef float f32x4 __attribute__((ext_vector_type(4)));
typedef __bf16 bf16x8 __attribute__((ext_vector_type(8)));
typedef __bf16 bf16x4 __attribute__((ext_vector_type(4)));
typedef __bf16 bf16x2 __attribute__((ext_vector_type(2)));

__device__ inline void gload16(const bf16* g, const bf16* lds_base) {
  __builtin_amdgcn_global_load_lds(
      (const __attribute__((address_space(1))) void*)g,
      (__attribute__((address_space(3))) void*)lds_base, 16, 0, 0);
}

// ---------------- fp32 -> bf16 convert (vectorized) ----------------
__global__ __launch_bounds__(256) void k_f2b(const float* __restrict__ in,
                                             bf16* __restrict__ out, long n4) {
  long i = (long)blockIdx.x * 256 + threadIdx.x;
  if (i >= n4) return;
  f32x4 v = *(const f32x4*)(in + i * 4);
  bf16x4 o;
  o[0] = (bf16)v[0]; o[1] = (bf16)v[1]; o[2] = (bf16)v[2]; o[3] = (bf16)v[3];
  *(bf16x4*)(out + i * 4) = o;
}

// ---------------- weight transpose+convert: out[n*K+k] = bf16(in[k*N+n]) ----
__global__ __launch_bounds__(256) void k_transpose_w(const float* __restrict__ in,
                                                     bf16* __restrict__ out,
                                                     int K, int N) {
  __shared__ float tile[64][65];
  int n0 = blockIdx.x * 64, k0 = blockIdx.y * 64;
  int t = threadIdx.x;
  int tr = t >> 4, tc = (t & 15) * 4;
#pragma unroll
  for (int p = 0; p < 4; p++) {
    int r = p * 16 + tr;
    f32x4 v = *(const f32x4*)(in + (long)(k0 + r) * N + n0 + tc);
    tile[r][tc] = v[0]; tile[r][tc + 1] = v[1];
    tile[r][tc + 2] = v[2]; tile[r][tc + 3] = v[3];
  }
  __syncthreads();
#pragma unroll
  for (int p = 0; p < 4; p++) {
    int rn = p * 16 + tr;
    bf16x4 o;
    o[0] = (bf16)tile[tc + 0][rn]; o[1] = (bf16)tile[tc + 1][rn];
    o[2] = (bf16)tile[tc + 2][rn]; o[3] = (bf16)tile[tc + 3][rn];
    *(bf16x4*)(out + (long)(n0 + rn) * K + k0 + tc) = o;
  }
}

// ---- V transpose: vt[(b*H+h)*DH+d][j] = vb[b][j][h*DH+d], j in [0,N) ------
__global__ __launch_bounds__(256) void k_transpose_v(const bf16* __restrict__ vb,
                                                     bf16* __restrict__ vt, int N) {
  __shared__ bf16 tile[64][72];
  int j0 = blockIdx.x * 64;
  int bh = blockIdx.y; int b = bh >> 4; int h = bh & 15;
  int t = threadIdx.x;
#pragma unroll
  for (int c = 0; c < 2; c++) {
    int id = t + c * 256;
    int r = id >> 3, c8 = (id & 7) * 8;
    *(bf16x8*)&tile[r][c8] =
        *(const bf16x8*)(vb + ((long)(b * N + j0 + r)) * Dc + h * DHc + c8);
  }
  __syncthreads();
#pragma unroll
  for (int c = 0; c < 2; c++) {
    int id = t + c * 256;
    int d = id >> 3, j8 = (id & 7) * 8;
    bf16x8 o;
#pragma unroll
    for (int e = 0; e < 8; e++) o[e] = tile[j8 + e][d];
    *(bf16x8*)(vt + ((long)bh * DHc + d) * N + j0 + j8) = o;
  }
}

// ---------------- 128x128 MFMA GEMM (m97 structure), BK=64 -----------------
// per-z A pointer, B slab, bias; C = act(A.Bt^T + bias) -> bf16
__global__ __launch_bounds__(256) void k_gemm128(
    const bf16* __restrict__ A0, const bf16* __restrict__ A1,
    const bf16* __restrict__ A2, long lda,
    const bf16* __restrict__ B0, long bstride,
    bf16* __restrict__ outB, long ldc, long cstride,
    const float* __restrict__ bias0, const float* __restrict__ bias1,
    const float* __restrict__ bias2, int Kdim, int act) {
  __shared__ __align__(16) bf16 As[128 * 64];
  __shared__ __align__(16) bf16 Bs[128 * 64];
  int z = blockIdx.z;
  const bf16* A = (z == 0) ? A0 : ((z == 1) ? A1 : A2);
  const bf16* Bt = B0 + (long)z * bstride;
  const float* bias = (z == 0) ? bias0 : ((z == 1) ? bias1 : bias2);
  long cbase = (long)z * cstride;
  int bm = blockIdx.y * 128, bn = blockIdx.x * 128;
  int t = threadIdx.x, w = t >> 6, lane = t & 63;
  int wm = w >> 1, wn = w & 1;
  int lr = lane & 15, lg = lane >> 4;
  int srow = lane >> 3, scol = (lane & 7) * 8;
  f32x4 acc[4][4] = {};
  int nk = Kdim >> 6;
  for (int kt = 0; kt < nk; ++kt) {
    long k0 = (long)kt * 64;
#pragma unroll
    for (int i = 0; i < 4; i++) {
      int row = (i * 4 + w) * 8 + srow;
      gload16(A + (long)(bm + row) * lda + k0 + scol, &As[(i * 4 + w) * 512]);
      gload16(Bt + (long)(bn + row) * Kdim + k0 + scol, &Bs[(i * 4 + w) * 512]);
    }
    __syncthreads();
#pragma unroll
    for (int kk = 0; kk < 2; kk++) {
      bf16x8 af[4], bfr[4];
#pragma unroll
      for (int m = 0; m < 4; m++)
        af[m] = *(const bf16x8*)&As[(wm * 64 + m * 16 + lr) * 64 + kk * 32 + lg * 8];
#pragma unroll
      for (int n = 0; n < 4; n++)
        bfr[n] = *(const bf16x8*)&Bs[(wn * 64 + n * 16 + lr) * 64 + kk * 32 + lg * 8];
#pragma unroll
      for (int m = 0; m < 4; m++)
#pragma unroll
        for (int n = 0; n < 4; n++)
          acc[m][n] = __builtin_amdgcn_mfma_f32_16x16x32_bf16(af[m], bfr[n],
                                                              acc[m][n], 0, 0, 0);
    }
    __syncthreads();
  }
#pragma unroll
  for (int n = 0; n < 4; n++) {
    int cg = bn + wn * 64 + n * 16 + lr;
    float bv = bias ? bias[cg] : 0.0f;
#pragma unroll
    for (int m = 0; m < 4; m++) {
#pragma unroll
      for (int rr = 0; rr < 4; rr++) {
        int rg = bm + wm * 64 + m * 16 + lg * 4 + rr;
        float v = acc[m][n][rr] + bv;
        if (act == 1) v = 0.5f * v * (1.0f + erff(v * 0.70710678f));
        outB[cbase + (long)rg * ldc + cg] = (bf16)v;
      }
    }
  }
}

// ---------------- split-K GEMM: psum[z] = A[:, zKc:(z+1)Kc] x Bt^T ----------
__global__ __launch_bounds__(256) void k_gemmsk(
    const bf16* __restrict__ A, long lda,
    const bf16* __restrict__ Bt, int Kfull,
    float* __restrict__ psum, long slab, int Kchunk, int ldc) {
  __shared__ __align__(16) bf16 As[128 * 64];
  __shared__ __align__(16) bf16 Bs[128 * 64];
  int z = blockIdx.z;
  int bm = blockIdx.y * 128, bn = blockIdx.x * 128;
  int t = threadIdx.x, w = t >> 6, lane = t & 63;
  int wm = w >> 1, wn = w & 1;
  int lr = lane & 15, lg = lane >> 4;
  int srow = lane >> 3, scol = (lane & 7) * 8;
  f32x4 acc[4][4] = {};
  int nk = Kchunk >> 6;
  long kstart = (long)z * Kchunk;
  for (int kt = 0; kt < nk; ++kt) {
    long k0 = kstart + (long)kt * 64;
#pragma unroll
    for (int i = 0; i < 4; i++) {
      int row = (i * 4 + w) * 8 + srow;
      gload16(A + (long)(bm + row) * lda + k0 + scol, &As[(i * 4 + w) * 512]);
      gload16(Bt + (long)(bn + row) * Kfull + k0 + scol, &Bs[(i * 4 + w) * 512]);
    }
    __syncthreads();
#pragma unroll
    for (int kk = 0; kk < 2; kk++) {
      bf16x8 af[4], bfr[4];
#pragma unroll
      for (int m = 0; m < 4; m++)
        af[m] = *(const bf16x8*)&As[(wm * 64 + m * 16 + lr) * 64 + kk * 32 + lg * 8];
#pragma unroll
      for (int n = 0; n < 4; n++)
        bfr[n] = *(const bf16x8*)&Bs[(wn * 64 + n * 16 + lr) * 64 + kk * 32 + lg * 8];
#pragma unroll
      for (int m = 0; m < 4; m++)
#pragma unroll
        for (int n = 0; n < 4; n++)
          acc[m][n] = __builtin_amdgcn_mfma_f32_16x16x32_bf16(af[m], bfr[n],
                                                              acc[m][n], 0, 0, 0);
    }
    __syncthreads();
  }
  float* po = psum + (long)z * slab;
#pragma unroll
  for (int n = 0; n < 4; n++) {
    int cg = bn + wn * 64 + n * 16 + lr;
#pragma unroll
    for (int m = 0; m < 4; m++) {
#pragma unroll
      for (int rr = 0; rr < 4; rr++) {
        int rg = bm + wm * 64 + m * 16 + lg * 4 + rr;
        po[(long)rg * ldc + cg] = acc[m][n][rr];
      }
    }
  }
}

// ---------------- flash attention v2 ---------------------------------------
template <int WINDOWED>
__global__ __launch_bounds__(256) void k_flash(const bf16* __restrict__ Qg,
                                               const bf16* __restrict__ Kg,
                                               const bf16* __restrict__ Vtg,
                                               bf16* __restrict__ Og, int nkv) {
  __shared__ __align__(16) bf16 Qs[64 * 64];
  __shared__ __align__(16) bf16 Ks[2][64 * 64];
  __shared__ __align__(16) bf16 Vs[2][64 * 64];
  __shared__ __align__(16) bf16 Pl[4][16 * 72];
  int i0 = blockIdx.x * 64;
  int bh = blockIdx.y; int b = bh >> 4, h = bh & 15;
  int t = threadIdx.x, w = t >> 6, lane = t & 63;
  int lr = lane & 15, lg = lane >> 4;
  long qoff = ((long)b * Lc + i0) * Dc + h * DHc;
  long koff = ((long)b * nkv) * Dc + h * DHc;
  long vtoff = (long)bh * DHc * nkv;
  int o0 = w * 1024 + (lane << 4), o1 = o0 + 4096;
  int r0 = o0 >> 7, c0 = (o0 & 127) ^ ((r0 & 7) << 4);
  int r1 = o1 >> 7, c1 = (o1 & 127) ^ ((r1 & 7) << 4);
  int d0 = c0 >> 1, d1 = c1 >> 1;
  gload16(Qg + qoff + (long)r0 * Dc + d0, &Qs[w * 512]);
  gload16(Qg + qoff + (long)r1 * Dc + d1, &Qs[2048 + w * 512]);
  int kb0 = WINDOWED ? (i0 >= 64 ? i0 - 64 : 0) : 0;
  int nt = WINDOWED ? ((i0 - kb0) >> 6) + 1 : (nkv >> 6);
  auto stage = [&](int buf, int kbase) {
    gload16(Kg + koff + (long)(kbase + r0) * Dc + d0, &Ks[buf][w * 512]);
    gload16(Kg + koff + (long)(kbase + r1) * Dc + d1, &Ks[buf][2048 + w * 512]);
    gload16(Vtg + vtoff + (long)r0 * nkv + kbase + d0, &Vs[buf][w * 512]);
    gload16(Vtg + vtoff + (long)r1 * nkv + kbase + d1, &Vs[buf][2048 + w * 512]);
  };
  stage(0, kb0);
  __syncthreads();
  bf16x8 bq[2];
#pragma unroll
  for (int ks = 0; ks < 2; ks++) {
    int rq = w * 16 + lr, cb = ks * 64 + lg * 16;
    bq[ks] = *(const bf16x8*)&Qs[((rq << 7) + (cb ^ ((rq & 7) << 4))) >> 1];
  }
  float mrun = -1e30f, lrun = 0.f;
  f32x4 oa[4] = {};
  float slope = WINDOWED ? exp2f(-0.5f * (float)(h + 1)) : 0.0f;
  int qabs = i0 + w * 16 + lr;
  for (int tch = 0; tch < nt; tch++) {
    int cur = tch & 1;
    if (tch + 1 < nt) stage(cur ^ 1, kb0 + (tch + 1) * 64);
    int kbase = kb0 + tch * 64;
    f32x4 st[4] = {};
#pragma unroll
    for (int ks = 0; ks < 2; ks++) {
#pragma unroll
      for (int m = 0; m < 4; m++) {
        int rk = m * 16 + lr, cb = ks * 64 + lg * 16;
        bf16x8 ka = *(const bf16x8*)&Ks[cur][((rk << 7) + (cb ^ ((rk & 7) << 4))) >> 1];
        st[m] = __builtin_amdgcn_mfma_f32_16x16x32_bf16(ka, bq[ks], st[m], 0, 0, 0);
      }
    }
    float sc[4][4];
    float mx = mrun;
#pragma unroll
    for (int m = 0; m < 4; m++)
#pragma unroll
      for (int rr = 0; rr < 4; rr++) {
        int kab = kbase + m * 16 + lg * 4 + rr;
        float v = st[m][rr] * 0.125f;
        if (WINDOWED) {
          v += slope * (float)(kab - qabs);
          bool valid = (kab <= qabs) && (qabs - kab < 64);
          v = valid ? v : -3.0e38f;
        }
        sc[m][rr] = v;
        mx = fmaxf(mx, v);
      }
    mx = fmaxf(mx, __shfl_xor(mx, 16));
    mx = fmaxf(mx, __shfl_xor(mx, 32));
    float corr = __expf(mrun - mx);
    mrun = mx;
    float ps = 0.f;
#pragma unroll
    for (int m = 0; m < 4; m++) {
#pragma unroll
      for (int hh = 0; hh < 2; hh++) {
        float p0 = __expf(sc[m][2 * hh] - mx);
        float p1 = __expf(sc[m][2 * hh + 1] - mx);
        ps += p0 + p1;
        bf16x2 pw; pw[0] = (bf16)p0; pw[1] = (bf16)p1;
        *(bf16x2*)&Pl[w][lr * 72 + m * 16 + lg * 4 + 2 * hh] = pw;
      }
    }
    lrun = lrun * corr + ps;
    float cq[4];
#pragma unroll
    for (int rr = 0; rr < 4; rr++) cq[rr] = __shfl(corr, lg * 4 + rr);
#pragma unroll
    for (int jd = 0; jd < 4; jd++) {
      oa[jd][0] *= cq[0]; oa[jd][1] *= cq[1];
      oa[jd][2] *= cq[2]; oa[jd][3] *= cq[3];
    }
#pragma unroll
    for (int ks = 0; ks < 2; ks++) {
      bf16x8 pa = *(const bf16x8*)&Pl[w][lr * 72 + ks * 32 + lg * 8];
#pragma unroll
      for (int jd = 0; jd < 4; jd++) {
        int rv = jd * 16 + lr, cb = ks * 64 + lg * 16;
        bf16x8 vf = *(const bf16x8*)&Vs[cur][((rv << 7) + (cb ^ ((rv & 7) << 4))) >> 1];
        oa[jd] = __builtin_amdgcn_mfma_f32_16x16x32_bf16(pa, vf, oa[jd], 0, 0, 0);
      }
    }
    __syncthreads();
  }
  float ls = lrun + __shfl_xor(lrun, 16);
  ls += __shfl_xor(ls, 32);
  float inv = 1.0f / ls;
  float iq[4];
#pragma unroll
  for (int rr = 0; rr < 4; rr++) iq[rr] = __shfl(inv, lg * 4 + rr);
#pragma unroll
  for (int rr = 0; rr < 4; rr++) {
    int qo = i0 + w * 16 + lg * 4 + rr;
#pragma unroll
    for (int jd = 0; jd < 4; jd++)
      Og[((long)b * Lc + qo) * Dc + h * DHc + jd * 16 + lr] =
          (bf16)(oa[jd][rr] * iq[rr]);
  }
}

// ---- fused: sum NS split-K slabs + bias + residual, then LayerNorm ---------
template <int NS>
__global__ __launch_bounds__(256) void k_lnred(const float* __restrict__ psum,
                                               long slab,
                                               const float* __restrict__ bias,
                                               const float* __restrict__ addsrc,
                                               const float* __restrict__ g,
                                               const float* __restrict__ bb,
                                               float* __restrict__ outF,
                                               bf16* __restrict__ outB) {
  long row = blockIdx.x;
  int t = threadIdx.x; int lane = t & 63; int wid = t >> 6;
  __shared__ float red[8];
  f32x4 v = *(const f32x4*)(psum + row * Dc + t * 4);
#pragma unroll
  for (int s = 1; s < NS; s++) {
    f32x4 u = *(const f32x4*)(psum + s * slab + row * Dc + t * 4);
    v[0] += u[0]; v[1] += u[1]; v[2] += u[2]; v[3] += u[3];
  }
  f32x4 bv = *(const f32x4*)(bias + t * 4);
  f32x4 av = *(const f32x4*)(addsrc + row * Dc + t * 4);
  v[0] += bv[0] + av[0]; v[1] += bv[1] + av[1];
  v[2] += bv[2] + av[2]; v[3] += bv[3] + av[3];
  float s = v[0] + v[1] + v[2] + v[3];
  float s2 = v[0] * v[0] + v[1] * v[1] + v[2] * v[2] + v[3] * v[3];
#pragma unroll
  for (int off = 1; off < 64; off <<= 1) {
    s += __shfl_xor(s, off);
    s2 += __shfl_xor(s2, off);
  }
  if (lane == 0) { red[wid] = s; red[4 + wid] = s2; }
  __syncthreads();
  s = red[0] + red[1] + red[2] + red[3];
  s2 = red[4] + red[5] + red[6] + red[7];
  float mu = s * (1.0f / Dc);
  float var = s2 * (1.0f / Dc) - mu * mu;
  float rs = rsqrtf(var + 1e-5f);
#pragma unroll
  for (int e = 0; e < 4; e++) {
    int c = t * 4 + e;
    float y = (v[e] - mu) * rs * g[c] + bb[c];
    if (outF) outF[row * Dc + c] = y;
    if (outB) outB[row * Dc + c] = (bf16)y;
  }
}

extern "C" void kernel_launch(void* const* d_in, const int* in_sizes, int n_in,
                              void* d_out, int out_size, void* d_ws,
                              size_t ws_size, hipStream_t stream) {
  (void)in_sizes; (void)n_in; (void)out_size; (void)ws_size;
  const float* x = (const float*)d_in[0];
  const float* mem = (const float*)d_in[1];
  const float* swq = (const float*)d_in[2];
  const float* swk = (const float*)d_in[3];
  const float* swv = (const float*)d_in[4];
  const float* swo = (const float*)d_in[5];
  const float* sbq = (const float*)d_in[6];
  const float* sbk = (const float*)d_in[7];
  const float* sbv = (const float*)d_in[8];
  const float* sbo = (const float*)d_in[9];
  const float* cwq = (const float*)d_in[10];
  const float* cwk = (const float*)d_in[11];
  const float* cwv = (const float*)d_in[12];
  const float* cwo = (const float*)d_in[13];
  const float* cbq = (const float*)d_in[14];
  const float* cbk = (const float*)d_in[15];
  const float* cbv = (const float*)d_in[16];
  const float* cbo = (const float*)d_in[17];
  const float* w1 = (const float*)d_in[18];
  const float* b1 = (const float*)d_in[19];
  const float* w2 = (const float*)d_in[20];
  const float* b2 = (const float*)d_in[21];
  const float* g1 = (const float*)d_in[22];
  const float* g2 = (const float*)d_in[23];
  const float* g3 = (const float*)d_in[24];
  const float* be1 = (const float*)d_in[25];
  const float* be2 = (const float*)d_in[26];
  const float* be3 = (const float*)d_in[27];
  float* out = (float*)d_out;

  char* ws = (char*)d_ws;
  size_t off = 0;
  auto alloc = [&](size_t bytes) -> char* {
    char* p = ws + off;
    off = (off + bytes + 255) & ~(size_t)255;
    return p;
  };

  const long BL = (long)Bc * Lc;  // 4096
  const long BM = (long)Bc * Mc;  // 4096
  const long DD = (long)Dc * Dc;
  const long SL = BL * Dc;  // one psum slab (elements)

  bf16* wT0 = (bf16*)alloc((size_t)8 * DD * 2);
  bf16* w1T = (bf16*)alloc((size_t)FFc * Dc * 2);
  bf16* w2T = (bf16*)alloc((size_t)Dc * FFc * 2);
  bf16* xb = (bf16*)alloc((size_t)BL * Dc * 2);
  bf16* memb = (bf16*)alloc((size_t)BM * Dc * 2);
  bf16* x1b = (bf16*)alloc((size_t)BL * Dc * 2);
  bf16* x2b = (bf16*)alloc((size_t)BL * Dc * 2);
  bf16* qb = (bf16*)alloc((size_t)BL * Dc * 2);  // qb,kb,vb contiguous
  bf16* kb = (bf16*)alloc((size_t)BM * Dc * 2);
  bf16* vb = (bf16*)alloc((size_t)BM * Dc * 2);
  bf16* ob = (bf16*)alloc((size_t)BL * Dc * 2);
  bf16* vtS = (bf16*)alloc((size_t)Bc * Hc * DHc * Lc * 2);
  bf16* vtC = (bf16*)alloc((size_t)Bc * Hc * DHc * Mc * 2);
  float* x1f = (float*)alloc((size_t)BL * Dc * 4);
  float* x2f = (float*)alloc((size_t)BL * Dc * 4);
  bf16* ffh = (bf16*)alloc((size_t)BL * FFc * 2);
  float* psum = (float*)alloc((size_t)4 * SL * 4);  // 4 split-K slabs

  // ---- prep: weights -> bf16 [N,K]
  const float* wsrc[8] = {swq, swk, swv, swo, cwq, cwk, cwv, cwo};
  for (int i = 0; i < 8; i++)
    k_transpose_w<<<dim3(Dc / 64, Dc / 64), 256, 0, stream>>>(wsrc[i], wT0 + i * DD, Dc, Dc);
  k_transpose_w<<<dim3(FFc / 64, Dc / 64), 256, 0, stream>>>(w1, w1T, Dc, FFc);
  k_transpose_w<<<dim3(Dc / 64, FFc / 64), 256, 0, stream>>>(w2, w2T, FFc, Dc);
  k_f2b<<<dim3((unsigned)(BL * Dc / 4 / 256)), 256, 0, stream>>>(x, xb, BL * Dc / 4);
  k_f2b<<<dim3((unsigned)(BM * Dc / 4 / 256)), 256, 0, stream>>>(mem, memb, BM * Dc / 4);

  // ---- self-attn QKV projections (z-batched: q,k,v) -> grid 768, 3/CU
  k_gemm128<<<dim3(Dc / 128, BL / 128, 3), 256, 0, stream>>>(
      xb, xb, xb, Dc, wT0, DD, qb, Dc, SL, sbq, sbk, sbv, Dc, 0);
  k_transpose_v<<<dim3(Lc / 64, Bc * Hc), 256, 0, stream>>>(vb, vtS, Lc);
  // ---- windowed causal self-attn + ALiBi
  k_flash<1><<<dim3(Lc / 64, Bc * Hc), 256, 0, stream>>>(qb, kb, vtS, ob, Lc);
  // ---- self O-proj (split-K=2) + fused bias/residual/LN
  k_gemmsk<<<dim3(Dc / 128, BL / 128, 2), 256, 0, stream>>>(
      ob, Dc, wT0 + 3 * DD, Dc, psum, SL, 512, Dc);
  k_lnred<2><<<dim3((unsigned)BL), 256, 0, stream>>>(psum, SL, sbo, x, g1, be1,
                                                     x1f, x1b);

  // ---- cross-attn Q,K,V projections (z-batched) -> grid 768, 3/CU
  k_gemm128<<<dim3(Dc / 128, BM / 128, 3), 256, 0, stream>>>(
      x1b, memb, memb, Dc, wT0 + 4 * DD, DD, qb, Dc, SL, cbq, cbk, cbv, Dc, 0);
  k_transpose_v<<<dim3(Mc / 64, Bc * Hc), 256, 0, stream>>>(vb, vtC, Mc);
  // ---- fused flash cross-attention
  k_flash<0><<<dim3(Lc / 64, Bc * Hc), 256, 0, stream>>>(qb, kb, vtC, ob, Mc);
  // ---- cross O-proj (split-K=2) + fused bias/residual/LN
  k_gemmsk<<<dim3(Dc / 128, BL / 128, 2), 256, 0, stream>>>(
      ob, Dc, wT0 + 7 * DD, Dc, psum, SL, 512, Dc);
  k_lnred<2><<<dim3((unsigned)BL), 256, 0, stream>>>(psum, SL, cbo, x1f, g2, be2,
                                                     x2f, x2b);

  // ---- FFN
  k_gemm128<<<dim3(FFc / 128, BL / 128, 1), 256, 0, stream>>>(
      x2b, x2b, x2b, Dc, w1T, 0, ffh, FFc, 0, b1, b1, b1, Dc, 1);
  // FFN2: split-K=4 -> grid 1024, 4/CU
  k_gemmsk<<<dim3(Dc / 128, BL / 128, 4), 256, 0, stream>>>(
      ffh, FFc, w2T, FFc, psum, SL, 1024, Dc);
  k_lnred<4><<<dim3((unsigned)BL), 256, 0, stream>>>(psum, SL, b2, x2f, g3, be3,
                                                     out, nullptr);
}

// Round 5
// 466.815 us; speedup vs baseline: 2.6555x; 1.0270x over previous
//
#include <hip/hip_runtime.h>
#include <hip/hip_bf16.h>
#include <math.h>

#define Bc 2
#define Lc 2048
#define Mc 2048
#define Dc 1024
#define Hc 16
#define FFc 4096
#define DHc 64

typedef __bf16 bf16;
typedef float f32x4 __attribute__((ext_vector_type(4)));
typedef __bf16 bf16x8 __attribute__((ext_vector_type(8)));
typedef __bf16 bf16x4 __attribute__((ext_vector_type(4)));
typedef __bf16 bf16x2 __attribute__((ext_vector_type(2)));

__device__ inline void gload16(const bf16* g, const bf16* lds_base) {
  __builtin_amdgcn_global_load_lds(
      (const __attribute__((address_space(1))) void*)g,
      (__attribute__((address_space(3))) void*)lds_base, 16, 0, 0);
}

#define WAIT_VM(n) asm volatile("s_waitcnt vmcnt(" #n ")" ::: "memory")
#define WAIT_LGKM0 asm volatile("s_waitcnt lgkmcnt(0)" ::: "memory")
#define RAW_BAR() __builtin_amdgcn_s_barrier()
#define SCHED_FENCE() __builtin_amdgcn_sched_barrier(0)

// ---------------- fp32 -> bf16 convert (vectorized) ----------------
__global__ __launch_bounds__(256) void k_f2b(const float* __restrict__ in,
                                             bf16* __restrict__ out, long n4) {
  long i = (long)blockIdx.x * 256 + threadIdx.x;
  if (i >= n4) return;
  f32x4 v = *(const f32x4*)(in + i * 4);
  bf16x4 o;
  o[0] = (bf16)v[0]; o[1] = (bf16)v[1]; o[2] = (bf16)v[2]; o[3] = (bf16)v[3];
  *(bf16x4*)(out + i * 4) = o;
}

// ---------------- weight transpose+convert: out[n*K+k] = bf16(in[k*N+n]) ----
__global__ __launch_bounds__(256) void k_transpose_w(const float* __restrict__ in,
                                                     bf16* __restrict__ out,
                                                     int K, int N) {
  __shared__ float tile[64][65];
  int n0 = blockIdx.x * 64, k0 = blockIdx.y * 64;
  int t = threadIdx.x;
  int tr = t >> 4, tc = (t & 15) * 4;
#pragma unroll
  for (int p = 0; p < 4; p++) {
    int r = p * 16 + tr;
    f32x4 v = *(const f32x4*)(in + (long)(k0 + r) * N + n0 + tc);
    tile[r][tc] = v[0]; tile[r][tc + 1] = v[1];
    tile[r][tc + 2] = v[2]; tile[r][tc + 3] = v[3];
  }
  __syncthreads();
#pragma unroll
  for (int p = 0; p < 4; p++) {
    int rn = p * 16 + tr;
    bf16x4 o;
    o[0] = (bf16)tile[tc + 0][rn]; o[1] = (bf16)tile[tc + 1][rn];
    o[2] = (bf16)tile[tc + 2][rn]; o[3] = (bf16)tile[tc + 3][rn];
    *(bf16x4*)(out + (long)(n0 + rn) * K + k0 + tc) = o;
  }
}

// ---- V transpose: vt[(b*H+h)*DH+d][j] = vb[b][j][h*DH+d], j in [0,N) ------
__global__ __launch_bounds__(256) void k_transpose_v(const bf16* __restrict__ vb,
                                                     bf16* __restrict__ vt, int N) {
  __shared__ bf16 tile[64][72];
  int j0 = blockIdx.x * 64;
  int bh = blockIdx.y; int b = bh >> 4; int h = bh & 15;
  int t = threadIdx.x;
#pragma unroll
  for (int c = 0; c < 2; c++) {
    int id = t + c * 256;
    int r = id >> 3, c8 = (id & 7) * 8;
    *(bf16x8*)&tile[r][c8] =
        *(const bf16x8*)(vb + ((long)(b * N + j0 + r)) * Dc + h * DHc + c8);
  }
  __syncthreads();
#pragma unroll
  for (int c = 0; c < 2; c++) {
    int id = t + c * 256;
    int d = id >> 3, j8 = (id & 7) * 8;
    bf16x8 o;
#pragma unroll
    for (int e = 0; e < 8; e++) o[e] = tile[j8 + e][d];
    *(bf16x8*)(vt + ((long)bh * DHc + d) * N + j0 + j8) = o;
  }
}

// ------- 128x128 MFMA GEMM, BK=64, 2-deep pipelined LDS dbuf (counted vmcnt)
__global__ __launch_bounds__(256) void k_gemm128(
    const bf16* __restrict__ A0, const bf16* __restrict__ A1,
    const bf16* __restrict__ A2, long lda,
    const bf16* __restrict__ B0, long bstride,
    bf16* __restrict__ outB, long ldc, long cstride,
    const float* __restrict__ bias0, const float* __restrict__ bias1,
    const float* __restrict__ bias2, int Kdim, int act) {
  __shared__ __align__(16) bf16 As[2][128 * 64];
  __shared__ __align__(16) bf16 Bs[2][128 * 64];
  int z = blockIdx.z;
  const bf16* A = (z == 0) ? A0 : ((z == 1) ? A1 : A2);
  const bf16* Bt = B0 + (long)z * bstride;
  const float* bias = (z == 0) ? bias0 : ((z == 1) ? bias1 : bias2);
  long cbase = (long)z * cstride;
  int bm = blockIdx.y * 128, bn = blockIdx.x * 128;
  int t = threadIdx.x, w = t >> 6, lane = t & 63;
  int wm = w >> 1, wn = w & 1;
  int lr = lane & 15, lg = lane >> 4;
  int srow = lane >> 3, scol = (lane & 7) * 8;
  f32x4 acc[4][4] = {};
  int nk = Kdim >> 6;
  auto stage = [&](int buf, int kt2) {
    long k0 = (long)kt2 * 64;
#pragma unroll
    for (int i = 0; i < 4; i++) {
      int row = (i * 4 + w) * 8 + srow;
      gload16(A + (long)(bm + row) * lda + k0 + scol, &As[buf][(i * 4 + w) * 512]);
      gload16(Bt + (long)(bn + row) * Kdim + k0 + scol, &Bs[buf][(i * 4 + w) * 512]);
    }
  };
  stage(0, 0);
  if (nk > 1) stage(1, 1);
  for (int kt = 0; kt < nk; ++kt) {
    int cur = kt & 1;
    if (kt + 1 < nk) { WAIT_VM(8); } else { WAIT_VM(0); }
    RAW_BAR();
    SCHED_FENCE();
    bf16x8 af[2][4], bfr[2][4];
#pragma unroll
    for (int kk = 0; kk < 2; kk++) {
#pragma unroll
      for (int m = 0; m < 4; m++)
        af[kk][m] = *(const bf16x8*)&As[cur][(wm * 64 + m * 16 + lr) * 64 + kk * 32 + lg * 8];
#pragma unroll
      for (int n = 0; n < 4; n++)
        bfr[kk][n] = *(const bf16x8*)&Bs[cur][(wn * 64 + n * 16 + lr) * 64 + kk * 32 + lg * 8];
    }
    WAIT_LGKM0;
    SCHED_FENCE();
    RAW_BAR();
    if (kt + 2 < nk) stage(cur, kt + 2);
#pragma unroll
    for (int kk = 0; kk < 2; kk++)
#pragma unroll
      for (int m = 0; m < 4; m++)
#pragma unroll
        for (int n = 0; n < 4; n++)
          acc[m][n] = __builtin_amdgcn_mfma_f32_16x16x32_bf16(af[kk][m], bfr[kk][n],
                                                              acc[m][n], 0, 0, 0);
  }
#pragma unroll
  for (int n = 0; n < 4; n++) {
    int cg = bn + wn * 64 + n * 16 + lr;
    float bv = bias ? bias[cg] : 0.0f;
#pragma unroll
    for (int m = 0; m < 4; m++) {
#pragma unroll
      for (int rr = 0; rr < 4; rr++) {
        int rg = bm + wm * 64 + m * 16 + lg * 4 + rr;
        float v = acc[m][n][rr] + bv;
        if (act == 1) v = 0.5f * v * (1.0f + erff(v * 0.70710678f));
        outB[cbase + (long)rg * ldc + cg] = (bf16)v;
      }
    }
  }
}

// ------- split-K GEMM (same pipeline): psum[z] = A[:, zKc:(z+1)Kc] x Bt^T ---
__global__ __launch_bounds__(256) void k_gemmsk(
    const bf16* __restrict__ A, long lda,
    const bf16* __restrict__ Bt, int Kfull,
    float* __restrict__ psum, long slab, int Kchunk, int ldc) {
  __shared__ __align__(16) bf16 As[2][128 * 64];
  __shared__ __align__(16) bf16 Bs[2][128 * 64];
  int z = blockIdx.z;
  int bm = blockIdx.y * 128, bn = blockIdx.x * 128;
  int t = threadIdx.x, w = t >> 6, lane = t & 63;
  int wm = w >> 1, wn = w & 1;
  int lr = lane & 15, lg = lane >> 4;
  int srow = lane >> 3, scol = (lane & 7) * 8;
  f32x4 acc[4][4] = {};
  int nk = Kchunk >> 6;
  long kstart = (long)z * Kchunk;
  auto stage = [&](int buf, int kt2) {
    long k0 = kstart + (long)kt2 * 64;
#pragma unroll
    for (int i = 0; i < 4; i++) {
      int row = (i * 4 + w) * 8 + srow;
      gload16(A + (long)(bm + row) * lda + k0 + scol, &As[buf][(i * 4 + w) * 512]);
      gload16(Bt + (long)(bn + row) * Kfull + k0 + scol, &Bs[buf][(i * 4 + w) * 512]);
    }
  };
  stage(0, 0);
  if (nk > 1) stage(1, 1);
  for (int kt = 0; kt < nk; ++kt) {
    int cur = kt & 1;
    if (kt + 1 < nk) { WAIT_VM(8); } else { WAIT_VM(0); }
    RAW_BAR();
    SCHED_FENCE();
    bf16x8 af[2][4], bfr[2][4];
#pragma unroll
    for (int kk = 0; kk < 2; kk++) {
#pragma unroll
      for (int m = 0; m < 4; m++)
        af[kk][m] = *(const bf16x8*)&As[cur][(wm * 64 + m * 16 + lr) * 64 + kk * 32 + lg * 8];
#pragma unroll
      for (int n = 0; n < 4; n++)
        bfr[kk][n] = *(const bf16x8*)&Bs[cur][(wn * 64 + n * 16 + lr) * 64 + kk * 32 + lg * 8];
    }
    WAIT_LGKM0;
    SCHED_FENCE();
    RAW_BAR();
    if (kt + 2 < nk) stage(cur, kt + 2);
#pragma unroll
    for (int kk = 0; kk < 2; kk++)
#pragma unroll
      for (int m = 0; m < 4; m++)
#pragma unroll
        for (int n = 0; n < 4; n++)
          acc[m][n] = __builtin_amdgcn_mfma_f32_16x16x32_bf16(af[kk][m], bfr[kk][n],
                                                              acc[m][n], 0, 0, 0);
  }
  float* po = psum + (long)z * slab;
#pragma unroll
  for (int n = 0; n < 4; n++) {
    int cg = bn + wn * 64 + n * 16 + lr;
#pragma unroll
    for (int m = 0; m < 4; m++) {
#pragma unroll
      for (int rr = 0; rr < 4; rr++) {
        int rg = bm + wm * 64 + m * 16 + lg * 4 + rr;
        po[(long)rg * ldc + cg] = acc[m][n][rr];
      }
    }
  }
}

// ---------------- flash attention v3 (pipelined, counted vmcnt) -------------
template <int WINDOWED>
__global__ __launch_bounds__(256) void k_flash(const bf16* __restrict__ Qg,
                                               const bf16* __restrict__ Kg,
                                               const bf16* __restrict__ Vtg,
                                               bf16* __restrict__ Og, int nkv) {
  __shared__ __align__(16) bf16 Qs[64 * 64];
  __shared__ __align__(16) bf16 Ks[2][64 * 64];
  __shared__ __align__(16) bf16 Vs[2][64 * 64];
  __shared__ __align__(16) bf16 Pl[4][16 * 72];
  int i0 = blockIdx.x * 64;
  int bh = blockIdx.y; int b = bh >> 4, h = bh & 15;
  int t = threadIdx.x, w = t >> 6, lane = t & 63;
  int lr = lane & 15, lg = lane >> 4;
  long qoff = ((long)b * Lc + i0) * Dc + h * DHc;
  long koff = ((long)b * nkv) * Dc + h * DHc;
  long vtoff = (long)bh * DHc * nkv;
  int o0 = w * 1024 + (lane << 4), o1 = o0 + 4096;
  int r0 = o0 >> 7, c0 = (o0 & 127) ^ ((r0 & 7) << 4);
  int r1 = o1 >> 7, c1 = (o1 & 127) ^ ((r1 & 7) << 4);
  int d0 = c0 >> 1, d1 = c1 >> 1;
  gload16(Qg + qoff + (long)r0 * Dc + d0, &Qs[w * 512]);
  gload16(Qg + qoff + (long)r1 * Dc + d1, &Qs[2048 + w * 512]);
  int kb0 = WINDOWED ? (i0 >= 64 ? i0 - 64 : 0) : 0;
  int nt = WINDOWED ? ((i0 - kb0) >> 6) + 1 : (nkv >> 6);
  auto stage = [&](int buf, int kbase) {
    gload16(Kg + koff + (long)(kbase + r0) * Dc + d0, &Ks[buf][w * 512]);
    gload16(Kg + koff + (long)(kbase + r1) * Dc + d1, &Ks[buf][2048 + w * 512]);
    gload16(Vtg + vtoff + (long)r0 * nkv + kbase + d0, &Vs[buf][w * 512]);
    gload16(Vtg + vtoff + (long)r1 * nkv + kbase + d1, &Vs[buf][2048 + w * 512]);
  };
  stage(0, kb0);
  WAIT_VM(4);  // Q complete (chunk-0 loads may remain in flight)
  RAW_BAR();
  SCHED_FENCE();
  bf16x8 bq[2];
#pragma unroll
  for (int ks = 0; ks < 2; ks++) {
    int rq = w * 16 + lr, cb = ks * 64 + lg * 16;
    bq[ks] = *(const bf16x8*)&Qs[((rq << 7) + (cb ^ ((rq & 7) << 4))) >> 1];
  }
  float mrun = -1e30f, lrun = 0.f;
  f32x4 oa[4] = {};
  float slope = WINDOWED ? exp2f(-0.5f * (float)(h + 1)) : 0.0f;
  int qabs = i0 + w * 16 + lr;
  for (int tch = 0; tch < nt; tch++) {
    int cur = tch & 1;
    if (tch + 1 < nt) {
      stage(cur ^ 1, kb0 + (tch + 1) * 64);
      WAIT_VM(4);
    } else {
      WAIT_VM(0);
    }
    RAW_BAR();
    SCHED_FENCE();
    int kbase = kb0 + tch * 64;
    f32x4 st[4] = {};
    __builtin_amdgcn_s_setprio(1);
#pragma unroll
    for (int ks = 0; ks < 2; ks++) {
#pragma unroll
      for (int m = 0; m < 4; m++) {
        int rk = m * 16 + lr, cb = ks * 64 + lg * 16;
        bf16x8 ka = *(const bf16x8*)&Ks[cur][((rk << 7) + (cb ^ ((rk & 7) << 4))) >> 1];
        st[m] = __builtin_amdgcn_mfma_f32_16x16x32_bf16(ka, bq[ks], st[m], 0, 0, 0);
      }
    }
    __builtin_amdgcn_s_setprio(0);
    float sc[4][4];
    float mx = mrun;
#pragma unroll
    for (int m = 0; m < 4; m++)
#pragma unroll
      for (int rr = 0; rr < 4; rr++) {
        int kab = kbase + m * 16 + lg * 4 + rr;
        float v = st[m][rr] * 0.125f;
        if (WINDOWED) {
          v += slope * (float)(kab - qabs);
          bool valid = (kab <= qabs) && (qabs - kab < 64);
          v = valid ? v : -3.0e38f;
        }
        sc[m][rr] = v;
        mx = fmaxf(mx, v);
      }
    mx = fmaxf(mx, __shfl_xor(mx, 16));
    mx = fmaxf(mx, __shfl_xor(mx, 32));
    float corr = __expf(mrun - mx);
    mrun = mx;
    float ps = 0.f;
#pragma unroll
    for (int m = 0; m < 4; m++) {
#pragma unroll
      for (int hh = 0; hh < 2; hh++) {
        float p0 = __expf(sc[m][2 * hh] - mx);
        float p1 = __expf(sc[m][2 * hh + 1] - mx);
        ps += p0 + p1;
        bf16x2 pw; pw[0] = (bf16)p0; pw[1] = (bf16)p1;
        *(bf16x2*)&Pl[w][lr * 72 + m * 16 + lg * 4 + 2 * hh] = pw;
      }
    }
    lrun = lrun * corr + ps;
    float cq[4];
#pragma unroll
    for (int rr = 0; rr < 4; rr++) cq[rr] = __shfl(corr, lg * 4 + rr);
#pragma unroll
    for (int jd = 0; jd < 4; jd++) {
      oa[jd][0] *= cq[0]; oa[jd][1] *= cq[1];
      oa[jd][2] *= cq[2]; oa[jd][3] *= cq[3];
    }
    __builtin_amdgcn_s_setprio(1);
#pragma unroll
    for (int ks = 0; ks < 2; ks++) {
      bf16x8 pa = *(const bf16x8*)&Pl[w][lr * 72 + ks * 32 + lg * 8];
#pragma unroll
      for (int jd = 0; jd < 4; jd++) {
        int rv = jd * 16 + lr, cb = ks * 64 + lg * 16;
        bf16x8 vf = *(const bf16x8*)&Vs[cur][((rv << 7) + (cb ^ ((rv & 7) << 4))) >> 1];
        oa[jd] = __builtin_amdgcn_mfma_f32_16x16x32_bf16(pa, vf, oa[jd], 0, 0, 0);
      }
    }
    __builtin_amdgcn_s_setprio(0);
    WAIT_LGKM0;
    SCHED_FENCE();
    RAW_BAR();
  }
  float ls = lrun + __shfl_xor(lrun, 16);
  ls += __shfl_xor(ls, 32);
  float inv = 1.0f / ls;
  float iq[4];
#pragma unroll
  for (int rr = 0; rr < 4; rr++) iq[rr] = __shfl(inv, lg * 4 + rr);
#pragma unroll
  for (int rr = 0; rr < 4; rr++) {
    int qo = i0 + w * 16 + lg * 4 + rr;
#pragma unroll
    for (int jd = 0; jd < 4; jd++)
      Og[((long)b * Lc + qo) * Dc + h * DHc + jd * 16 + lr] =
          (bf16)(oa[jd][rr] * iq[rr]);
  }
}

// ---- fused: sum NS split-K slabs + bias + residual, then LayerNorm ---------
template <int NS>
__global__ __launch_bounds__(256) void k_lnred(const float* __restrict__ psum,
                                               long slab,
                                               const float* __restrict__ bias,
                                               const float* __restrict__ addsrc,
                                               const float* __restrict__ g,
                                               const float* __restrict__ bb,
                                               float* __restrict__ outF,
                                               bf16* __restrict__ outB) {
  long row = blockIdx.x;
  int t = threadIdx.x; int lane = t & 63; int wid = t >> 6;
  __shared__ float red[8];
  f32x4 v = *(const f32x4*)(psum + row * Dc + t * 4);
#pragma unroll
  for (int s = 1; s < NS; s++) {
    f32x4 u = *(const f32x4*)(psum + s * slab + row * Dc + t * 4);
    v[0] += u[0]; v[1] += u[1]; v[2] += u[2]; v[3] += u[3];
  }
  f32x4 bv = *(const f32x4*)(bias + t * 4);
  f32x4 av = *(const f32x4*)(addsrc + row * Dc + t * 4);
  v[0] += bv[0] + av[0]; v[1] += bv[1] + av[1];
  v[2] += bv[2] + av[2]; v[3] += bv[3] + av[3];
  float s = v[0] + v[1] + v[2] + v[3];
  float s2 = v[0] * v[0] + v[1] * v[1] + v[2] * v[2] + v[3] * v[3];
#pragma unroll
  for (int off = 1; off < 64; off <<= 1) {
    s += __shfl_xor(s, off);
    s2 += __shfl_xor(s2, off);
  }
  if (lane == 0) { red[wid] = s; red[4 + wid] = s2; }
  __syncthreads();
  s = red[0] + red[1] + red[2] + red[3];
  s2 = red[4] + red[5] + red[6] + red[7];
  float mu = s * (1.0f / Dc);
  float var = s2 * (1.0f / Dc) - mu * mu;
  float rs = rsqrtf(var + 1e-5f);
#pragma unroll
  for (int e = 0; e < 4; e++) {
    int c = t * 4 + e;
    float y = (v[e] - mu) * rs * g[c] + bb[c];
    if (outF) outF[row * Dc + c] = y;
    if (outB) outB[row * Dc + c] = (bf16)y;
  }
}

extern "C" void kernel_launch(void* const* d_in, const int* in_sizes, int n_in,
                              void* d_out, int out_size, void* d_ws,
                              size_t ws_size, hipStream_t stream) {
  (void)in_sizes; (void)n_in; (void)out_size; (void)ws_size;
  const float* x = (const float*)d_in[0];
  const float* mem = (const float*)d_in[1];
  const float* swq = (const float*)d_in[2];
  const float* swk = (const float*)d_in[3];
  const float* swv = (const float*)d_in[4];
  const float* swo = (const float*)d_in[5];
  const float* sbq = (const float*)d_in[6];
  const float* sbk = (const float*)d_in[7];
  const float* sbv = (const float*)d_in[8];
  const float* sbo = (const float*)d_in[9];
  const float* cwq = (const float*)d_in[10];
  const float* cwk = (const float*)d_in[11];
  const float* cwv = (const float*)d_in[12];
  const float* cwo = (const float*)d_in[13];
  const float* cbq = (const float*)d_in[14];
  const float* cbk = (const float*)d_in[15];
  const float* cbv = (const float*)d_in[16];
  const float* cbo = (const float*)d_in[17];
  const float* w1 = (const float*)d_in[18];
  const float* b1 = (const float*)d_in[19];
  const float* w2 = (const float*)d_in[20];
  const float* b2 = (const float*)d_in[21];
  const float* g1 = (const float*)d_in[22];
  const float* g2 = (const float*)d_in[23];
  const float* g3 = (const float*)d_in[24];
  const float* be1 = (const float*)d_in[25];
  const float* be2 = (const float*)d_in[26];
  const float* be3 = (const float*)d_in[27];
  float* out = (float*)d_out;

  char* ws = (char*)d_ws;
  size_t off = 0;
  auto alloc = [&](size_t bytes) -> char* {
    char* p = ws + off;
    off = (off + bytes + 255) & ~(size_t)255;
    return p;
  };

  const long BL = (long)Bc * Lc;  // 4096
  const long BM = (long)Bc * Mc;  // 4096
  const long DD = (long)Dc * Dc;
  const long SL = BL * Dc;  // one psum slab (elements)

  bf16* wT0 = (bf16*)alloc((size_t)8 * DD * 2);
  bf16* w1T = (bf16*)alloc((size_t)FFc * Dc * 2);
  bf16* w2T = (bf16*)alloc((size_t)Dc * FFc * 2);
  bf16* xb = (bf16*)alloc((size_t)BL * Dc * 2);
  bf16* memb = (bf16*)alloc((size_t)BM * Dc * 2);
  bf16* x1b = (bf16*)alloc((size_t)BL * Dc * 2);
  bf16* x2b = (bf16*)alloc((size_t)BL * Dc * 2);
  bf16* qb = (bf16*)alloc((size_t)BL * Dc * 2);  // qb,kb,vb contiguous
  bf16* kb = (bf16*)alloc((size_t)BM * Dc * 2);
  bf16* vb = (bf16*)alloc((size_t)BM * Dc * 2);
  bf16* ob = (bf16*)alloc((size_t)BL * Dc * 2);
  bf16* vtS = (bf16*)alloc((size_t)Bc * Hc * DHc * Lc * 2);
  bf16* vtC = (bf16*)alloc((size_t)Bc * Hc * DHc * Mc * 2);
  float* x1f = (float*)alloc((size_t)BL * Dc * 4);
  float* x2f = (float*)alloc((size_t)BL * Dc * 4);
  bf16* ffh = (bf16*)alloc((size_t)BL * FFc * 2);
  float* psum = (float*)alloc((size_t)4 * SL * 4);  // 4 split-K slabs

  // ---- prep: weights -> bf16 [N,K]
  const float* wsrc[8] = {swq, swk, swv, swo, cwq, cwk, cwv, cwo};
  for (int i = 0; i < 8; i++)
    k_transpose_w<<<dim3(Dc / 64, Dc / 64), 256, 0, stream>>>(wsrc[i], wT0 + i * DD, Dc, Dc);
  k_transpose_w<<<dim3(FFc / 64, Dc / 64), 256, 0, stream>>>(w1, w1T, Dc, FFc);
  k_transpose_w<<<dim3(Dc / 64, FFc / 64), 256, 0, stream>>>(w2, w2T, FFc, Dc);
  k_f2b<<<dim3((unsigned)(BL * Dc / 4 / 256)), 256, 0, stream>>>(x, xb, BL * Dc / 4);
  k_f2b<<<dim3((unsigned)(BM * Dc / 4 / 256)), 256, 0, stream>>>(mem, memb, BM * Dc / 4);

  // ---- self-attn QKV projections (z-batched: q,k,v) -> grid 768, 3/CU
  k_gemm128<<<dim3(Dc / 128, BL / 128, 3), 256, 0, stream>>>(
      xb, xb, xb, Dc, wT0, DD, qb, Dc, SL, sbq, sbk, sbv, Dc, 0);
  k_transpose_v<<<dim3(Lc / 64, Bc * Hc), 256, 0, stream>>>(vb, vtS, Lc);
  // ---- windowed causal self-attn + ALiBi
  k_flash<1><<<dim3(Lc / 64, Bc * Hc), 256, 0, stream>>>(qb, kb, vtS, ob, Lc);
  // ---- self O-proj (split-K=2) + fused bias/residual/LN
  k_gemmsk<<<dim3(Dc / 128, BL / 128, 2), 256, 0, stream>>>(
      ob, Dc, wT0 + 3 * DD, Dc, psum, SL, 512, Dc);
  k_lnred<2><<<dim3((unsigned)BL), 256, 0, stream>>>(psum, SL, sbo, x, g1, be1,
                                                     x1f, x1b);

  // ---- cross-attn Q,K,V projections (z-batched) -> grid 768, 3/CU
  k_gemm128<<<dim3(Dc / 128, BM / 128, 3), 256, 0, stream>>>(
      x1b, memb, memb, Dc, wT0 + 4 * DD, DD, qb, Dc, SL, cbq, cbk, cbv, Dc, 0);
  k_transpose_v<<<dim3(Mc / 64, Bc * Hc), 256, 0, stream>>>(vb, vtC, Mc);
  // ---- fused flash cross-attention
  k_flash<0><<<dim3(Lc / 64, Bc * Hc), 256, 0, stream>>>(qb, kb, vtC, ob, Mc);
  // ---- cross O-proj (split-K=2) + fused bias/residual/LN
  k_gemmsk<<<dim3(Dc / 128, BL / 128, 2), 256, 0, stream>>>(
      ob, Dc, wT0 + 7 * DD, Dc, psum, SL, 512, Dc);
  k_lnred<2><<<dim3((unsigned)BL), 256, 0, stream>>>(psum, SL, cbo, x1f, g2, be2,
                                                     x2f, x2b);

  // ---- FFN
  k_gemm128<<<dim3(FFc / 128, BL / 128, 1), 256, 0, stream>>>(
      x2b, x2b, x2b, Dc, w1T, 0, ffh, FFc, 0, b1, b1, b1, Dc, 1);
  // FFN2: split-K=4 -> grid 1024
  k_gemmsk<<<dim3(Dc / 128, BL / 128, 4), 256, 0, stream>>>(
      ffh, FFc, w2T, FFc, psum, SL, 1024, Dc);
  k_lnred<4><<<dim3((unsigned)BL), 256, 0, stream>>>(psum, SL, b2, x2f, g3, be3,
                                                     out, nullptr);
}

// Round 6
// 445.475 us; speedup vs baseline: 2.7827x; 1.0479x over previous
//
#include <hip/hip_runtime.h>
#include <hip/hip_bf16.h>
#include <math.h>

#define Bc 2
#define Lc 2048
#define Mc 2048
#define Dc 1024
#define Hc 16
#define FFc 4096
#define DHc 64

typedef __bf16 bf16;
typedef float f32x4 __attribute__((ext_vector_type(4)));
typedef __bf16 bf16x8 __attribute__((ext_vector_type(8)));
typedef __bf16 bf16x4 __attribute__((ext_vector_type(4)));
typedef __bf16 bf16x2 __attribute__((ext_vector_type(2)));

__device__ inline void gload16(const bf16* g, const bf16* lds_base) {
  __builtin_amdgcn_global_load_lds(
      (const __attribute__((address_space(1))) void*)g,
      (__attribute__((address_space(3))) void*)lds_base, 16, 0, 0);
}

#define WAIT_VM(n) asm volatile("s_waitcnt vmcnt(" #n ")" ::: "memory")
#define WAIT_LGKM0 asm volatile("s_waitcnt lgkmcnt(0)" ::: "memory")
#define RAW_BAR() __builtin_amdgcn_s_barrier()
#define SCHED_FENCE() __builtin_amdgcn_sched_barrier(0)

// ---------------- fp32 -> bf16 convert (vectorized) ----------------
__global__ __launch_bounds__(256) void k_f2b(const float* __restrict__ in,
                                             bf16* __restrict__ out, long n4) {
  long i = (long)blockIdx.x * 256 + threadIdx.x;
  if (i >= n4) return;
  f32x4 v = *(const f32x4*)(in + i * 4);
  bf16x4 o;
  o[0] = (bf16)v[0]; o[1] = (bf16)v[1]; o[2] = (bf16)v[2]; o[3] = (bf16)v[3];
  *(bf16x4*)(out + i * 4) = o;
}

// ---------------- weight transpose+convert: out[n*K+k] = bf16(in[k*N+n]) ----
__global__ __launch_bounds__(256) void k_transpose_w(const float* __restrict__ in,
                                                     bf16* __restrict__ out,
                                                     int K, int N) {
  __shared__ float tile[64][65];
  int n0 = blockIdx.x * 64, k0 = blockIdx.y * 64;
  int t = threadIdx.x;
  int tr = t >> 4, tc = (t & 15) * 4;
#pragma unroll
  for (int p = 0; p < 4; p++) {
    int r = p * 16 + tr;
    f32x4 v = *(const f32x4*)(in + (long)(k0 + r) * N + n0 + tc);
    tile[r][tc] = v[0]; tile[r][tc + 1] = v[1];
    tile[r][tc + 2] = v[2]; tile[r][tc + 3] = v[3];
  }
  __syncthreads();
#pragma unroll
  for (int p = 0; p < 4; p++) {
    int rn = p * 16 + tr;
    bf16x4 o;
    o[0] = (bf16)tile[tc + 0][rn]; o[1] = (bf16)tile[tc + 1][rn];
    o[2] = (bf16)tile[tc + 2][rn]; o[3] = (bf16)tile[tc + 3][rn];
    *(bf16x4*)(out + (long)(n0 + rn) * K + k0 + tc) = o;
  }
}

// ---- V transpose: vt[(b*H+h)*DH+d][j] = vb[b][j][h*DH+d], j in [0,N) ------
__global__ __launch_bounds__(256) void k_transpose_v(const bf16* __restrict__ vb,
                                                     bf16* __restrict__ vt, int N) {
  __shared__ bf16 tile[64][72];
  int j0 = blockIdx.x * 64;
  int bh = blockIdx.y; int b = bh >> 4; int h = bh & 15;
  int t = threadIdx.x;
#pragma unroll
  for (int c = 0; c < 2; c++) {
    int id = t + c * 256;
    int r = id >> 3, c8 = (id & 7) * 8;
    *(bf16x8*)&tile[r][c8] =
        *(const bf16x8*)(vb + ((long)(b * N + j0 + r)) * Dc + h * DHc + c8);
  }
  __syncthreads();
#pragma unroll
  for (int c = 0; c < 2; c++) {
    int id = t + c * 256;
    int d = id >> 3, j8 = (id & 7) * 8;
    bf16x8 o;
#pragma unroll
    for (int e = 0; e < 8; e++) o[e] = tile[j8 + e][d];
    *(bf16x8*)(vt + ((long)bh * DHc + d) * N + j0 + j8) = o;
  }
}

// ------- 128x128 MFMA GEMM, BK=64, 2-deep pipelined LDS dbuf (counted vmcnt)
__global__ __launch_bounds__(256) void k_gemm128(
    const bf16* __restrict__ A0, const bf16* __restrict__ A1,
    const bf16* __restrict__ A2, long lda,
    const bf16* __restrict__ B0, long bstride,
    bf16* __restrict__ outB, long ldc, long cstride,
    const float* __restrict__ bias0, const float* __restrict__ bias1,
    const float* __restrict__ bias2, int Kdim, int act, float scale0) {
  __shared__ __align__(16) bf16 As[2][128 * 64];
  __shared__ __align__(16) bf16 Bs[2][128 * 64];
  int z = blockIdx.z;
  const bf16* A = (z == 0) ? A0 : ((z == 1) ? A1 : A2);
  const bf16* Bt = B0 + (long)z * bstride;
  const float* bias = (z == 0) ? bias0 : ((z == 1) ? bias1 : bias2);
  float scl = (z == 0) ? scale0 : 1.0f;
  long cbase = (long)z * cstride;
  int bm = blockIdx.y * 128, bn = blockIdx.x * 128;
  int t = threadIdx.x, w = t >> 6, lane = t & 63;
  int wm = w >> 1, wn = w & 1;
  int lr = lane & 15, lg = lane >> 4;
  int srow = lane >> 3, scol = (lane & 7) * 8;
  f32x4 acc[4][4] = {};
  int nk = Kdim >> 6;
  auto stage = [&](int buf, int kt2) {
    long k0 = (long)kt2 * 64;
#pragma unroll
    for (int i = 0; i < 4; i++) {
      int row = (i * 4 + w) * 8 + srow;
      gload16(A + (long)(bm + row) * lda + k0 + scol, &As[buf][(i * 4 + w) * 512]);
      gload16(Bt + (long)(bn + row) * Kdim + k0 + scol, &Bs[buf][(i * 4 + w) * 512]);
    }
  };
  stage(0, 0);
  if (nk > 1) stage(1, 1);
  for (int kt = 0; kt < nk; ++kt) {
    int cur = kt & 1;
    if (kt + 1 < nk) { WAIT_VM(8); } else { WAIT_VM(0); }
    RAW_BAR();
    SCHED_FENCE();
    bf16x8 af[2][4], bfr[2][4];
#pragma unroll
    for (int kk = 0; kk < 2; kk++) {
#pragma unroll
      for (int m = 0; m < 4; m++)
        af[kk][m] = *(const bf16x8*)&As[cur][(wm * 64 + m * 16 + lr) * 64 + kk * 32 + lg * 8];
#pragma unroll
      for (int n = 0; n < 4; n++)
        bfr[kk][n] = *(const bf16x8*)&Bs[cur][(wn * 64 + n * 16 + lr) * 64 + kk * 32 + lg * 8];
    }
    WAIT_LGKM0;
    SCHED_FENCE();
    RAW_BAR();
    if (kt + 2 < nk) stage(cur, kt + 2);
#pragma unroll
    for (int kk = 0; kk < 2; kk++)
#pragma unroll
      for (int m = 0; m < 4; m++)
#pragma unroll
        for (int n = 0; n < 4; n++)
          acc[m][n] = __builtin_amdgcn_mfma_f32_16x16x32_bf16(af[kk][m], bfr[kk][n],
                                                              acc[m][n], 0, 0, 0);
  }
#pragma unroll
  for (int n = 0; n < 4; n++) {
    int cg = bn + wn * 64 + n * 16 + lr;
    float bv = bias ? bias[cg] : 0.0f;
#pragma unroll
    for (int m = 0; m < 4; m++) {
#pragma unroll
      for (int rr = 0; rr < 4; rr++) {
        int rg = bm + wm * 64 + m * 16 + lg * 4 + rr;
        float v = (acc[m][n][rr] + bv) * scl;
        if (act == 1) v = 0.5f * v * (1.0f + erff(v * 0.70710678f));
        outB[cbase + (long)rg * ldc + cg] = (bf16)v;
      }
    }
  }
}

// ------- split-K GEMM (same pipeline): psum[z] = A[:, zKc:(z+1)Kc] x Bt^T ---
__global__ __launch_bounds__(256) void k_gemmsk(
    const bf16* __restrict__ A, long lda,
    const bf16* __restrict__ Bt, int Kfull,
    float* __restrict__ psum, long slab, int Kchunk, int ldc) {
  __shared__ __align__(16) bf16 As[2][128 * 64];
  __shared__ __align__(16) bf16 Bs[2][128 * 64];
  int z = blockIdx.z;
  int bm = blockIdx.y * 128, bn = blockIdx.x * 128;
  int t = threadIdx.x, w = t >> 6, lane = t & 63;
  int wm = w >> 1, wn = w & 1;
  int lr = lane & 15, lg = lane >> 4;
  int srow = lane >> 3, scol = (lane & 7) * 8;
  f32x4 acc[4][4] = {};
  int nk = Kchunk >> 6;
  long kstart = (long)z * Kchunk;
  auto stage = [&](int buf, int kt2) {
    long k0 = kstart + (long)kt2 * 64;
#pragma unroll
    for (int i = 0; i < 4; i++) {
      int row = (i * 4 + w) * 8 + srow;
      gload16(A + (long)(bm + row) * lda + k0 + scol, &As[buf][(i * 4 + w) * 512]);
      gload16(Bt + (long)(bn + row) * Kfull + k0 + scol, &Bs[buf][(i * 4 + w) * 512]);
    }
  };
  stage(0, 0);
  if (nk > 1) stage(1, 1);
  for (int kt = 0; kt < nk; ++kt) {
    int cur = kt & 1;
    if (kt + 1 < nk) { WAIT_VM(8); } else { WAIT_VM(0); }
    RAW_BAR();
    SCHED_FENCE();
    bf16x8 af[2][4], bfr[2][4];
#pragma unroll
    for (int kk = 0; kk < 2; kk++) {
#pragma unroll
      for (int m = 0; m < 4; m++)
        af[kk][m] = *(const bf16x8*)&As[cur][(wm * 64 + m * 16 + lr) * 64 + kk * 32 + lg * 8];
#pragma unroll
      for (int n = 0; n < 4; n++)
        bfr[kk][n] = *(const bf16x8*)&Bs[cur][(wn * 64 + n * 16 + lr) * 64 + kk * 32 + lg * 8];
    }
    WAIT_LGKM0;
    SCHED_FENCE();
    RAW_BAR();
    if (kt + 2 < nk) stage(cur, kt + 2);
#pragma unroll
    for (int kk = 0; kk < 2; kk++)
#pragma unroll
      for (int m = 0; m < 4; m++)
#pragma unroll
        for (int n = 0; n < 4; n++)
          acc[m][n] = __builtin_amdgcn_mfma_f32_16x16x32_bf16(af[kk][m], bfr[kk][n],
                                                              acc[m][n], 0, 0, 0);
  }
  float* po = psum + (long)z * slab;
#pragma unroll
  for (int n = 0; n < 4; n++) {
    int cg = bn + wn * 64 + n * 16 + lr;
#pragma unroll
    for (int m = 0; m < 4; m++) {
#pragma unroll
      for (int rr = 0; rr < 4; rr++) {
        int rg = bm + wm * 64 + m * 16 + lg * 4 + rr;
        po[(long)rg * ldc + cg] = acc[m][n][rr];
      }
    }
  }
}

// ---------------- flash attention v4 ---------------------------------------
// exp2 domain (Q prescaled by 0.125*log2e), defer-max, P aliased into Q tile,
// XCD-swizzled block mapping. 40 KB LDS -> 4 blocks/CU.
template <int WINDOWED>
__global__ __launch_bounds__(256) void k_flash(const bf16* __restrict__ Qg,
                                               const bf16* __restrict__ Kg,
                                               const bf16* __restrict__ Vtg,
                                               bf16* __restrict__ Og, int nkv) {
  __shared__ __align__(16) bf16 Qs[64 * 64];  // Q tile; after hoist: P buffer
  __shared__ __align__(16) bf16 Ks[2][64 * 64];
  __shared__ __align__(16) bf16 Vs[2][64 * 64];
  // XCD-aware remap (grid = 32 x 32, 1024 % 8 == 0 -> bijective)
  int flat = blockIdx.y * 32 + blockIdx.x;
  int flat2 = (flat & 7) * 128 + (flat >> 3);
  int i0 = (flat2 & 31) * 64;
  int bh = flat2 >> 5;
  int b = bh >> 4, h = bh & 15;
  int t = threadIdx.x, w = t >> 6, lane = t & 63;
  int lr = lane & 15, lg = lane >> 4;
  long qoff = ((long)b * Lc + i0) * Dc + h * DHc;
  long koff = ((long)b * nkv) * Dc + h * DHc;
  long vtoff = (long)bh * DHc * nkv;
  int o0 = w * 1024 + (lane << 4), o1 = o0 + 4096;
  int r0 = o0 >> 7, c0 = (o0 & 127) ^ ((r0 & 7) << 4);
  int r1 = o1 >> 7, c1 = (o1 & 127) ^ ((r1 & 7) << 4);
  int d0 = c0 >> 1, d1 = c1 >> 1;
  gload16(Qg + qoff + (long)r0 * Dc + d0, &Qs[w * 512]);
  gload16(Qg + qoff + (long)r1 * Dc + d1, &Qs[2048 + w * 512]);
  int kb0 = WINDOWED ? (i0 >= 64 ? i0 - 64 : 0) : 0;
  int nt = WINDOWED ? ((i0 - kb0) >> 6) + 1 : (nkv >> 6);
  auto stage = [&](int buf, int kbase) {
    gload16(Kg + koff + (long)(kbase + r0) * Dc + d0, &Ks[buf][w * 512]);
    gload16(Kg + koff + (long)(kbase + r1) * Dc + d1, &Ks[buf][2048 + w * 512]);
    gload16(Vtg + vtoff + (long)r0 * nkv + kbase + d0, &Vs[buf][w * 512]);
    gload16(Vtg + vtoff + (long)r1 * nkv + kbase + d1, &Vs[buf][2048 + w * 512]);
  };
  stage(0, kb0);
  WAIT_VM(4);  // Q complete
  RAW_BAR();
  SCHED_FENCE();
  bf16x8 bq[2];
#pragma unroll
  for (int ks = 0; ks < 2; ks++) {
    int rq = w * 16 + lr, cb = ks * 64 + lg * 16;
    bq[ks] = *(const bf16x8*)&Qs[((rq << 7) + (cb ^ ((rq & 7) << 4))) >> 1];
  }
  char* pbase = (char*)&Qs[w * 1024];  // per-wave-private P region (dead Q rows)
  float mrun = -1e30f, lrun = 0.f;
  f32x4 oa[4] = {};
  float slopeL2 = WINDOWED ? exp2f(-0.5f * (float)(h + 1)) * 1.44269504f : 0.0f;
  int qabs = i0 + w * 16 + lr;
  for (int tch = 0; tch < nt; tch++) {
    int cur = tch & 1;
    if (tch + 1 < nt) {
      stage(cur ^ 1, kb0 + (tch + 1) * 64);
      WAIT_VM(4);
    } else {
      WAIT_VM(0);
    }
    RAW_BAR();
    SCHED_FENCE();
    int kbase = kb0 + tch * 64;
    f32x4 st[4] = {};
    __builtin_amdgcn_s_setprio(1);
#pragma unroll
    for (int ks = 0; ks < 2; ks++) {
#pragma unroll
      for (int m = 0; m < 4; m++) {
        int rk = m * 16 + lr, cb = ks * 64 + lg * 16;
        bf16x8 ka = *(const bf16x8*)&Ks[cur][((rk << 7) + (cb ^ ((rk & 7) << 4))) >> 1];
        st[m] = __builtin_amdgcn_mfma_f32_16x16x32_bf16(ka, bq[ks], st[m], 0, 0, 0);
      }
    }
    __builtin_amdgcn_s_setprio(0);
    // scores already in log2 domain (Q prescaled)
    float sc[4][4];
    float pmax = -3.0e38f;
#pragma unroll
    for (int m = 0; m < 4; m++)
#pragma unroll
      for (int rr = 0; rr < 4; rr++) {
        int kab = kbase + m * 16 + lg * 4 + rr;
        float v = st[m][rr];
        if (WINDOWED) {
          v += slopeL2 * (float)(kab - qabs);
          bool valid = (kab <= qabs) && (qabs - kab < 64);
          v = valid ? v : -3.0e38f;
        }
        sc[m][rr] = v;
        pmax = fmaxf(pmax, v);
      }
    pmax = fmaxf(pmax, __shfl_xor(pmax, 16));
    pmax = fmaxf(pmax, __shfl_xor(pmax, 32));
    float mx = mrun;
    if (!__all(pmax - mrun <= 8.0f)) {  // rescale only when max grows a lot
      mx = fmaxf(mrun, pmax);
      float corr = exp2f(mrun - mx);
      mrun = mx;
      lrun *= corr;
      float cq[4];
#pragma unroll
      for (int rr = 0; rr < 4; rr++) cq[rr] = __shfl(corr, lg * 4 + rr);
#pragma unroll
      for (int jd = 0; jd < 4; jd++) {
        oa[jd][0] *= cq[0]; oa[jd][1] *= cq[1];
        oa[jd][2] *= cq[2]; oa[jd][3] *= cq[3];
      }
    }
    float ps = 0.f;
#pragma unroll
    for (int m = 0; m < 4; m++) {
#pragma unroll
      for (int hh = 0; hh < 2; hh++) {
        float p0 = exp2f(sc[m][2 * hh] - mx);
        float p1 = exp2f(sc[m][2 * hh + 1] - mx);
        ps += p0 + p1;
        bf16x2 pw; pw[0] = (bf16)p0; pw[1] = (bf16)p1;
        int kcol = m * 16 + lg * 4 + 2 * hh;
        *(bf16x2*)(pbase + (lr << 7) + (((kcol << 1)) ^ ((lr & 7) << 4))) = pw;
      }
    }
    lrun += ps;
    __builtin_amdgcn_s_setprio(1);
#pragma unroll
    for (int ks = 0; ks < 2; ks++) {
      bf16x8 pa = *(const bf16x8*)(pbase + (lr << 7) +
                                   (((ks * 64 + lg * 16)) ^ ((lr & 7) << 4)));
#pragma unroll
      for (int jd = 0; jd < 4; jd++) {
        int rv = jd * 16 + lr, cb = ks * 64 + lg * 16;
        bf16x8 vf = *(const bf16x8*)&Vs[cur][((rv << 7) + (cb ^ ((rv & 7) << 4))) >> 1];
        oa[jd] = __builtin_amdgcn_mfma_f32_16x16x32_bf16(pa, vf, oa[jd], 0, 0, 0);
      }
    }
    __builtin_amdgcn_s_setprio(0);
    WAIT_LGKM0;
    SCHED_FENCE();
    RAW_BAR();
  }
  float ls = lrun + __shfl_xor(lrun, 16);
  ls += __shfl_xor(ls, 32);
  float inv = 1.0f / ls;
  float iq[4];
#pragma unroll
  for (int rr = 0; rr < 4; rr++) iq[rr] = __shfl(inv, lg * 4 + rr);
#pragma unroll
  for (int rr = 0; rr < 4; rr++) {
    int qo = i0 + w * 16 + lg * 4 + rr;
#pragma unroll
    for (int jd = 0; jd < 4; jd++)
      Og[((long)b * Lc + qo) * Dc + h * DHc + jd * 16 + lr] =
          (bf16)(oa[jd][rr] * iq[rr]);
  }
}

// ---- fused: sum NS split-K slabs + bias + residual, then LayerNorm ---------
template <int NS>
__global__ __launch_bounds__(256) void k_lnred(const float* __restrict__ psum,
                                               long slab,
                                               const float* __restrict__ bias,
                                               const float* __restrict__ addsrc,
                                               const float* __restrict__ g,
                                               const float* __restrict__ bb,
                                               float* __restrict__ outF,
                                               bf16* __restrict__ outB) {
  long row = blockIdx.x;
  int t = threadIdx.x; int lane = t & 63; int wid = t >> 6;
  __shared__ float red[8];
  f32x4 v = *(const f32x4*)(psum + row * Dc + t * 4);
#pragma unroll
  for (int s = 1; s < NS; s++) {
    f32x4 u = *(const f32x4*)(psum + s * slab + row * Dc + t * 4);
    v[0] += u[0]; v[1] += u[1]; v[2] += u[2]; v[3] += u[3];
  }
  f32x4 bv = *(const f32x4*)(bias + t * 4);
  f32x4 av = *(const f32x4*)(addsrc + row * Dc + t * 4);
  v[0] += bv[0] + av[0]; v[1] += bv[1] + av[1];
  v[2] += bv[2] + av[2]; v[3] += bv[3] + av[3];
  float s = v[0] + v[1] + v[2] + v[3];
  float s2 = v[0] * v[0] + v[1] * v[1] + v[2] * v[2] + v[3] * v[3];
#pragma unroll
  for (int off = 1; off < 64; off <<= 1) {
    s += __shfl_xor(s, off);
    s2 += __shfl_xor(s2, off);
  }
  if (lane == 0) { red[wid] = s; red[4 + wid] = s2; }
  __syncthreads();
  s = red[0] + red[1] + red[2] + red[3];
  s2 = red[4] + red[5] + red[6] + red[7];
  float mu = s * (1.0f / Dc);
  float var = s2 * (1.0f / Dc) - mu * mu;
  float rs = rsqrtf(var + 1e-5f);
#pragma unroll
  for (int e = 0; e < 4; e++) {
    int c = t * 4 + e;
    float y = (v[e] - mu) * rs * g[c] + bb[c];
    if (outF) outF[row * Dc + c] = y;
    if (outB) outB[row * Dc + c] = (bf16)y;
  }
}

extern "C" void kernel_launch(void* const* d_in, const int* in_sizes, int n_in,
                              void* d_out, int out_size, void* d_ws,
                              size_t ws_size, hipStream_t stream) {
  (void)in_sizes; (void)n_in; (void)out_size; (void)ws_size;
  const float* x = (const float*)d_in[0];
  const float* mem = (const float*)d_in[1];
  const float* swq = (const float*)d_in[2];
  const float* swk = (const float*)d_in[3];
  const float* swv = (const float*)d_in[4];
  const float* swo = (const float*)d_in[5];
  const float* sbq = (const float*)d_in[6];
  const float* sbk = (const float*)d_in[7];
  const float* sbv = (const float*)d_in[8];
  const float* sbo = (const float*)d_in[9];
  const float* cwq = (const float*)d_in[10];
  const float* cwk = (const float*)d_in[11];
  const float* cwv = (const float*)d_in[12];
  const float* cwo = (const float*)d_in[13];
  const float* cbq = (const float*)d_in[14];
  const float* cbk = (const float*)d_in[15];
  const float* cbv = (const float*)d_in[16];
  const float* cbo = (const float*)d_in[17];
  const float* w1 = (const float*)d_in[18];
  const float* b1 = (const float*)d_in[19];
  const float* w2 = (const float*)d_in[20];
  const float* b2 = (const float*)d_in[21];
  const float* g1 = (const float*)d_in[22];
  const float* g2 = (const float*)d_in[23];
  const float* g3 = (const float*)d_in[24];
  const float* be1 = (const float*)d_in[25];
  const float* be2 = (const float*)d_in[26];
  const float* be3 = (const float*)d_in[27];
  float* out = (float*)d_out;

  char* ws = (char*)d_ws;
  size_t off = 0;
  auto alloc = [&](size_t bytes) -> char* {
    char* p = ws + off;
    off = (off + bytes + 255) & ~(size_t)255;
    return p;
  };

  const long BL = (long)Bc * Lc;  // 4096
  const long BM = (long)Bc * Mc;  // 4096
  const long DD = (long)Dc * Dc;
  const long SL = BL * Dc;  // one psum slab (elements)
  const float QSCL = 0.125f * 1.44269504f;  // fold 1/sqrt(DH) * log2(e) into Q

  bf16* wT0 = (bf16*)alloc((size_t)8 * DD * 2);
  bf16* w1T = (bf16*)alloc((size_t)FFc * Dc * 2);
  bf16* w2T = (bf16*)alloc((size_t)Dc * FFc * 2);
  bf16* xb = (bf16*)alloc((size_t)BL * Dc * 2);
  bf16* memb = (bf16*)alloc((size_t)BM * Dc * 2);
  bf16* x1b = (bf16*)alloc((size_t)BL * Dc * 2);
  bf16* x2b = (bf16*)alloc((size_t)BL * Dc * 2);
  bf16* qb = (bf16*)alloc((size_t)BL * Dc * 2);  // qb,kb,vb contiguous
  bf16* kb = (bf16*)alloc((size_t)BM * Dc * 2);
  bf16* vb = (bf16*)alloc((size_t)BM * Dc * 2);
  bf16* ob = (bf16*)alloc((size_t)BL * Dc * 2);
  bf16* vtS = (bf16*)alloc((size_t)Bc * Hc * DHc * Lc * 2);
  bf16* vtC = (bf16*)alloc((size_t)Bc * Hc * DHc * Mc * 2);
  float* x1f = (float*)alloc((size_t)BL * Dc * 4);
  float* x2f = (float*)alloc((size_t)BL * Dc * 4);
  bf16* ffh = (bf16*)alloc((size_t)BL * FFc * 2);
  float* psum = (float*)alloc((size_t)4 * SL * 4);  // 4 split-K slabs

  // ---- prep: weights -> bf16 [N,K]
  const float* wsrc[8] = {swq, swk, swv, swo, cwq, cwk, cwv, cwo};
  for (int i = 0; i < 8; i++)
    k_transpose_w<<<dim3(Dc / 64, Dc / 64), 256, 0, stream>>>(wsrc[i], wT0 + i * DD, Dc, Dc);
  k_transpose_w<<<dim3(FFc / 64, Dc / 64), 256, 0, stream>>>(w1, w1T, Dc, FFc);
  k_transpose_w<<<dim3(Dc / 64, FFc / 64), 256, 0, stream>>>(w2, w2T, FFc, Dc);
  k_f2b<<<dim3((unsigned)(BL * Dc / 4 / 256)), 256, 0, stream>>>(x, xb, BL * Dc / 4);
  k_f2b<<<dim3((unsigned)(BM * Dc / 4 / 256)), 256, 0, stream>>>(mem, memb, BM * Dc / 4);

  // ---- self-attn QKV projections (z: q,k,v); Q prescaled
  k_gemm128<<<dim3(Dc / 128, BL / 128, 3), 256, 0, stream>>>(
      xb, xb, xb, Dc, wT0, DD, qb, Dc, SL, sbq, sbk, sbv, Dc, 0, QSCL);
  k_transpose_v<<<dim3(Lc / 64, Bc * Hc), 256, 0, stream>>>(vb, vtS, Lc);
  // ---- windowed causal self-attn + ALiBi
  k_flash<1><<<dim3(Lc / 64, Bc * Hc), 256, 0, stream>>>(qb, kb, vtS, ob, Lc);
  // ---- self O-proj (split-K=2) + fused bias/residual/LN
  k_gemmsk<<<dim3(Dc / 128, BL / 128, 2), 256, 0, stream>>>(
      ob, Dc, wT0 + 3 * DD, Dc, psum, SL, 512, Dc);
  k_lnred<2><<<dim3((unsigned)BL), 256, 0, stream>>>(psum, SL, sbo, x, g1, be1,
                                                     x1f, x1b);

  // ---- cross-attn Q,K,V projections (z: q,k,v); Q prescaled
  k_gemm128<<<dim3(Dc / 128, BM / 128, 3), 256, 0, stream>>>(
      x1b, memb, memb, Dc, wT0 + 4 * DD, DD, qb, Dc, SL, cbq, cbk, cbv, Dc, 0, QSCL);
  k_transpose_v<<<dim3(Mc / 64, Bc * Hc), 256, 0, stream>>>(vb, vtC, Mc);
  // ---- fused flash cross-attention
  k_flash<0><<<dim3(Lc / 64, Bc * Hc), 256, 0, stream>>>(qb, kb, vtC, ob, Mc);
  // ---- cross O-proj (split-K=2) + fused bias/residual/LN
  k_gemmsk<<<dim3(Dc / 128, BL / 128, 2), 256, 0, stream>>>(
      ob, Dc, wT0 + 7 * DD, Dc, psum, SL, 512, Dc);
  k_lnred<2><<<dim3((unsigned)BL), 256, 0, stream>>>(psum, SL, cbo, x1f, g2, be2,
                                                     x2f, x2b);

  // ---- FFN
  k_gemm128<<<dim3(FFc / 128, BL / 128, 1), 256, 0, stream>>>(
      x2b, x2b, x2b, Dc, w1T, 0, ffh, FFc, 0, b1, b1, b1, Dc, 1, 1.0f);
  // FFN2: split-K=4 -> grid 1024
  k_gemmsk<<<dim3(Dc / 128, BL / 128, 4), 256, 0, stream>>>(
      ffh, FFc, w2T, FFc, psum, SL, 1024, Dc);
  k_lnred<4><<<dim3((unsigned)BL), 256, 0, stream>>>(psum, SL, b2, x2f, g3, be3,
                                                     out, nullptr);
}

// Round 7
// 413.348 us; speedup vs baseline: 2.9990x; 1.0777x over previous
//
#include <hip/hip_runtime.h>
#include <hip/hip_bf16.h>
#include <math.h>

#define Bc 2
#define Lc 2048
#define Mc 2048
#define Dc 1024
#define Hc 16
#define FFc 4096
#define DHc 64

typedef __bf16 bf16;
typedef float f32x4 __attribute__((ext_vector_type(4)));
typedef __bf16 bf16x8 __attribute__((ext_vector_type(8)));
typedef __bf16 bf16x4 __attribute__((ext_vector_type(4)));
typedef __bf16 bf16x2 __attribute__((ext_vector_type(2)));

__device__ inline void gload16(const bf16* g, const bf16* lds_base) {
  __builtin_amdgcn_global_load_lds(
      (const __attribute__((address_space(1))) void*)g,
      (__attribute__((address_space(3))) void*)lds_base, 16, 0, 0);
}

#define WAIT_VM(n) asm volatile("s_waitcnt vmcnt(" #n ")" ::: "memory")
#define WAIT_LGKM0 asm volatile("s_waitcnt lgkmcnt(0)" ::: "memory")
#define RAW_BAR() __builtin_amdgcn_s_barrier()
#define SCHED_FENCE() __builtin_amdgcn_sched_barrier(0)

__device__ inline float gelu_f(float v) {
  // tanh-approx GELU in exp2 domain (abs err ~1e-3, ok for bf16-grade check)
  float u = 0.7978845608f * (v + 0.044715f * v * v * v);
  float e = exp2f(u * 2.885390082f);  // exp(2u)
  float th = 1.0f - 2.0f / (e + 1.0f);
  return 0.5f * v * (1.0f + th);
}

// ---------------- fp32 -> bf16 convert (vectorized) ----------------
__global__ __launch_bounds__(256) void k_f2b(const float* __restrict__ in,
                                             bf16* __restrict__ out, long n4) {
  long i = (long)blockIdx.x * 256 + threadIdx.x;
  if (i >= n4) return;
  f32x4 v = *(const f32x4*)(in + i * 4);
  bf16x4 o;
  o[0] = (bf16)v[0]; o[1] = (bf16)v[1]; o[2] = (bf16)v[2]; o[3] = (bf16)v[3];
  *(bf16x4*)(out + i * 4) = o;
}

// ---------------- weight transpose+convert: out[n*K+k] = bf16(in[k*N+n]) ----
__global__ __launch_bounds__(256) void k_transpose_w(const float* __restrict__ in,
                                                     bf16* __restrict__ out,
                                                     int K, int N) {
  __shared__ float tile[64][65];
  int n0 = blockIdx.x * 64, k0 = blockIdx.y * 64;
  int t = threadIdx.x;
  int tr = t >> 4, tc = (t & 15) * 4;
#pragma unroll
  for (int p = 0; p < 4; p++) {
    int r = p * 16 + tr;
    f32x4 v = *(const f32x4*)(in + (long)(k0 + r) * N + n0 + tc);
    tile[r][tc] = v[0]; tile[r][tc + 1] = v[1];
    tile[r][tc + 2] = v[2]; tile[r][tc + 3] = v[3];
  }
  __syncthreads();
#pragma unroll
  for (int p = 0; p < 4; p++) {
    int rn = p * 16 + tr;
    bf16x4 o;
    o[0] = (bf16)tile[tc + 0][rn]; o[1] = (bf16)tile[tc + 1][rn];
    o[2] = (bf16)tile[tc + 2][rn]; o[3] = (bf16)tile[tc + 3][rn];
    *(bf16x4*)(out + (long)(n0 + rn) * K + k0 + tc) = o;
  }
}

// ---- V transpose: vt[(b*H+h)*DH+d][j] = vb[b][j][h*DH+d], j in [0,N) ------
__global__ __launch_bounds__(256) void k_transpose_v(const bf16* __restrict__ vb,
                                                     bf16* __restrict__ vt, int N) {
  __shared__ bf16 tile[64][72];
  int j0 = blockIdx.x * 64;
  int bh = blockIdx.y; int b = bh >> 4; int h = bh & 15;
  int t = threadIdx.x;
#pragma unroll
  for (int c = 0; c < 2; c++) {
    int id = t + c * 256;
    int r = id >> 3, c8 = (id & 7) * 8;
    *(bf16x8*)&tile[r][c8] =
        *(const bf16x8*)(vb + ((long)(b * N + j0 + r)) * Dc + h * DHc + c8);
  }
  __syncthreads();
#pragma unroll
  for (int c = 0; c < 2; c++) {
    int id = t + c * 256;
    int d = id >> 3, j8 = (id & 7) * 8;
    bf16x8 o;
#pragma unroll
    for (int e = 0; e < 8; e++) o[e] = tile[j8 + e][d];
    *(bf16x8*)(vt + ((long)bh * DHc + d) * N + j0 + j8) = o;
  }
}

// ------- 128x128 MFMA GEMM, BK=64, pipelined dbuf + T2 XOR-swizzled LDS ----
__global__ __launch_bounds__(256) void k_gemm128(
    const bf16* __restrict__ A0, const bf16* __restrict__ A1,
    const bf16* __restrict__ A2, long lda,
    const bf16* __restrict__ B0, long bstride,
    bf16* __restrict__ outB, long ldc, long cstride,
    const float* __restrict__ bias0, const float* __restrict__ bias1,
    const float* __restrict__ bias2, int Kdim, int act, float scale0) {
  __shared__ __align__(16) bf16 As[2][128 * 64];
  __shared__ __align__(16) bf16 Bs[2][128 * 64];
  int z = blockIdx.z;
  const bf16* A = (z == 0) ? A0 : ((z == 1) ? A1 : A2);
  const bf16* Bt = B0 + (long)z * bstride;
  const float* bias = (z == 0) ? bias0 : ((z == 1) ? bias1 : bias2);
  float scl = (z == 0) ? scale0 : 1.0f;
  long cbase = (long)z * cstride;
  int bm = blockIdx.y * 128, bn = blockIdx.x * 128;
  int t = threadIdx.x, w = t >> 6, lane = t & 63;
  int wm = w >> 1, wn = w & 1;
  int lr = lane & 15, lg = lane >> 4;
  int srow = lane >> 3;
  // pre-swizzled global source column (bytes): cb ^ ((row&7)<<4), row&7==lane>>3
  int scol = (((lane & 7) * 16) ^ ((lane >> 3) << 4)) >> 1;  // elements
  f32x4 acc[4][4] = {};
  int nk = Kdim >> 6;
  auto stage = [&](int buf, int kt2) {
    long k0 = (long)kt2 * 64;
#pragma unroll
    for (int i = 0; i < 4; i++) {
      int row = (i * 4 + w) * 8 + srow;
      gload16(A + (long)(bm + row) * lda + k0 + scol, &As[buf][(i * 4 + w) * 512]);
      gload16(Bt + (long)(bn + row) * Kdim + k0 + scol, &Bs[buf][(i * 4 + w) * 512]);
    }
  };
  stage(0, 0);
  if (nk > 1) stage(1, 1);
  for (int kt = 0; kt < nk; ++kt) {
    int cur = kt & 1;
    if (kt + 1 < nk) { WAIT_VM(8); } else { WAIT_VM(0); }
    RAW_BAR();
    SCHED_FENCE();
    const char* pa = (const char*)&As[cur][0];
    const char* pb = (const char*)&Bs[cur][0];
    int xr = (lr & 7) << 4;
    bf16x8 af[2][4], bfr[2][4];
#pragma unroll
    for (int kk = 0; kk < 2; kk++) {
#pragma unroll
      for (int m = 0; m < 4; m++) {
        int row = wm * 64 + m * 16 + lr;
        af[kk][m] = *(const bf16x8*)(pa + (row << 7) + ((kk * 64 + lg * 16) ^ xr));
      }
#pragma unroll
      for (int n = 0; n < 4; n++) {
        int row = wn * 64 + n * 16 + lr;
        bfr[kk][n] = *(const bf16x8*)(pb + (row << 7) + ((kk * 64 + lg * 16) ^ xr));
      }
    }
    WAIT_LGKM0;
    SCHED_FENCE();
    RAW_BAR();
    if (kt + 2 < nk) stage(cur, kt + 2);
#pragma unroll
    for (int kk = 0; kk < 2; kk++)
#pragma unroll
      for (int m = 0; m < 4; m++)
#pragma unroll
        for (int n = 0; n < 4; n++)
          acc[m][n] = __builtin_amdgcn_mfma_f32_16x16x32_bf16(af[kk][m], bfr[kk][n],
                                                              acc[m][n], 0, 0, 0);
  }
#pragma unroll
  for (int n = 0; n < 4; n++) {
    int cg = bn + wn * 64 + n * 16 + lr;
    float bv = bias ? bias[cg] : 0.0f;
#pragma unroll
    for (int m = 0; m < 4; m++) {
#pragma unroll
      for (int rr = 0; rr < 4; rr++) {
        int rg = bm + wm * 64 + m * 16 + lg * 4 + rr;
        float v = (acc[m][n][rr] + bv) * scl;
        if (act == 1) v = gelu_f(v);
        outB[cbase + (long)rg * ldc + cg] = (bf16)v;
      }
    }
  }
}

// ------- split-K GEMM (same pipeline + swizzle) ----------------------------
__global__ __launch_bounds__(256) void k_gemmsk(
    const bf16* __restrict__ A, long lda,
    const bf16* __restrict__ Bt, int Kfull,
    float* __restrict__ psum, long slab, int Kchunk, int ldc) {
  __shared__ __align__(16) bf16 As[2][128 * 64];
  __shared__ __align__(16) bf16 Bs[2][128 * 64];
  int z = blockIdx.z;
  int bm = blockIdx.y * 128, bn = blockIdx.x * 128;
  int t = threadIdx.x, w = t >> 6, lane = t & 63;
  int wm = w >> 1, wn = w & 1;
  int lr = lane & 15, lg = lane >> 4;
  int srow = lane >> 3;
  int scol = (((lane & 7) * 16) ^ ((lane >> 3) << 4)) >> 1;
  f32x4 acc[4][4] = {};
  int nk = Kchunk >> 6;
  long kstart = (long)z * Kchunk;
  auto stage = [&](int buf, int kt2) {
    long k0 = kstart + (long)kt2 * 64;
#pragma unroll
    for (int i = 0; i < 4; i++) {
      int row = (i * 4 + w) * 8 + srow;
      gload16(A + (long)(bm + row) * lda + k0 + scol, &As[buf][(i * 4 + w) * 512]);
      gload16(Bt + (long)(bn + row) * Kfull + k0 + scol, &Bs[buf][(i * 4 + w) * 512]);
    }
  };
  stage(0, 0);
  if (nk > 1) stage(1, 1);
  for (int kt = 0; kt < nk; ++kt) {
    int cur = kt & 1;
    if (kt + 1 < nk) { WAIT_VM(8); } else { WAIT_VM(0); }
    RAW_BAR();
    SCHED_FENCE();
    const char* pa = (const char*)&As[cur][0];
    const char* pb = (const char*)&Bs[cur][0];
    int xr = (lr & 7) << 4;
    bf16x8 af[2][4], bfr[2][4];
#pragma unroll
    for (int kk = 0; kk < 2; kk++) {
#pragma unroll
      for (int m = 0; m < 4; m++) {
        int row = wm * 64 + m * 16 + lr;
        af[kk][m] = *(const bf16x8*)(pa + (row << 7) + ((kk * 64 + lg * 16) ^ xr));
      }
#pragma unroll
      for (int n = 0; n < 4; n++) {
        int row = wn * 64 + n * 16 + lr;
        bfr[kk][n] = *(const bf16x8*)(pb + (row << 7) + ((kk * 64 + lg * 16) ^ xr));
      }
    }
    WAIT_LGKM0;
    SCHED_FENCE();
    RAW_BAR();
    if (kt + 2 < nk) stage(cur, kt + 2);
#pragma unroll
    for (int kk = 0; kk < 2; kk++)
#pragma unroll
      for (int m = 0; m < 4; m++)
#pragma unroll
        for (int n = 0; n < 4; n++)
          acc[m][n] = __builtin_amdgcn_mfma_f32_16x16x32_bf16(af[kk][m], bfr[kk][n],
                                                              acc[m][n], 0, 0, 0);
  }
  float* po = psum + (long)z * slab;
#pragma unroll
  for (int n = 0; n < 4; n++) {
    int cg = bn + wn * 64 + n * 16 + lr;
#pragma unroll
    for (int m = 0; m < 4; m++) {
#pragma unroll
      for (int rr = 0; rr < 4; rr++) {
        int rg = bm + wm * 64 + m * 16 + lg * 4 + rr;
        po[(long)rg * ldc + cg] = acc[m][n][rr];
      }
    }
  }
}

// ---------------- flash attention v4 ---------------------------------------
template <int WINDOWED>
__global__ __launch_bounds__(256) void k_flash(const bf16* __restrict__ Qg,
                                               const bf16* __restrict__ Kg,
                                               const bf16* __restrict__ Vtg,
                                               bf16* __restrict__ Og, int nkv) {
  __shared__ __align__(16) bf16 Qs[64 * 64];  // Q tile; after hoist: P buffer
  __shared__ __align__(16) bf16 Ks[2][64 * 64];
  __shared__ __align__(16) bf16 Vs[2][64 * 64];
  int flat = blockIdx.y * 32 + blockIdx.x;
  int flat2 = (flat & 7) * 128 + (flat >> 3);
  int i0 = (flat2 & 31) * 64;
  int bh = flat2 >> 5;
  int b = bh >> 4, h = bh & 15;
  int t = threadIdx.x, w = t >> 6, lane = t & 63;
  int lr = lane & 15, lg = lane >> 4;
  long qoff = ((long)b * Lc + i0) * Dc + h * DHc;
  long koff = ((long)b * nkv) * Dc + h * DHc;
  long vtoff = (long)bh * DHc * nkv;
  int o0 = w * 1024 + (lane << 4), o1 = o0 + 4096;
  int r0 = o0 >> 7, c0 = (o0 & 127) ^ ((r0 & 7) << 4);
  int r1 = o1 >> 7, c1 = (o1 & 127) ^ ((r1 & 7) << 4);
  int d0 = c0 >> 1, d1 = c1 >> 1;
  gload16(Qg + qoff + (long)r0 * Dc + d0, &Qs[w * 512]);
  gload16(Qg + qoff + (long)r1 * Dc + d1, &Qs[2048 + w * 512]);
  int kb0 = WINDOWED ? (i0 >= 64 ? i0 - 64 : 0) : 0;
  int nt = WINDOWED ? ((i0 - kb0) >> 6) + 1 : (nkv >> 6);
  auto stage = [&](int buf, int kbase) {
    gload16(Kg + koff + (long)(kbase + r0) * Dc + d0, &Ks[buf][w * 512]);
    gload16(Kg + koff + (long)(kbase + r1) * Dc + d1, &Ks[buf][2048 + w * 512]);
    gload16(Vtg + vtoff + (long)r0 * nkv + kbase + d0, &Vs[buf][w * 512]);
    gload16(Vtg + vtoff + (long)r1 * nkv + kbase + d1, &Vs[buf][2048 + w * 512]);
  };
  stage(0, kb0);
  WAIT_VM(4);  // Q complete
  RAW_BAR();
  SCHED_FENCE();
  bf16x8 bq[2];
#pragma unroll
  for (int ks = 0; ks < 2; ks++) {
    int rq = w * 16 + lr, cb = ks * 64 + lg * 16;
    bq[ks] = *(const bf16x8*)&Qs[((rq << 7) + (cb ^ ((rq & 7) << 4))) >> 1];
  }
  char* pbase = (char*)&Qs[w * 1024];  // per-wave-private P region
  float mrun = -1e30f, lrun = 0.f;
  f32x4 oa[4] = {};
  float slopeL2 = WINDOWED ? exp2f(-0.5f * (float)(h + 1)) * 1.44269504f : 0.0f;
  int qabs = i0 + w * 16 + lr;
  for (int tch = 0; tch < nt; tch++) {
    int cur = tch & 1;
    if (tch + 1 < nt) {
      stage(cur ^ 1, kb0 + (tch + 1) * 64);
      WAIT_VM(4);
    } else {
      WAIT_VM(0);
    }
    RAW_BAR();
    SCHED_FENCE();
    int kbase = kb0 + tch * 64;
    f32x4 st[4] = {};
    __builtin_amdgcn_s_setprio(1);
#pragma unroll
    for (int ks = 0; ks < 2; ks++) {
#pragma unroll
      for (int m = 0; m < 4; m++) {
        int rk = m * 16 + lr, cb = ks * 64 + lg * 16;
        bf16x8 ka = *(const bf16x8*)&Ks[cur][((rk << 7) + (cb ^ ((rk & 7) << 4))) >> 1];
        st[m] = __builtin_amdgcn_mfma_f32_16x16x32_bf16(ka, bq[ks], st[m], 0, 0, 0);
      }
    }
    __builtin_amdgcn_s_setprio(0);
    float sc[4][4];
    float pmax = -3.0e38f;
#pragma unroll
    for (int m = 0; m < 4; m++)
#pragma unroll
      for (int rr = 0; rr < 4; rr++) {
        int kab = kbase + m * 16 + lg * 4 + rr;
        float v = st[m][rr];
        if (WINDOWED) {
          v += slopeL2 * (float)(kab - qabs);
          bool valid = (kab <= qabs) && (qabs - kab < 64);
          v = valid ? v : -3.0e38f;
        }
        sc[m][rr] = v;
        pmax = fmaxf(pmax, v);
      }
    pmax = fmaxf(pmax, __shfl_xor(pmax, 16));
    pmax = fmaxf(pmax, __shfl_xor(pmax, 32));
    float mx = mrun;
    if (!__all(pmax - mrun <= 8.0f)) {
      mx = fmaxf(mrun, pmax);
      float corr = exp2f(mrun - mx);
      mrun = mx;
      lrun *= corr;
      float cq[4];
#pragma unroll
      for (int rr = 0; rr < 4; rr++) cq[rr] = __shfl(corr, lg * 4 + rr);
#pragma unroll
      for (int jd = 0; jd < 4; jd++) {
        oa[jd][0] *= cq[0]; oa[jd][1] *= cq[1];
        oa[jd][2] *= cq[2]; oa[jd][3] *= cq[3];
      }
    }
    float ps = 0.f;
#pragma unroll
    for (int m = 0; m < 4; m++) {
#pragma unroll
      for (int hh = 0; hh < 2; hh++) {
        float p0 = exp2f(sc[m][2 * hh] - mx);
        float p1 = exp2f(sc[m][2 * hh + 1] - mx);
        ps += p0 + p1;
        bf16x2 pw; pw[0] = (bf16)p0; pw[1] = (bf16)p1;
        int kcol = m * 16 + lg * 4 + 2 * hh;
        *(bf16x2*)(pbase + (lr << 7) + (((kcol << 1)) ^ ((lr & 7) << 4))) = pw;
      }
    }
    lrun += ps;
    __builtin_amdgcn_s_setprio(1);
#pragma unroll
    for (int ks = 0; ks < 2; ks++) {
      bf16x8 pa = *(const bf16x8*)(pbase + (lr << 7) +
                                   (((ks * 64 + lg * 16)) ^ ((lr & 7) << 4)));
#pragma unroll
      for (int jd = 0; jd < 4; jd++) {
        int rv = jd * 16 + lr, cb = ks * 64 + lg * 16;
        bf16x8 vf = *(const bf16x8*)&Vs[cur][((rv << 7) + (cb ^ ((rv & 7) << 4))) >> 1];
        oa[jd] = __builtin_amdgcn_mfma_f32_16x16x32_bf16(pa, vf, oa[jd], 0, 0, 0);
      }
    }
    __builtin_amdgcn_s_setprio(0);
    WAIT_LGKM0;
    SCHED_FENCE();
    RAW_BAR();
  }
  float ls = lrun + __shfl_xor(lrun, 16);
  ls += __shfl_xor(ls, 32);
  float inv = 1.0f / ls;
  float iq[4];
#pragma unroll
  for (int rr = 0; rr < 4; rr++) iq[rr] = __shfl(inv, lg * 4 + rr);
#pragma unroll
  for (int rr = 0; rr < 4; rr++) {
    int qo = i0 + w * 16 + lg * 4 + rr;
#pragma unroll
    for (int jd = 0; jd < 4; jd++)
      Og[((long)b * Lc + qo) * Dc + h * DHc + jd * 16 + lr] =
          (bf16)(oa[jd][rr] * iq[rr]);
  }
}

// ---- fused: sum NS split-K slabs + bias + residual, then LayerNorm ---------
template <int NS>
__global__ __launch_bounds__(256) void k_lnred(const float* __restrict__ psum,
                                               long slab,
                                               const float* __restrict__ bias,
                                               const float* __restrict__ addsrc,
                                               const float* __restrict__ g,
                                               const float* __restrict__ bb,
                                               float* __restrict__ outF,
                                               bf16* __restrict__ outB) {
  long row = blockIdx.x;
  int t = threadIdx.x; int lane = t & 63; int wid = t >> 6;
  __shared__ float red[8];
  f32x4 v = *(const f32x4*)(psum + row * Dc + t * 4);
#pragma unroll
  for (int s = 1; s < NS; s++) {
    f32x4 u = *(const f32x4*)(psum + s * slab + row * Dc + t * 4);
    v[0] += u[0]; v[1] += u[1]; v[2] += u[2]; v[3] += u[3];
  }
  f32x4 bv = *(const f32x4*)(bias + t * 4);
  f32x4 av = *(const f32x4*)(addsrc + row * Dc + t * 4);
  v[0] += bv[0] + av[0]; v[1] += bv[1] + av[1];
  v[2] += bv[2] + av[2]; v[3] += bv[3] + av[3];
  float s = v[0] + v[1] + v[2] + v[3];
  float s2 = v[0] * v[0] + v[1] * v[1] + v[2] * v[2] + v[3] * v[3];
#pragma unroll
  for (int off = 1; off < 64; off <<= 1) {
    s += __shfl_xor(s, off);
    s2 += __shfl_xor(s2, off);
  }
  if (lane == 0) { red[wid] = s; red[4 + wid] = s2; }
  __syncthreads();
  s = red[0] + red[1] + red[2] + red[3];
  s2 = red[4] + red[5] + red[6] + red[7];
  float mu = s * (1.0f / Dc);
  float var = s2 * (1.0f / Dc) - mu * mu;
  float rs = rsqrtf(var + 1e-5f);
#pragma unroll
  for (int e = 0; e < 4; e++) {
    int c = t * 4 + e;
    float y = (v[e] - mu) * rs * g[c] + bb[c];
    if (outF) outF[row * Dc + c] = y;
    if (outB) outB[row * Dc + c] = (bf16)y;
  }
}

extern "C" void kernel_launch(void* const* d_in, const int* in_sizes, int n_in,
                              void* d_out, int out_size, void* d_ws,
                              size_t ws_size, hipStream_t stream) {
  (void)in_sizes; (void)n_in; (void)out_size; (void)ws_size;
  const float* x = (const float*)d_in[0];
  const float* mem = (const float*)d_in[1];
  const float* swq = (const float*)d_in[2];
  const float* swk = (const float*)d_in[3];
  const float* swv = (const float*)d_in[4];
  const float* swo = (const float*)d_in[5];
  const float* sbq = (const float*)d_in[6];
  const float* sbk = (const float*)d_in[7];
  const float* sbv = (const float*)d_in[8];
  const float* sbo = (const float*)d_in[9];
  const float* cwq = (const float*)d_in[10];
  const float* cwk = (const float*)d_in[11];
  const float* cwv = (const float*)d_in[12];
  const float* cwo = (const float*)d_in[13];
  const float* cbq = (const float*)d_in[14];
  const float* cbk = (const float*)d_in[15];
  const float* cbv = (const float*)d_in[16];
  const float* cbo = (const float*)d_in[17];
  const float* w1 = (const float*)d_in[18];
  const float* b1 = (const float*)d_in[19];
  const float* w2 = (const float*)d_in[20];
  const float* b2 = (const float*)d_in[21];
  const float* g1 = (const float*)d_in[22];
  const float* g2 = (const float*)d_in[23];
  const float* g3 = (const float*)d_in[24];
  const float* be1 = (const float*)d_in[25];
  const float* be2 = (const float*)d_in[26];
  const float* be3 = (const float*)d_in[27];
  float* out = (float*)d_out;

  char* ws = (char*)d_ws;
  size_t off = 0;
  auto alloc = [&](size_t bytes) -> char* {
    char* p = ws + off;
    off = (off + bytes + 255) & ~(size_t)255;
    return p;
  };

  const long BL = (long)Bc * Lc;  // 4096
  const long BM = (long)Bc * Mc;  // 4096
  const long DD = (long)Dc * Dc;
  const long SL = BL * Dc;  // one psum slab (elements)
  const float QSCL = 0.125f * 1.44269504f;  // fold 1/sqrt(DH)*log2e into Q

  bf16* wT0 = (bf16*)alloc((size_t)8 * DD * 2);
  bf16* w1T = (bf16*)alloc((size_t)FFc * Dc * 2);
  bf16* w2T = (bf16*)alloc((size_t)Dc * FFc * 2);
  bf16* xb = (bf16*)alloc((size_t)BL * Dc * 2);
  bf16* memb = (bf16*)alloc((size_t)BM * Dc * 2);
  bf16* x1b = (bf16*)alloc((size_t)BL * Dc * 2);
  bf16* x2b = (bf16*)alloc((size_t)BL * Dc * 2);
  bf16* qb = (bf16*)alloc((size_t)BL * Dc * 2);  // qb,kb,vb contiguous
  bf16* kb = (bf16*)alloc((size_t)BM * Dc * 2);
  bf16* vb = (bf16*)alloc((size_t)BM * Dc * 2);
  bf16* ob = (bf16*)alloc((size_t)BL * Dc * 2);
  bf16* vtS = (bf16*)alloc((size_t)Bc * Hc * DHc * Lc * 2);
  bf16* vtC = (bf16*)alloc((size_t)Bc * Hc * DHc * Mc * 2);
  float* x1f = (float*)alloc((size_t)BL * Dc * 4);
  float* x2f = (float*)alloc((size_t)BL * Dc * 4);
  bf16* ffh = (bf16*)alloc((size_t)BL * FFc * 2);
  float* psum = (float*)alloc((size_t)4 * SL * 4);  // 4 split-K slabs

  // ---- prep: weights -> bf16 [N,K]
  const float* wsrc[8] = {swq, swk, swv, swo, cwq, cwk, cwv, cwo};
  for (int i = 0; i < 8; i++)
    k_transpose_w<<<dim3(Dc / 64, Dc / 64), 256, 0, stream>>>(wsrc[i], wT0 + i * DD, Dc, Dc);
  k_transpose_w<<<dim3(FFc / 64, Dc / 64), 256, 0, stream>>>(w1, w1T, Dc, FFc);
  k_transpose_w<<<dim3(Dc / 64, FFc / 64), 256, 0, stream>>>(w2, w2T, FFc, Dc);
  k_f2b<<<dim3((unsigned)(BL * Dc / 4 / 256)), 256, 0, stream>>>(x, xb, BL * Dc / 4);
  k_f2b<<<dim3((unsigned)(BM * Dc / 4 / 256)), 256, 0, stream>>>(mem, memb, BM * Dc / 4);

  // ---- self-attn QKV projections (z: q,k,v); Q prescaled
  k_gemm128<<<dim3(Dc / 128, BL / 128, 3), 256, 0, stream>>>(
      xb, xb, xb, Dc, wT0, DD, qb, Dc, SL, sbq, sbk, sbv, Dc, 0, QSCL);
  k_transpose_v<<<dim3(Lc / 64, Bc * Hc), 256, 0, stream>>>(vb, vtS, Lc);
  // ---- windowed causal self-attn + ALiBi
  k_flash<1><<<dim3(Lc / 64, Bc * Hc), 256, 0, stream>>>(qb, kb, vtS, ob, Lc);
  // ---- self O-proj (split-K=2) + fused bias/residual/LN
  k_gemmsk<<<dim3(Dc / 128, BL / 128, 2), 256, 0, stream>>>(
      ob, Dc, wT0 + 3 * DD, Dc, psum, SL, 512, Dc);
  k_lnred<2><<<dim3((unsigned)BL), 256, 0, stream>>>(psum, SL, sbo, x, g1, be1,
                                                     x1f, x1b);

  // ---- cross-attn Q,K,V projections (z: q,k,v); Q prescaled
  k_gemm128<<<dim3(Dc / 128, BM / 128, 3), 256, 0, stream>>>(
      x1b, memb, memb, Dc, wT0 + 4 * DD, DD, qb, Dc, SL, cbq, cbk, cbv, Dc, 0, QSCL);
  k_transpose_v<<<dim3(Mc / 64, Bc * Hc), 256, 0, stream>>>(vb, vtC, Mc);
  // ---- fused flash cross-attention
  k_flash<0><<<dim3(Lc / 64, Bc * Hc), 256, 0, stream>>>(qb, kb, vtC, ob, Mc);
  // ---- cross O-proj (split-K=2) + fused bias/residual/LN
  k_gemmsk<<<dim3(Dc / 128, BL / 128, 2), 256, 0, stream>>>(
      ob, Dc, wT0 + 7 * DD, Dc, psum, SL, 512, Dc);
  k_lnred<2><<<dim3((unsigned)BL), 256, 0, stream>>>(psum, SL, cbo, x1f, g2, be2,
                                                     x2f, x2b);

  // ---- FFN
  k_gemm128<<<dim3(FFc / 128, BL / 128, 1), 256, 0, stream>>>(
      x2b, x2b, x2b, Dc, w1T, 0, ffh, FFc, 0, b1, b1, b1, Dc, 1, 1.0f);
  // FFN2: split-K=4 -> grid 1024
  k_gemmsk<<<dim3(Dc / 128, BL / 128, 4), 256, 0, stream>>>(
      ffh, FFc, w2T, FFc, psum, SL, 1024, Dc);
  k_lnred<4><<<dim3((unsigned)BL), 256, 0, stream>>>(psum, SL, b2, x2f, g3, be3,
                                                     out, nullptr);
}

// Round 8
// 383.432 us; speedup vs baseline: 3.2330x; 1.0780x over previous
//
#include <hip/hip_runtime.h>
#include <hip/hip_bf16.h>
#include <math.h>

#define Bc 2
#define Lc 2048
#define Mc 2048
#define Dc 1024
#define Hc 16
#define FFc 4096
#define DHc 64

typedef __bf16 bf16;
typedef float f32x4 __attribute__((ext_vector_type(4)));
typedef __bf16 bf16x8 __attribute__((ext_vector_type(8)));
typedef __bf16 bf16x4 __attribute__((ext_vector_type(4)));
typedef __bf16 bf16x2 __attribute__((ext_vector_type(2)));

struct Ptrs8 { const float* p[8]; };

__device__ inline void gload16(const bf16* g, const bf16* lds_base) {
  __builtin_amdgcn_global_load_lds(
      (const __attribute__((address_space(1))) void*)g,
      (__attribute__((address_space(3))) void*)lds_base, 16, 0, 0);
}

#define WAIT_VM(n) asm volatile("s_waitcnt vmcnt(" #n ")" ::: "memory")
#define WAIT_LGKM(n) asm volatile("s_waitcnt lgkmcnt(" #n ")" ::: "memory")
#define RAW_BAR() __builtin_amdgcn_s_barrier()
#define SCHED_FENCE() __builtin_amdgcn_sched_barrier(0)

__device__ inline float gelu_f(float v) {
  float u = 0.7978845608f * (v + 0.044715f * v * v * v);
  float e = exp2f(u * 2.885390082f);  // exp(2u)
  float th = 1.0f - 2.0f / (e + 1.0f);
  return 0.5f * v * (1.0f + th);
}

// XCD-aware bijective remap of flat block id (requires nwg % 8 == 0)
__device__ inline int xcd_remap(int flat, int nwg) {
  int cpx = nwg >> 3;
  return (flat & 7) * cpx + (flat >> 3);
}

// ---------------- fp32 -> bf16 convert (vectorized) ----------------
__global__ __launch_bounds__(256) void k_f2b(const float* __restrict__ in,
                                             bf16* __restrict__ out, long n4) {
  long i = (long)blockIdx.x * 256 + threadIdx.x;
  if (i >= n4) return;
  f32x4 v = *(const f32x4*)(in + i * 4);
  bf16x4 o;
  o[0] = (bf16)v[0]; o[1] = (bf16)v[1]; o[2] = (bf16)v[2]; o[3] = (bf16)v[3];
  *(bf16x4*)(out + i * 4) = o;
}

// ------- batched weight transpose (8x DxD): out[z][n*K+k] = bf16(in_z[k*N+n])
__global__ __launch_bounds__(256) void k_transpose_w8(Ptrs8 srcs,
                                                      bf16* __restrict__ out) {
  __shared__ float tile[64][65];
  const float* in = srcs.p[blockIdx.z];
  bf16* o = out + (long)blockIdx.z * Dc * Dc;
  int n0 = blockIdx.x * 64, k0 = blockIdx.y * 64;
  int t = threadIdx.x;
  int tr = t >> 4, tc = (t & 15) * 4;
#pragma unroll
  for (int p = 0; p < 4; p++) {
    int r = p * 16 + tr;
    f32x4 v = *(const f32x4*)(in + (long)(k0 + r) * Dc + n0 + tc);
    tile[r][tc] = v[0]; tile[r][tc + 1] = v[1];
    tile[r][tc + 2] = v[2]; tile[r][tc + 3] = v[3];
  }
  __syncthreads();
#pragma unroll
  for (int p = 0; p < 4; p++) {
    int rn = p * 16 + tr;
    bf16x4 ov;
    ov[0] = (bf16)tile[tc + 0][rn]; ov[1] = (bf16)tile[tc + 1][rn];
    ov[2] = (bf16)tile[tc + 2][rn]; ov[3] = (bf16)tile[tc + 3][rn];
    *(bf16x4*)(o + (long)(n0 + rn) * Dc + k0 + tc) = ov;
  }
}

// ---------------- weight transpose+convert: out[n*K+k] = bf16(in[k*N+n]) ----
__global__ __launch_bounds__(256) void k_transpose_w(const float* __restrict__ in,
                                                     bf16* __restrict__ out,
                                                     int K, int N) {
  __shared__ float tile[64][65];
  int n0 = blockIdx.x * 64, k0 = blockIdx.y * 64;
  int t = threadIdx.x;
  int tr = t >> 4, tc = (t & 15) * 4;
#pragma unroll
  for (int p = 0; p < 4; p++) {
    int r = p * 16 + tr;
    f32x4 v = *(const f32x4*)(in + (long)(k0 + r) * N + n0 + tc);
    tile[r][tc] = v[0]; tile[r][tc + 1] = v[1];
    tile[r][tc + 2] = v[2]; tile[r][tc + 3] = v[3];
  }
  __syncthreads();
#pragma unroll
  for (int p = 0; p < 4; p++) {
    int rn = p * 16 + tr;
    bf16x4 o;
    o[0] = (bf16)tile[tc + 0][rn]; o[1] = (bf16)tile[tc + 1][rn];
    o[2] = (bf16)tile[tc + 2][rn]; o[3] = (bf16)tile[tc + 3][rn];
    *(bf16x4*)(out + (long)(n0 + rn) * K + k0 + tc) = o;
  }
}

// ---- V transpose: vt[(b*H+h)*DH+d][j] = vb[b][j][h*DH+d], j in [0,N) ------
__global__ __launch_bounds__(256) void k_transpose_v(const bf16* __restrict__ vb,
                                                     bf16* __restrict__ vt, int N) {
  __shared__ bf16 tile[64][72];
  int j0 = blockIdx.x * 64;
  int bh = blockIdx.y; int b = bh >> 4; int h = bh & 15;
  int t = threadIdx.x;
#pragma unroll
  for (int c = 0; c < 2; c++) {
    int id = t + c * 256;
    int r = id >> 3, c8 = (id & 7) * 8;
    *(bf16x8*)&tile[r][c8] =
        *(const bf16x8*)(vb + ((long)(b * N + j0 + r)) * Dc + h * DHc + c8);
  }
  __syncthreads();
#pragma unroll
  for (int c = 0; c < 2; c++) {
    int id = t + c * 256;
    int d = id >> 3, j8 = (id & 7) * 8;
    bf16x8 o;
#pragma unroll
    for (int e = 0; e < 8; e++) o[e] = tile[j8 + e][d];
    *(bf16x8*)(vt + ((long)bh * DHc + d) * N + j0 + j8) = o;
  }
}

// ------- 128x128 MFMA GEMM, BK=64, pipelined dbuf, T2 swizzle, T1 remap ----
__global__ __launch_bounds__(256) void k_gemm128(
    const bf16* __restrict__ A0, const bf16* __restrict__ A1,
    const bf16* __restrict__ A2, long lda,
    const bf16* __restrict__ B0, long bstride,
    bf16* __restrict__ outB, long ldc, long cstride,
    const float* __restrict__ bias0, const float* __restrict__ bias1,
    const float* __restrict__ bias2, int Kdim, int act, float scale0) {
  __shared__ __align__(16) bf16 As[2][128 * 64];
  __shared__ __align__(16) bf16 Bs[2][128 * 64];
  int gx = gridDim.x, gy = gridDim.y;
  int nwg = gx * gy * gridDim.z;
  int flat = (blockIdx.z * gy + blockIdx.y) * gx + blockIdx.x;
  int f2 = xcd_remap(flat, nwg);
  int bxi = f2 % gx; int tmp = f2 / gx;
  int byi = tmp % gy; int z = tmp / gy;
  const bf16* A = (z == 0) ? A0 : ((z == 1) ? A1 : A2);
  const bf16* Bt = B0 + (long)z * bstride;
  const float* bias = (z == 0) ? bias0 : ((z == 1) ? bias1 : bias2);
  float scl = (z == 0) ? scale0 : 1.0f;
  long cbase = (long)z * cstride;
  int bm = byi * 128, bn = bxi * 128;
  int t = threadIdx.x, w = t >> 6, lane = t & 63;
  int wm = w >> 1, wn = w & 1;
  int lr = lane & 15, lg = lane >> 4;
  int srow = lane >> 3;
  int scol = (((lane & 7) * 16) ^ ((lane >> 3) << 4)) >> 1;  // pre-swizzled src
  f32x4 acc[4][4] = {};
  int nk = Kdim >> 6;
  auto stage = [&](int buf, int kt2) {
    long k0 = (long)kt2 * 64;
#pragma unroll
    for (int i = 0; i < 4; i++) {
      int row = (i * 4 + w) * 8 + srow;
      gload16(A + (long)(bm + row) * lda + k0 + scol, &As[buf][(i * 4 + w) * 512]);
      gload16(Bt + (long)(bn + row) * Kdim + k0 + scol, &Bs[buf][(i * 4 + w) * 512]);
    }
  };
  stage(0, 0);
  if (nk > 1) stage(1, 1);
  for (int kt = 0; kt < nk; ++kt) {
    int cur = kt & 1;
    if (kt + 1 < nk) { WAIT_VM(8); } else { WAIT_VM(0); }
    RAW_BAR();
    SCHED_FENCE();
    const char* pa = (const char*)&As[cur][0];
    const char* pb = (const char*)&Bs[cur][0];
    int xr = (lr & 7) << 4;
    bf16x8 af[2][4], bfr[2][4];
    // kk=0 reads first (issue order pinned), then kk=1
#pragma unroll
    for (int m = 0; m < 4; m++) {
      int row = wm * 64 + m * 16 + lr;
      af[0][m] = *(const bf16x8*)(pa + (row << 7) + ((lg * 16) ^ xr));
    }
#pragma unroll
    for (int n = 0; n < 4; n++) {
      int row = wn * 64 + n * 16 + lr;
      bfr[0][n] = *(const bf16x8*)(pb + (row << 7) + ((lg * 16) ^ xr));
    }
    SCHED_FENCE();
#pragma unroll
    for (int m = 0; m < 4; m++) {
      int row = wm * 64 + m * 16 + lr;
      af[1][m] = *(const bf16x8*)(pa + (row << 7) + ((64 + lg * 16) ^ xr));
    }
#pragma unroll
    for (int n = 0; n < 4; n++) {
      int row = wn * 64 + n * 16 + lr;
      bfr[1][n] = *(const bf16x8*)(pb + (row << 7) + ((64 + lg * 16) ^ xr));
    }
    SCHED_FENCE();
    WAIT_LGKM(8);
    SCHED_FENCE();
#pragma unroll
    for (int m = 0; m < 4; m++)
#pragma unroll
      for (int n = 0; n < 4; n++)
        acc[m][n] = __builtin_amdgcn_mfma_f32_16x16x32_bf16(af[0][m], bfr[0][n],
                                                            acc[m][n], 0, 0, 0);
    WAIT_LGKM(0);
    SCHED_FENCE();
    RAW_BAR();
    if (kt + 2 < nk) stage(cur, kt + 2);
    SCHED_FENCE();
#pragma unroll
    for (int m = 0; m < 4; m++)
#pragma unroll
      for (int n = 0; n < 4; n++)
        acc[m][n] = __builtin_amdgcn_mfma_f32_16x16x32_bf16(af[1][m], bfr[1][n],
                                                            acc[m][n], 0, 0, 0);
  }
#pragma unroll
  for (int n = 0; n < 4; n++) {
    int cg = bn + wn * 64 + n * 16 + lr;
    float bv = bias ? bias[cg] : 0.0f;
#pragma unroll
    for (int m = 0; m < 4; m++) {
#pragma unroll
      for (int rr = 0; rr < 4; rr++) {
        int rg = bm + wm * 64 + m * 16 + lg * 4 + rr;
        float v = (acc[m][n][rr] + bv) * scl;
        if (act == 1) v = gelu_f(v);
        outB[cbase + (long)rg * ldc + cg] = (bf16)v;
      }
    }
  }
}

// ------- split-K GEMM (same pipeline + swizzle + remap) ---------------------
__global__ __launch_bounds__(256) void k_gemmsk(
    const bf16* __restrict__ A, long lda,
    const bf16* __restrict__ Bt, int Kfull,
    float* __restrict__ psum, long slab, int Kchunk, int ldc) {
  __shared__ __align__(16) bf16 As[2][128 * 64];
  __shared__ __align__(16) bf16 Bs[2][128 * 64];
  int gx = gridDim.x, gy = gridDim.y;
  int nwg = gx * gy * gridDim.z;
  int flat = (blockIdx.z * gy + blockIdx.y) * gx + blockIdx.x;
  int f2 = xcd_remap(flat, nwg);
  int bxi = f2 % gx; int tmp = f2 / gx;
  int byi = tmp % gy; int z = tmp / gy;
  int bm = byi * 128, bn = bxi * 128;
  int t = threadIdx.x, w = t >> 6, lane = t & 63;
  int wm = w >> 1, wn = w & 1;
  int lr = lane & 15, lg = lane >> 4;
  int srow = lane >> 3;
  int scol = (((lane & 7) * 16) ^ ((lane >> 3) << 4)) >> 1;
  f32x4 acc[4][4] = {};
  int nk = Kchunk >> 6;
  long kstart = (long)z * Kchunk;
  auto stage = [&](int buf, int kt2) {
    long k0 = kstart + (long)kt2 * 64;
#pragma unroll
    for (int i = 0; i < 4; i++) {
      int row = (i * 4 + w) * 8 + srow;
      gload16(A + (long)(bm + row) * lda + k0 + scol, &As[buf][(i * 4 + w) * 512]);
      gload16(Bt + (long)(bn + row) * Kfull + k0 + scol, &Bs[buf][(i * 4 + w) * 512]);
    }
  };
  stage(0, 0);
  if (nk > 1) stage(1, 1);
  for (int kt = 0; kt < nk; ++kt) {
    int cur = kt & 1;
    if (kt + 1 < nk) { WAIT_VM(8); } else { WAIT_VM(0); }
    RAW_BAR();
    SCHED_FENCE();
    const char* pa = (const char*)&As[cur][0];
    const char* pb = (const char*)&Bs[cur][0];
    int xr = (lr & 7) << 4;
    bf16x8 af[2][4], bfr[2][4];
#pragma unroll
    for (int m = 0; m < 4; m++) {
      int row = wm * 64 + m * 16 + lr;
      af[0][m] = *(const bf16x8*)(pa + (row << 7) + ((lg * 16) ^ xr));
    }
#pragma unroll
    for (int n = 0; n < 4; n++) {
      int row = wn * 64 + n * 16 + lr;
      bfr[0][n] = *(const bf16x8*)(pb + (row << 7) + ((lg * 16) ^ xr));
    }
    SCHED_FENCE();
#pragma unroll
    for (int m = 0; m < 4; m++) {
      int row = wm * 64 + m * 16 + lr;
      af[1][m] = *(const bf16x8*)(pa + (row << 7) + ((64 + lg * 16) ^ xr));
    }
#pragma unroll
    for (int n = 0; n < 4; n++) {
      int row = wn * 64 + n * 16 + lr;
      bfr[1][n] = *(const bf16x8*)(pb + (row << 7) + ((64 + lg * 16) ^ xr));
    }
    SCHED_FENCE();
    WAIT_LGKM(8);
    SCHED_FENCE();
#pragma unroll
    for (int m = 0; m < 4; m++)
#pragma unroll
      for (int n = 0; n < 4; n++)
        acc[m][n] = __builtin_amdgcn_mfma_f32_16x16x32_bf16(af[0][m], bfr[0][n],
                                                            acc[m][n], 0, 0, 0);
    WAIT_LGKM(0);
    SCHED_FENCE();
    RAW_BAR();
    if (kt + 2 < nk) stage(cur, kt + 2);
    SCHED_FENCE();
#pragma unroll
    for (int m = 0; m < 4; m++)
#pragma unroll
      for (int n = 0; n < 4; n++)
        acc[m][n] = __builtin_amdgcn_mfma_f32_16x16x32_bf16(af[1][m], bfr[1][n],
                                                            acc[m][n], 0, 0, 0);
  }
  float* po = psum + (long)z * slab;
#pragma unroll
  for (int n = 0; n < 4; n++) {
    int cg = bn + wn * 64 + n * 16 + lr;
#pragma unroll
    for (int m = 0; m < 4; m++) {
#pragma unroll
      for (int rr = 0; rr < 4; rr++) {
        int rg = bm + wm * 64 + m * 16 + lg * 4 + rr;
        po[(long)rg * ldc + cg] = acc[m][n][rr];
      }
    }
  }
}

// ---------------- flash attention v5 ---------------------------------------
template <int WINDOWED>
__global__ __launch_bounds__(256) void k_flash(const bf16* __restrict__ Qg,
                                               const bf16* __restrict__ Kg,
                                               const bf16* __restrict__ Vtg,
                                               bf16* __restrict__ Og, int nkv) {
  __shared__ __align__(16) bf16 Qs[64 * 64];  // Q tile; after hoist: P buffer
  __shared__ __align__(16) bf16 Ks[2][64 * 64];
  __shared__ __align__(16) bf16 Vs[2][64 * 64];
  int flat = blockIdx.y * 32 + blockIdx.x;
  int flat2 = (flat & 7) * 128 + (flat >> 3);
  int i0 = (flat2 & 31) * 64;
  int bh = flat2 >> 5;
  int b = bh >> 4, h = bh & 15;
  int t = threadIdx.x, w = t >> 6, lane = t & 63;
  int lr = lane & 15, lg = lane >> 4;
  long qoff = ((long)b * Lc + i0) * Dc + h * DHc;
  long koff = ((long)b * nkv) * Dc + h * DHc;
  long vtoff = (long)bh * DHc * nkv;
  int o0 = w * 1024 + (lane << 4), o1 = o0 + 4096;
  int r0 = o0 >> 7, c0 = (o0 & 127) ^ ((r0 & 7) << 4);
  int r1 = o1 >> 7, c1 = (o1 & 127) ^ ((r1 & 7) << 4);
  int d0 = c0 >> 1, d1 = c1 >> 1;
  gload16(Qg + qoff + (long)r0 * Dc + d0, &Qs[w * 512]);
  gload16(Qg + qoff + (long)r1 * Dc + d1, &Qs[2048 + w * 512]);
  int kb0 = WINDOWED ? (i0 >= 64 ? i0 - 64 : 0) : 0;
  int nt = WINDOWED ? ((i0 - kb0) >> 6) + 1 : (nkv >> 6);
  auto stage = [&](int buf, int kbase) {
    gload16(Kg + koff + (long)(kbase + r0) * Dc + d0, &Ks[buf][w * 512]);
    gload16(Kg + koff + (long)(kbase + r1) * Dc + d1, &Ks[buf][2048 + w * 512]);
    gload16(Vtg + vtoff + (long)r0 * nkv + kbase + d0, &Vs[buf][w * 512]);
    gload16(Vtg + vtoff + (long)r1 * nkv + kbase + d1, &Vs[buf][2048 + w * 512]);
  };
  stage(0, kb0);
  WAIT_VM(4);  // Q complete
  RAW_BAR();
  SCHED_FENCE();
  bf16x8 bq[2];
#pragma unroll
  for (int ks = 0; ks < 2; ks++) {
    int rq = w * 16 + lr, cb = ks * 64 + lg * 16;
    bq[ks] = *(const bf16x8*)&Qs[((rq << 7) + (cb ^ ((rq & 7) << 4))) >> 1];
  }
  char* pbase = (char*)&Qs[w * 1024];  // per-wave-private P region
  float mrun = -1e30f, lrun = 0.f;
  f32x4 oa[4] = {};
  float slopeL2 = WINDOWED ? exp2f(-0.5f * (float)(h + 1)) * 1.44269504f : 0.0f;
  int qabs = i0 + w * 16 + lr;
  for (int tch = 0; tch < nt; tch++) {
    int cur = tch & 1;
    if (tch + 1 < nt) {
      stage(cur ^ 1, kb0 + (tch + 1) * 64);
      WAIT_VM(4);
    } else {
      WAIT_VM(0);
    }
    RAW_BAR();
    SCHED_FENCE();
    int kbase = kb0 + tch * 64;
    f32x4 st[4] = {};
    __builtin_amdgcn_s_setprio(1);
#pragma unroll
    for (int ks = 0; ks < 2; ks++) {
#pragma unroll
      for (int m = 0; m < 4; m++) {
        int rk = m * 16 + lr, cb = ks * 64 + lg * 16;
        bf16x8 ka = *(const bf16x8*)&Ks[cur][((rk << 7) + (cb ^ ((rk & 7) << 4))) >> 1];
        st[m] = __builtin_amdgcn_mfma_f32_16x16x32_bf16(ka, bq[ks], st[m], 0, 0, 0);
      }
    }
    __builtin_amdgcn_s_setprio(0);
    float sc[4][4];
#pragma unroll
    for (int m = 0; m < 4; m++)
#pragma unroll
      for (int rr = 0; rr < 4; rr++) {
        float v = st[m][rr];
        if (WINDOWED) {
          int kab = kbase + m * 16 + lg * 4 + rr;
          v += slopeL2 * (float)(kab - qabs);
          bool valid = (kab <= qabs) && (qabs - kab < 64);
          v = valid ? v : -3.0e38f;
        }
        sc[m][rr] = v;
      }
    // max3-friendly reduction tree (7 max3 + 1 max when fused)
    float pmax = fmaxf(fmaxf(sc[0][0], sc[0][1]), sc[0][2]);
    pmax = fmaxf(fmaxf(pmax, sc[0][3]), sc[1][0]);
    pmax = fmaxf(fmaxf(pmax, sc[1][1]), sc[1][2]);
    pmax = fmaxf(fmaxf(pmax, sc[1][3]), sc[2][0]);
    pmax = fmaxf(fmaxf(pmax, sc[2][1]), sc[2][2]);
    pmax = fmaxf(fmaxf(pmax, sc[2][3]), sc[3][0]);
    pmax = fmaxf(fmaxf(pmax, sc[3][1]), sc[3][2]);
    pmax = fmaxf(pmax, sc[3][3]);
    pmax = fmaxf(pmax, __shfl_xor(pmax, 16));
    pmax = fmaxf(pmax, __shfl_xor(pmax, 32));
    float mx = mrun;
    if (!__all(pmax - mrun <= 8.0f)) {  // rescale only when max grows a lot
      mx = fmaxf(mrun, pmax);
      float corr = exp2f(mrun - mx);
      mrun = mx;
      lrun *= corr;
      float cq[4];
#pragma unroll
      for (int rr = 0; rr < 4; rr++) cq[rr] = __shfl(corr, lg * 4 + rr);
#pragma unroll
      for (int jd = 0; jd < 4; jd++) {
        oa[jd][0] *= cq[0]; oa[jd][1] *= cq[1];
        oa[jd][2] *= cq[2]; oa[jd][3] *= cq[3];
      }
    }
    float ps0 = 0.f, ps1 = 0.f;
#pragma unroll
    for (int m = 0; m < 4; m++) {
#pragma unroll
      for (int hh = 0; hh < 2; hh++) {
        float p0 = exp2f(sc[m][2 * hh] - mx);
        float p1 = exp2f(sc[m][2 * hh + 1] - mx);
        ps0 += p0; ps1 += p1;
        bf16x2 pw; pw[0] = (bf16)p0; pw[1] = (bf16)p1;
        int kcol = m * 16 + lg * 4 + 2 * hh;
        *(bf16x2*)(pbase + (lr << 7) + (((kcol << 1)) ^ ((lr & 7) << 4))) = pw;
      }
    }
    lrun += ps0 + ps1;
    __builtin_amdgcn_s_setprio(1);
#pragma unroll
    for (int ks = 0; ks < 2; ks++) {
      bf16x8 pa = *(const bf16x8*)(pbase + (lr << 7) +
                                   (((ks * 64 + lg * 16)) ^ ((lr & 7) << 4)));
#pragma unroll
      for (int jd = 0; jd < 4; jd++) {
        int rv = jd * 16 + lr, cb = ks * 64 + lg * 16;
        bf16x8 vf = *(const bf16x8*)&Vs[cur][((rv << 7) + (cb ^ ((rv & 7) << 4))) >> 1];
        oa[jd] = __builtin_amdgcn_mfma_f32_16x16x32_bf16(pa, vf, oa[jd], 0, 0, 0);
      }
    }
    __builtin_amdgcn_s_setprio(0);
    WAIT_LGKM(0);
    SCHED_FENCE();
    RAW_BAR();
  }
  float ls = lrun + __shfl_xor(lrun, 16);
  ls += __shfl_xor(ls, 32);
  float inv = 1.0f / ls;
  float iq[4];
#pragma unroll
  for (int rr = 0; rr < 4; rr++) iq[rr] = __shfl(inv, lg * 4 + rr);
#pragma unroll
  for (int rr = 0; rr < 4; rr++) {
    int qo = i0 + w * 16 + lg * 4 + rr;
#pragma unroll
    for (int jd = 0; jd < 4; jd++)
      Og[((long)b * Lc + qo) * Dc + h * DHc + jd * 16 + lr] =
          (bf16)(oa[jd][rr] * iq[rr]);
  }
}

// ---- fused: sum NS split-K slabs + bias + residual, then LayerNorm ---------
template <int NS>
__global__ __launch_bounds__(256) void k_lnred(const float* __restrict__ psum,
                                               long slab,
                                               const float* __restrict__ bias,
                                               const float* __restrict__ addsrc,
                                               const float* __restrict__ g,
                                               const float* __restrict__ bb,
                                               float* __restrict__ outF,
                                               bf16* __restrict__ outB) {
  long row = blockIdx.x;
  int t = threadIdx.x; int lane = t & 63; int wid = t >> 6;
  __shared__ float red[8];
  f32x4 v = *(const f32x4*)(psum + row * Dc + t * 4);
#pragma unroll
  for (int s = 1; s < NS; s++) {
    f32x4 u = *(const f32x4*)(psum + s * slab + row * Dc + t * 4);
    v[0] += u[0]; v[1] += u[1]; v[2] += u[2]; v[3] += u[3];
  }
  f32x4 bv = *(const f32x4*)(bias + t * 4);
  f32x4 av = *(const f32x4*)(addsrc + row * Dc + t * 4);
  v[0] += bv[0] + av[0]; v[1] += bv[1] + av[1];
  v[2] += bv[2] + av[2]; v[3] += bv[3] + av[3];
  float s = v[0] + v[1] + v[2] + v[3];
  float s2 = v[0] * v[0] + v[1] * v[1] + v[2] * v[2] + v[3] * v[3];
#pragma unroll
  for (int off = 1; off < 64; off <<= 1) {
    s += __shfl_xor(s, off);
    s2 += __shfl_xor(s2, off);
  }
  if (lane == 0) { red[wid] = s; red[4 + wid] = s2; }
  __syncthreads();
  s = red[0] + red[1] + red[2] + red[3];
  s2 = red[4] + red[5] + red[6] + red[7];
  float mu = s * (1.0f / Dc);
  float var = s2 * (1.0f / Dc) - mu * mu;
  float rs = rsqrtf(var + 1e-5f);
#pragma unroll
  for (int e = 0; e < 4; e++) {
    int c = t * 4 + e;
    float y = (v[e] - mu) * rs * g[c] + bb[c];
    if (outF) outF[row * Dc + c] = y;
    if (outB) outB[row * Dc + c] = (bf16)y;
  }
}

extern "C" void kernel_launch(void* const* d_in, const int* in_sizes, int n_in,
                              void* d_out, int out_size, void* d_ws,
                              size_t ws_size, hipStream_t stream) {
  (void)in_sizes; (void)n_in; (void)out_size; (void)ws_size;
  const float* x = (const float*)d_in[0];
  const float* mem = (const float*)d_in[1];
  const float* swq = (const float*)d_in[2];
  const float* swk = (const float*)d_in[3];
  const float* swv = (const float*)d_in[4];
  const float* swo = (const float*)d_in[5];
  const float* sbq = (const float*)d_in[6];
  const float* sbk = (const float*)d_in[7];
  const float* sbv = (const float*)d_in[8];
  const float* sbo = (const float*)d_in[9];
  const float* cwq = (const float*)d_in[10];
  const float* cwk = (const float*)d_in[11];
  const float* cwv = (const float*)d_in[12];
  const float* cwo = (const float*)d_in[13];
  const float* cbq = (const float*)d_in[14];
  const float* cbk = (const float*)d_in[15];
  const float* cbv = (const float*)d_in[16];
  const float* cbo = (const float*)d_in[17];
  const float* w1 = (const float*)d_in[18];
  const float* b1 = (const float*)d_in[19];
  const float* w2 = (const float*)d_in[20];
  const float* b2 = (const float*)d_in[21];
  const float* g1 = (const float*)d_in[22];
  const float* g2 = (const float*)d_in[23];
  const float* g3 = (const float*)d_in[24];
  const float* be1 = (const float*)d_in[25];
  const float* be2 = (const float*)d_in[26];
  const float* be3 = (const float*)d_in[27];
  float* out = (float*)d_out;

  char* ws = (char*)d_ws;
  size_t off = 0;
  auto alloc = [&](size_t bytes) -> char* {
    char* p = ws + off;
    off = (off + bytes + 255) & ~(size_t)255;
    return p;
  };

  const long BL = (long)Bc * Lc;  // 4096
  const long BM = (long)Bc * Mc;  // 4096
  const long DD = (long)Dc * Dc;
  const long SL = BL * Dc;  // one psum slab (elements)
  const float QSCL = 0.125f * 1.44269504f;  // fold 1/sqrt(DH)*log2e into Q

  bf16* wT0 = (bf16*)alloc((size_t)8 * DD * 2);
  bf16* w1T = (bf16*)alloc((size_t)FFc * Dc * 2);
  bf16* w2T = (bf16*)alloc((size_t)Dc * FFc * 2);
  bf16* xb = (bf16*)alloc((size_t)BL * Dc * 2);
  bf16* memb = (bf16*)alloc((size_t)BM * Dc * 2);
  bf16* x1b = (bf16*)alloc((size_t)BL * Dc * 2);
  bf16* x2b = (bf16*)alloc((size_t)BL * Dc * 2);
  bf16* qb = (bf16*)alloc((size_t)BL * Dc * 2);  // qb,kb,vb contiguous
  bf16* kb = (bf16*)alloc((size_t)BM * Dc * 2);
  bf16* vb = (bf16*)alloc((size_t)BM * Dc * 2);
  bf16* ob = (bf16*)alloc((size_t)BL * Dc * 2);
  bf16* vtS = (bf16*)alloc((size_t)Bc * Hc * DHc * Lc * 2);
  bf16* vtC = (bf16*)alloc((size_t)Bc * Hc * DHc * Mc * 2);
  float* x1f = (float*)alloc((size_t)BL * Dc * 4);
  float* x2f = (float*)alloc((size_t)BL * Dc * 4);
  bf16* ffh = (bf16*)alloc((size_t)BL * FFc * 2);
  float* psum = (float*)alloc((size_t)4 * SL * 4);  // 4 split-K slabs

  // ---- prep: weights -> bf16 [N,K] (8 DxD batched into one launch)
  Ptrs8 srcs;
  srcs.p[0] = swq; srcs.p[1] = swk; srcs.p[2] = swv; srcs.p[3] = swo;
  srcs.p[4] = cwq; srcs.p[5] = cwk; srcs.p[6] = cwv; srcs.p[7] = cwo;
  k_transpose_w8<<<dim3(Dc / 64, Dc / 64, 8), 256, 0, stream>>>(srcs, wT0);
  k_transpose_w<<<dim3(FFc / 64, Dc / 64), 256, 0, stream>>>(w1, w1T, Dc, FFc);
  k_transpose_w<<<dim3(Dc / 64, FFc / 64), 256, 0, stream>>>(w2, w2T, FFc, Dc);
  k_f2b<<<dim3((unsigned)(BL * Dc / 4 / 256)), 256, 0, stream>>>(x, xb, BL * Dc / 4);
  k_f2b<<<dim3((unsigned)(BM * Dc / 4 / 256)), 256, 0, stream>>>(mem, memb, BM * Dc / 4);

  // ---- self-attn QKV projections (z: q,k,v); Q prescaled
  k_gemm128<<<dim3(Dc / 128, BL / 128, 3), 256, 0, stream>>>(
      xb, xb, xb, Dc, wT0, DD, qb, Dc, SL, sbq, sbk, sbv, Dc, 0, QSCL);
  k_transpose_v<<<dim3(Lc / 64, Bc * Hc), 256, 0, stream>>>(vb, vtS, Lc);
  // ---- windowed causal self-attn + ALiBi
  k_flash<1><<<dim3(Lc / 64, Bc * Hc), 256, 0, stream>>>(qb, kb, vtS, ob, Lc);
  // ---- self O-proj (split-K=2) + fused bias/residual/LN
  k_gemmsk<<<dim3(Dc / 128, BL / 128, 2), 256, 0, stream>>>(
      ob, Dc, wT0 + 3 * DD, Dc, psum, SL, 512, Dc);
  k_lnred<2><<<dim3((unsigned)BL), 256, 0, stream>>>(psum, SL, sbo, x, g1, be1,
                                                     x1f, x1b);

  // ---- cross-attn Q,K,V projections (z: q,k,v); Q prescaled
  k_gemm128<<<dim3(Dc / 128, BM / 128, 3), 256, 0, stream>>>(
      x1b, memb, memb, Dc, wT0 + 4 * DD, DD, qb, Dc, SL, cbq, cbk, cbv, Dc, 0, QSCL);
  k_transpose_v<<<dim3(Mc / 64, Bc * Hc), 256, 0, stream>>>(vb, vtC, Mc);
  // ---- fused flash cross-attention
  k_flash<0><<<dim3(Lc / 64, Bc * Hc), 256, 0, stream>>>(qb, kb, vtC, ob, Mc);
  // ---- cross O-proj (split-K=2) + fused bias/residual/LN
  k_gemmsk<<<dim3(Dc / 128, BL / 128, 2), 256, 0, stream>>>(
      ob, Dc, wT0 + 7 * DD, Dc, psum, SL, 512, Dc);
  k_lnred<2><<<dim3((unsigned)BL), 256, 0, stream>>>(psum, SL, cbo, x1f, g2, be2,
                                                     x2f, x2b);

  // ---- FFN
  k_gemm128<<<dim3(FFc / 128, BL / 128, 1), 256, 0, stream>>>(
      x2b, x2b, x2b, Dc, w1T, 0, ffh, FFc, 0, b1, b1, b1, Dc, 1, 1.0f);
  // FFN2: split-K=4 -> grid 1024
  k_gemmsk<<<dim3(Dc / 128, BL / 128, 4), 256, 0, stream>>>(
      ffh, FFc, w2T, FFc, psum, SL, 1024, Dc);
  k_lnred<4><<<dim3((unsigned)BL), 256, 0, stream>>>(psum, SL, b2, x2f, g3, be3,
                                                     out, nullptr);
}

// Round 9
// 359.929 us; speedup vs baseline: 3.4441x; 1.0653x over previous
//
#include <hip/hip_runtime.h>
#include <hip/hip_bf16.h>
#include <math.h>

#define Bc 2
#define Lc 2048
#define Mc 2048
#define Dc 1024
#define Hc 16
#define FFc 4096
#define DHc 64

typedef __bf16 bf16;
typedef float f32x4 __attribute__((ext_vector_type(4)));
typedef __bf16 bf16x8 __attribute__((ext_vector_type(8)));
typedef __bf16 bf16x4 __attribute__((ext_vector_type(4)));
typedef __bf16 bf16x2 __attribute__((ext_vector_type(2)));

struct Ptrs8 { const float* p[8]; };

__device__ inline void gload16(const bf16* g, const bf16* lds_base) {
  __builtin_amdgcn_global_load_lds(
      (const __attribute__((address_space(1))) void*)g,
      (__attribute__((address_space(3))) void*)lds_base, 16, 0, 0);
}

#define WAIT_VM(n) asm volatile("s_waitcnt vmcnt(" #n ")" ::: "memory")
#define WAIT_LGKM(n) asm volatile("s_waitcnt lgkmcnt(" #n ")" ::: "memory")
#define RAW_BAR() __builtin_amdgcn_s_barrier()
#define SCHED_FENCE() __builtin_amdgcn_sched_barrier(0)

__device__ inline float gelu_f(float v) {
  float u = 0.7978845608f * (v + 0.044715f * v * v * v);
  float e = exp2f(u * 2.885390082f);  // exp(2u)
  float th = 1.0f - 2.0f / (e + 1.0f);
  return 0.5f * v * (1.0f + th);
}

// XCD-aware bijective remap of flat block id (requires nwg % 8 == 0)
__device__ inline int xcd_remap(int flat, int nwg) {
  int cpx = nwg >> 3;
  return (flat & 7) * cpx + (flat >> 3);
}

// ---------------- fp32 -> bf16 convert (vectorized) ----------------
__global__ __launch_bounds__(256) void k_f2b(const float* __restrict__ in,
                                             bf16* __restrict__ out, long n4) {
  long i = (long)blockIdx.x * 256 + threadIdx.x;
  if (i >= n4) return;
  f32x4 v = *(const f32x4*)(in + i * 4);
  bf16x4 o;
  o[0] = (bf16)v[0]; o[1] = (bf16)v[1]; o[2] = (bf16)v[2]; o[3] = (bf16)v[3];
  *(bf16x4*)(out + i * 4) = o;
}

// ------- batched weight transpose (8x DxD): out[z][n*K+k] = bf16(in_z[k*N+n])
__global__ __launch_bounds__(256) void k_transpose_w8(Ptrs8 srcs,
                                                      bf16* __restrict__ out) {
  __shared__ float tile[64][65];
  const float* in = srcs.p[blockIdx.z];
  bf16* o = out + (long)blockIdx.z * Dc * Dc;
  int n0 = blockIdx.x * 64, k0 = blockIdx.y * 64;
  int t = threadIdx.x;
  int tr = t >> 4, tc = (t & 15) * 4;
#pragma unroll
  for (int p = 0; p < 4; p++) {
    int r = p * 16 + tr;
    f32x4 v = *(const f32x4*)(in + (long)(k0 + r) * Dc + n0 + tc);
    tile[r][tc] = v[0]; tile[r][tc + 1] = v[1];
    tile[r][tc + 2] = v[2]; tile[r][tc + 3] = v[3];
  }
  __syncthreads();
#pragma unroll
  for (int p = 0; p < 4; p++) {
    int rn = p * 16 + tr;
    bf16x4 ov;
    ov[0] = (bf16)tile[tc + 0][rn]; ov[1] = (bf16)tile[tc + 1][rn];
    ov[2] = (bf16)tile[tc + 2][rn]; ov[3] = (bf16)tile[tc + 3][rn];
    *(bf16x4*)(o + (long)(n0 + rn) * Dc + k0 + tc) = ov;
  }
}

// ---------------- weight transpose+convert: out[n*K+k] = bf16(in[k*N+n]) ----
__global__ __launch_bounds__(256) void k_transpose_w(const float* __restrict__ in,
                                                     bf16* __restrict__ out,
                                                     int K, int N) {
  __shared__ float tile[64][65];
  int n0 = blockIdx.x * 64, k0 = blockIdx.y * 64;
  int t = threadIdx.x;
  int tr = t >> 4, tc = (t & 15) * 4;
#pragma unroll
  for (int p = 0; p < 4; p++) {
    int r = p * 16 + tr;
    f32x4 v = *(const f32x4*)(in + (long)(k0 + r) * N + n0 + tc);
    tile[r][tc] = v[0]; tile[r][tc + 1] = v[1];
    tile[r][tc + 2] = v[2]; tile[r][tc + 3] = v[3];
  }
  __syncthreads();
#pragma unroll
  for (int p = 0; p < 4; p++) {
    int rn = p * 16 + tr;
    bf16x4 o;
    o[0] = (bf16)tile[tc + 0][rn]; o[1] = (bf16)tile[tc + 1][rn];
    o[2] = (bf16)tile[tc + 2][rn]; o[3] = (bf16)tile[tc + 3][rn];
    *(bf16x4*)(out + (long)(n0 + rn) * K + k0 + tc) = o;
  }
}

// ---- V transpose: vt[(b*H+h)*DH+d][j] = vb[b][j][h*DH+d], j in [0,N) ------
__global__ __launch_bounds__(256) void k_transpose_v(const bf16* __restrict__ vb,
                                                     bf16* __restrict__ vt, int N) {
  __shared__ bf16 tile[64][72];
  int j0 = blockIdx.x * 64;
  int bh = blockIdx.y; int b = bh >> 4; int h = bh & 15;
  int t = threadIdx.x;
#pragma unroll
  for (int c = 0; c < 2; c++) {
    int id = t + c * 256;
    int r = id >> 3, c8 = (id & 7) * 8;
    *(bf16x8*)&tile[r][c8] =
        *(const bf16x8*)(vb + ((long)(b * N + j0 + r)) * Dc + h * DHc + c8);
  }
  __syncthreads();
#pragma unroll
  for (int c = 0; c < 2; c++) {
    int id = t + c * 256;
    int d = id >> 3, j8 = (id & 7) * 8;
    bf16x8 o;
#pragma unroll
    for (int e = 0; e < 8; e++) o[e] = tile[j8 + e][d];
    *(bf16x8*)(vt + ((long)bh * DHc + d) * N + j0 + j8) = o;
  }
}

// ------- 128x128 MFMA GEMM, BK=64, pipelined dbuf, T2 swizzle, T1 remap ----
__global__ __launch_bounds__(256) void k_gemm128(
    const bf16* __restrict__ A0, const bf16* __restrict__ A1,
    const bf16* __restrict__ A2, long lda,
    const bf16* __restrict__ B0, long bstride,
    bf16* __restrict__ outB, long ldc, long cstride,
    const float* __restrict__ bias0, const float* __restrict__ bias1,
    const float* __restrict__ bias2, int Kdim, int act, float scale0) {
  __shared__ __align__(16) bf16 As[2][128 * 64];
  __shared__ __align__(16) bf16 Bs[2][128 * 64];
  int gx = gridDim.x, gy = gridDim.y;
  int nwg = gx * gy * gridDim.z;
  int flat = (blockIdx.z * gy + blockIdx.y) * gx + blockIdx.x;
  int f2 = xcd_remap(flat, nwg);
  int bxi = f2 % gx; int tmp = f2 / gx;
  int byi = tmp % gy; int z = tmp / gy;
  const bf16* A = (z == 0) ? A0 : ((z == 1) ? A1 : A2);
  const bf16* Bt = B0 + (long)z * bstride;
  const float* bias = (z == 0) ? bias0 : ((z == 1) ? bias1 : bias2);
  float scl = (z == 0) ? scale0 : 1.0f;
  long cbase = (long)z * cstride;
  int bm = byi * 128, bn = bxi * 128;
  int t = threadIdx.x, w = t >> 6, lane = t & 63;
  int wm = w >> 1, wn = w & 1;
  int lr = lane & 15, lg = lane >> 4;
  int srow = lane >> 3;
  int scol = (((lane & 7) * 16) ^ ((lane >> 3) << 4)) >> 1;  // pre-swizzled src
  f32x4 acc[4][4] = {};
  int nk = Kdim >> 6;
  auto stage = [&](int buf, int kt2) {
    long k0 = (long)kt2 * 64;
#pragma unroll
    for (int i = 0; i < 4; i++) {
      int row = (i * 4 + w) * 8 + srow;
      gload16(A + (long)(bm + row) * lda + k0 + scol, &As[buf][(i * 4 + w) * 512]);
      gload16(Bt + (long)(bn + row) * Kdim + k0 + scol, &Bs[buf][(i * 4 + w) * 512]);
    }
  };
  stage(0, 0);
  if (nk > 1) stage(1, 1);
  for (int kt = 0; kt < nk; ++kt) {
    int cur = kt & 1;
    if (kt + 1 < nk) { WAIT_VM(8); } else { WAIT_VM(0); }
    RAW_BAR();
    SCHED_FENCE();
    const char* pa = (const char*)&As[cur][0];
    const char* pb = (const char*)&Bs[cur][0];
    int xr = (lr & 7) << 4;
    bf16x8 af[2][4], bfr[2][4];
#pragma unroll
    for (int m = 0; m < 4; m++) {
      int row = wm * 64 + m * 16 + lr;
      af[0][m] = *(const bf16x8*)(pa + (row << 7) + ((lg * 16) ^ xr));
    }
#pragma unroll
    for (int n = 0; n < 4; n++) {
      int row = wn * 64 + n * 16 + lr;
      bfr[0][n] = *(const bf16x8*)(pb + (row << 7) + ((lg * 16) ^ xr));
    }
    SCHED_FENCE();
#pragma unroll
    for (int m = 0; m < 4; m++) {
      int row = wm * 64 + m * 16 + lr;
      af[1][m] = *(const bf16x8*)(pa + (row << 7) + ((64 + lg * 16) ^ xr));
    }
#pragma unroll
    for (int n = 0; n < 4; n++) {
      int row = wn * 64 + n * 16 + lr;
      bfr[1][n] = *(const bf16x8*)(pb + (row << 7) + ((64 + lg * 16) ^ xr));
    }
    SCHED_FENCE();
    WAIT_LGKM(8);
    SCHED_FENCE();
#pragma unroll
    for (int m = 0; m < 4; m++)
#pragma unroll
      for (int n = 0; n < 4; n++)
        acc[m][n] = __builtin_amdgcn_mfma_f32_16x16x32_bf16(af[0][m], bfr[0][n],
                                                            acc[m][n], 0, 0, 0);
    WAIT_LGKM(0);
    SCHED_FENCE();
    RAW_BAR();
    if (kt + 2 < nk) stage(cur, kt + 2);
    SCHED_FENCE();
#pragma unroll
    for (int m = 0; m < 4; m++)
#pragma unroll
      for (int n = 0; n < 4; n++)
        acc[m][n] = __builtin_amdgcn_mfma_f32_16x16x32_bf16(af[1][m], bfr[1][n],
                                                            acc[m][n], 0, 0, 0);
  }
#pragma unroll
  for (int n = 0; n < 4; n++) {
    int cg = bn + wn * 64 + n * 16 + lr;
    float bv = bias ? bias[cg] : 0.0f;
#pragma unroll
    for (int m = 0; m < 4; m++) {
#pragma unroll
      for (int rr = 0; rr < 4; rr++) {
        int rg = bm + wm * 64 + m * 16 + lg * 4 + rr;
        float v = (acc[m][n][rr] + bv) * scl;
        if (act == 1) v = gelu_f(v);
        outB[cbase + (long)rg * ldc + cg] = (bf16)v;
      }
    }
  }
}

// ------- split-K GEMM -> bf16 partial slabs --------------------------------
__global__ __launch_bounds__(256) void k_gemmsk(
    const bf16* __restrict__ A, long lda,
    const bf16* __restrict__ Bt, int Kfull,
    bf16* __restrict__ psum, long slab, int Kchunk, int ldc) {
  __shared__ __align__(16) bf16 As[2][128 * 64];
  __shared__ __align__(16) bf16 Bs[2][128 * 64];
  int gx = gridDim.x, gy = gridDim.y;
  int nwg = gx * gy * gridDim.z;
  int flat = (blockIdx.z * gy + blockIdx.y) * gx + blockIdx.x;
  int f2 = xcd_remap(flat, nwg);
  int bxi = f2 % gx; int tmp = f2 / gx;
  int byi = tmp % gy; int z = tmp / gy;
  int bm = byi * 128, bn = bxi * 128;
  int t = threadIdx.x, w = t >> 6, lane = t & 63;
  int wm = w >> 1, wn = w & 1;
  int lr = lane & 15, lg = lane >> 4;
  int srow = lane >> 3;
  int scol = (((lane & 7) * 16) ^ ((lane >> 3) << 4)) >> 1;
  f32x4 acc[4][4] = {};
  int nk = Kchunk >> 6;
  long kstart = (long)z * Kchunk;
  auto stage = [&](int buf, int kt2) {
    long k0 = kstart + (long)kt2 * 64;
#pragma unroll
    for (int i = 0; i < 4; i++) {
      int row = (i * 4 + w) * 8 + srow;
      gload16(A + (long)(bm + row) * lda + k0 + scol, &As[buf][(i * 4 + w) * 512]);
      gload16(Bt + (long)(bn + row) * Kfull + k0 + scol, &Bs[buf][(i * 4 + w) * 512]);
    }
  };
  stage(0, 0);
  if (nk > 1) stage(1, 1);
  for (int kt = 0; kt < nk; ++kt) {
    int cur = kt & 1;
    if (kt + 1 < nk) { WAIT_VM(8); } else { WAIT_VM(0); }
    RAW_BAR();
    SCHED_FENCE();
    const char* pa = (const char*)&As[cur][0];
    const char* pb = (const char*)&Bs[cur][0];
    int xr = (lr & 7) << 4;
    bf16x8 af[2][4], bfr[2][4];
#pragma unroll
    for (int m = 0; m < 4; m++) {
      int row = wm * 64 + m * 16 + lr;
      af[0][m] = *(const bf16x8*)(pa + (row << 7) + ((lg * 16) ^ xr));
    }
#pragma unroll
    for (int n = 0; n < 4; n++) {
      int row = wn * 64 + n * 16 + lr;
      bfr[0][n] = *(const bf16x8*)(pb + (row << 7) + ((lg * 16) ^ xr));
    }
    SCHED_FENCE();
#pragma unroll
    for (int m = 0; m < 4; m++) {
      int row = wm * 64 + m * 16 + lr;
      af[1][m] = *(const bf16x8*)(pa + (row << 7) + ((64 + lg * 16) ^ xr));
    }
#pragma unroll
    for (int n = 0; n < 4; n++) {
      int row = wn * 64 + n * 16 + lr;
      bfr[1][n] = *(const bf16x8*)(pb + (row << 7) + ((64 + lg * 16) ^ xr));
    }
    SCHED_FENCE();
    WAIT_LGKM(8);
    SCHED_FENCE();
#pragma unroll
    for (int m = 0; m < 4; m++)
#pragma unroll
      for (int n = 0; n < 4; n++)
        acc[m][n] = __builtin_amdgcn_mfma_f32_16x16x32_bf16(af[0][m], bfr[0][n],
                                                            acc[m][n], 0, 0, 0);
    WAIT_LGKM(0);
    SCHED_FENCE();
    RAW_BAR();
    if (kt + 2 < nk) stage(cur, kt + 2);
    SCHED_FENCE();
#pragma unroll
    for (int m = 0; m < 4; m++)
#pragma unroll
      for (int n = 0; n < 4; n++)
        acc[m][n] = __builtin_amdgcn_mfma_f32_16x16x32_bf16(af[1][m], bfr[1][n],
                                                            acc[m][n], 0, 0, 0);
  }
  bf16* po = psum + (long)z * slab;
#pragma unroll
  for (int n = 0; n < 4; n++) {
    int cg = bn + wn * 64 + n * 16 + lr;
#pragma unroll
    for (int m = 0; m < 4; m++) {
#pragma unroll
      for (int rr = 0; rr < 4; rr++) {
        int rg = bm + wm * 64 + m * 16 + lg * 4 + rr;
        po[(long)rg * ldc + cg] = (bf16)acc[m][n][rr];
      }
    }
  }
}

// ---------------- flash attention v6 ---------------------------------------
// cross (WINDOWED=0): chunk0-max, ones-MFMA denominator, overflow guard.
// self (WINDOWED=1): R8 defer-max path.
template <int WINDOWED>
__global__ __launch_bounds__(256) void k_flash(const bf16* __restrict__ Qg,
                                               const bf16* __restrict__ Kg,
                                               const bf16* __restrict__ Vtg,
                                               bf16* __restrict__ Og, int nkv) {
  __shared__ __align__(16) bf16 Qs[64 * 64];  // Q tile; after hoist: P buffer
  __shared__ __align__(16) bf16 Ks[2][64 * 64];
  __shared__ __align__(16) bf16 Vs[2][64 * 64];
  int flat = blockIdx.y * 32 + blockIdx.x;
  int flat2 = (flat & 7) * 128 + (flat >> 3);
  int i0 = (flat2 & 31) * 64;
  int bh = flat2 >> 5;
  int b = bh >> 4, h = bh & 15;
  int t = threadIdx.x, w = t >> 6, lane = t & 63;
  int lr = lane & 15, lg = lane >> 4;
  long qoff = ((long)b * Lc + i0) * Dc + h * DHc;
  long koff = ((long)b * nkv) * Dc + h * DHc;
  long vtoff = (long)bh * DHc * nkv;
  int o0 = w * 1024 + (lane << 4), o1 = o0 + 4096;
  int r0 = o0 >> 7, c0 = (o0 & 127) ^ ((r0 & 7) << 4);
  int r1 = o1 >> 7, c1 = (o1 & 127) ^ ((r1 & 7) << 4);
  int d0 = c0 >> 1, d1 = c1 >> 1;
  gload16(Qg + qoff + (long)r0 * Dc + d0, &Qs[w * 512]);
  gload16(Qg + qoff + (long)r1 * Dc + d1, &Qs[2048 + w * 512]);
  int kb0 = WINDOWED ? (i0 >= 64 ? i0 - 64 : 0) : 0;
  int nt = WINDOWED ? ((i0 - kb0) >> 6) + 1 : (nkv >> 6);
  auto stage = [&](int buf, int kbase) {
    gload16(Kg + koff + (long)(kbase + r0) * Dc + d0, &Ks[buf][w * 512]);
    gload16(Kg + koff + (long)(kbase + r1) * Dc + d1, &Ks[buf][2048 + w * 512]);
    gload16(Vtg + vtoff + (long)r0 * nkv + kbase + d0, &Vs[buf][w * 512]);
    gload16(Vtg + vtoff + (long)r1 * nkv + kbase + d1, &Vs[buf][2048 + w * 512]);
  };
  stage(0, kb0);
  WAIT_VM(4);  // Q complete
  RAW_BAR();
  SCHED_FENCE();
  bf16x8 bq[2];
#pragma unroll
  for (int ks = 0; ks < 2; ks++) {
    int rq = w * 16 + lr, cb = ks * 64 + lg * 16;
    bq[ks] = *(const bf16x8*)&Qs[((rq << 7) + (cb ^ ((rq & 7) << 4))) >> 1];
  }
  char* pbase = (char*)&Qs[w * 1024];  // per-wave-private P region
  float mrun = -1e30f, lrun = 0.f;     // windowed path state
  float mx_c = 0.0f;                   // cross path: per-q running max
  f32x4 oa[4] = {};
  f32x4 lacc = {};                     // cross path: denominator acc
  bf16x8 ones;
#pragma unroll
  for (int e = 0; e < 8; e++) ones[e] = (bf16)1.0f;
  float slopeL2 = WINDOWED ? exp2f(-0.5f * (float)(h + 1)) * 1.44269504f : 0.0f;
  int qabs = i0 + w * 16 + lr;
  int xr16 = (lr & 7) << 4;
  for (int tch = 0; tch < nt; tch++) {
    int cur = tch & 1;
    if (tch + 1 < nt) {
      stage(cur ^ 1, kb0 + (tch + 1) * 64);
      WAIT_VM(4);
    } else {
      WAIT_VM(0);
    }
    RAW_BAR();
    SCHED_FENCE();
    int kbase = kb0 + tch * 64;
    f32x4 st[4] = {};
    __builtin_amdgcn_s_setprio(1);
#pragma unroll
    for (int ks = 0; ks < 2; ks++) {
#pragma unroll
      for (int m = 0; m < 4; m++) {
        int rk = m * 16 + lr, cb = ks * 64 + lg * 16;
        bf16x8 ka = *(const bf16x8*)&Ks[cur][((rk << 7) + (cb ^ ((rk & 7) << 4))) >> 1];
        st[m] = __builtin_amdgcn_mfma_f32_16x16x32_bf16(ka, bq[ks], st[m], 0, 0, 0);
      }
    }
    __builtin_amdgcn_s_setprio(0);
    if (WINDOWED) {
      // --------- defer-max online softmax (R8 path) ---------
      float sc[4][4];
#pragma unroll
      for (int m = 0; m < 4; m++)
#pragma unroll
        for (int rr = 0; rr < 4; rr++) {
          float v = st[m][rr];
          int kab = kbase + m * 16 + lg * 4 + rr;
          v += slopeL2 * (float)(kab - qabs);
          bool valid = (kab <= qabs) && (qabs - kab < 64);
          sc[m][rr] = valid ? v : -3.0e38f;
        }
      float pmax = sc[0][0];
#pragma unroll
      for (int m = 0; m < 4; m++)
#pragma unroll
        for (int rr = 0; rr < 4; rr++) pmax = fmaxf(pmax, sc[m][rr]);
      pmax = fmaxf(pmax, __shfl_xor(pmax, 16));
      pmax = fmaxf(pmax, __shfl_xor(pmax, 32));
      float mx = mrun;
      if (!__all(pmax - mrun <= 8.0f)) {
        mx = fmaxf(mrun, pmax);
        float corr = exp2f(mrun - mx);
        mrun = mx;
        lrun *= corr;
        float cq[4];
#pragma unroll
        for (int rr = 0; rr < 4; rr++) cq[rr] = __shfl(corr, lg * 4 + rr);
#pragma unroll
        for (int jd = 0; jd < 4; jd++) {
          oa[jd][0] *= cq[0]; oa[jd][1] *= cq[1];
          oa[jd][2] *= cq[2]; oa[jd][3] *= cq[3];
        }
      }
      float ps = 0.f;
#pragma unroll
      for (int m = 0; m < 4; m++) {
        float p0 = exp2f(sc[m][0] - mx);
        float p1 = exp2f(sc[m][1] - mx);
        float p2 = exp2f(sc[m][2] - mx);
        float p3 = exp2f(sc[m][3] - mx);
        ps += (p0 + p1) + (p2 + p3);
        bf16x4 pw; pw[0] = (bf16)p0; pw[1] = (bf16)p1;
        pw[2] = (bf16)p2; pw[3] = (bf16)p3;
        *(bf16x4*)(pbase + (lr << 7) + ((m * 32 + lg * 8) ^ xr16)) = pw;
      }
      lrun += ps;
      __builtin_amdgcn_s_setprio(1);
#pragma unroll
      for (int ks = 0; ks < 2; ks++) {
        bf16x8 pa = *(const bf16x8*)(pbase + (lr << 7) +
                                     ((ks * 64 + lg * 16) ^ xr16));
#pragma unroll
        for (int jd = 0; jd < 4; jd++) {
          int rv = jd * 16 + lr, cb = ks * 64 + lg * 16;
          bf16x8 vf = *(const bf16x8*)&Vs[cur][((rv << 7) + (cb ^ ((rv & 7) << 4))) >> 1];
          oa[jd] = __builtin_amdgcn_mfma_f32_16x16x32_bf16(pa, vf, oa[jd], 0, 0, 0);
        }
      }
      __builtin_amdgcn_s_setprio(0);
    } else {
      // --------- cross path: chunk0-max + ones-MFMA denominator ---------
      if (tch == 0) {
        float pmax = st[0][0];
#pragma unroll
        for (int m = 0; m < 4; m++)
#pragma unroll
          for (int rr = 0; rr < 4; rr++) pmax = fmaxf(pmax, st[m][rr]);
        pmax = fmaxf(pmax, __shfl_xor(pmax, 16));
        pmax = fmaxf(pmax, __shfl_xor(pmax, 32));
        mx_c = pmax;
      }
#pragma unroll
      for (int m = 0; m < 4; m++) {
        float p0 = exp2f(st[m][0] - mx_c);
        float p1 = exp2f(st[m][1] - mx_c);
        float p2 = exp2f(st[m][2] - mx_c);
        float p3 = exp2f(st[m][3] - mx_c);
        bf16x4 pw; pw[0] = (bf16)p0; pw[1] = (bf16)p1;
        pw[2] = (bf16)p2; pw[3] = (bf16)p3;
        *(bf16x4*)(pbase + (lr << 7) + ((m * 32 + lg * 8) ^ xr16)) = pw;
      }
      __builtin_amdgcn_s_setprio(1);
#pragma unroll
      for (int ks = 0; ks < 2; ks++) {
        bf16x8 pa = *(const bf16x8*)(pbase + (lr << 7) +
                                     ((ks * 64 + lg * 16) ^ xr16));
        lacc = __builtin_amdgcn_mfma_f32_16x16x32_bf16(pa, ones, lacc, 0, 0, 0);
#pragma unroll
        for (int jd = 0; jd < 4; jd++) {
          int rv = jd * 16 + lr, cb = ks * 64 + lg * 16;
          bf16x8 vf = *(const bf16x8*)&Vs[cur][((rv << 7) + (cb ^ ((rv & 7) << 4))) >> 1];
          oa[jd] = __builtin_amdgcn_mfma_f32_16x16x32_bf16(pa, vf, oa[jd], 0, 0, 0);
        }
      }
      __builtin_amdgcn_s_setprio(0);
      // overflow guard (rarely trips): exact power-of-2 rescale
      float lm = fmaxf(fmaxf(lacc[0], lacc[1]), fmaxf(lacc[2], lacc[3]));
      if (!__all(lm < 16777216.0f)) {
        const float cs = 2.3283064365386963e-10f;  // 2^-32
        mx_c += 32.0f;
#pragma unroll
        for (int jd = 0; jd < 4; jd++) {
          oa[jd][0] *= cs; oa[jd][1] *= cs;
          oa[jd][2] *= cs; oa[jd][3] *= cs;
        }
        lacc[0] *= cs; lacc[1] *= cs; lacc[2] *= cs; lacc[3] *= cs;
      }
    }
    WAIT_LGKM(0);
    SCHED_FENCE();
    RAW_BAR();
  }
  if (WINDOWED) {
    float ls = lrun + __shfl_xor(lrun, 16);
    ls += __shfl_xor(ls, 32);
    float inv = 1.0f / ls;
    float iq[4];
#pragma unroll
    for (int rr = 0; rr < 4; rr++) iq[rr] = __shfl(inv, lg * 4 + rr);
#pragma unroll
    for (int rr = 0; rr < 4; rr++) {
      int qo = i0 + w * 16 + lg * 4 + rr;
#pragma unroll
      for (int jd = 0; jd < 4; jd++)
        Og[((long)b * Lc + qo) * Dc + h * DHc + jd * 16 + lr] =
            (bf16)(oa[jd][rr] * iq[rr]);
    }
  } else {
#pragma unroll
    for (int rr = 0; rr < 4; rr++) {
      float inv = 1.0f / lacc[rr];
      int qo = i0 + w * 16 + lg * 4 + rr;
#pragma unroll
      for (int jd = 0; jd < 4; jd++)
        Og[((long)b * Lc + qo) * Dc + h * DHc + jd * 16 + lr] =
            (bf16)(oa[jd][rr] * inv);
    }
  }
}

// ---- fused: sum NS bf16 split-K slabs + bias + residual, then LayerNorm ----
template <int NS>
__global__ __launch_bounds__(256) void k_lnred(const bf16* __restrict__ psum,
                                               long slab,
                                               const float* __restrict__ bias,
                                               const float* __restrict__ addsrc,
                                               const float* __restrict__ g,
                                               const float* __restrict__ bb,
                                               float* __restrict__ outF,
                                               bf16* __restrict__ outB) {
  long row = blockIdx.x;
  int t = threadIdx.x; int lane = t & 63; int wid = t >> 6;
  __shared__ float red[8];
  bf16x4 v0 = *(const bf16x4*)(psum + row * Dc + t * 4);
  float v[4] = {(float)v0[0], (float)v0[1], (float)v0[2], (float)v0[3]};
#pragma unroll
  for (int s = 1; s < NS; s++) {
    bf16x4 u = *(const bf16x4*)(psum + s * slab + row * Dc + t * 4);
    v[0] += (float)u[0]; v[1] += (float)u[1];
    v[2] += (float)u[2]; v[3] += (float)u[3];
  }
  f32x4 bv = *(const f32x4*)(bias + t * 4);
  f32x4 av = *(const f32x4*)(addsrc + row * Dc + t * 4);
  v[0] += bv[0] + av[0]; v[1] += bv[1] + av[1];
  v[2] += bv[2] + av[2]; v[3] += bv[3] + av[3];
  float s = v[0] + v[1] + v[2] + v[3];
  float s2 = v[0] * v[0] + v[1] * v[1] + v[2] * v[2] + v[3] * v[3];
#pragma unroll
  for (int off = 1; off < 64; off <<= 1) {
    s += __shfl_xor(s, off);
    s2 += __shfl_xor(s2, off);
  }
  if (lane == 0) { red[wid] = s; red[4 + wid] = s2; }
  __syncthreads();
  s = red[0] + red[1] + red[2] + red[3];
  s2 = red[4] + red[5] + red[6] + red[7];
  float mu = s * (1.0f / Dc);
  float var = s2 * (1.0f / Dc) - mu * mu;
  float rs = rsqrtf(var + 1e-5f);
#pragma unroll
  for (int e = 0; e < 4; e++) {
    int c = t * 4 + e;
    float y = (v[e] - mu) * rs * g[c] + bb[c];
    if (outF) outF[row * Dc + c] = y;
    if (outB) outB[row * Dc + c] = (bf16)y;
  }
}

extern "C" void kernel_launch(void* const* d_in, const int* in_sizes, int n_in,
                              void* d_out, int out_size, void* d_ws,
                              size_t ws_size, hipStream_t stream) {
  (void)in_sizes; (void)n_in; (void)out_size; (void)ws_size;
  const float* x = (const float*)d_in[0];
  const float* mem = (const float*)d_in[1];
  const float* swq = (const float*)d_in[2];
  const float* swk = (const float*)d_in[3];
  const float* swv = (const float*)d_in[4];
  const float* swo = (const float*)d_in[5];
  const float* sbq = (const float*)d_in[6];
  const float* sbk = (const float*)d_in[7];
  const float* sbv = (const float*)d_in[8];
  const float* sbo = (const float*)d_in[9];
  const float* cwq = (const float*)d_in[10];
  const float* cwk = (const float*)d_in[11];
  const float* cwv = (const float*)d_in[12];
  const float* cwo = (const float*)d_in[13];
  const float* cbq = (const float*)d_in[14];
  const float* cbk = (const float*)d_in[15];
  const float* cbv = (const float*)d_in[16];
  const float* cbo = (const float*)d_in[17];
  const float* w1 = (const float*)d_in[18];
  const float* b1 = (const float*)d_in[19];
  const float* w2 = (const float*)d_in[20];
  const float* b2 = (const float*)d_in[21];
  const float* g1 = (const float*)d_in[22];
  const float* g2 = (const float*)d_in[23];
  const float* g3 = (const float*)d_in[24];
  const float* be1 = (const float*)d_in[25];
  const float* be2 = (const float*)d_in[26];
  const float* be3 = (const float*)d_in[27];
  float* out = (float*)d_out;

  char* ws = (char*)d_ws;
  size_t off = 0;
  auto alloc = [&](size_t bytes) -> char* {
    char* p = ws + off;
    off = (off + bytes + 255) & ~(size_t)255;
    return p;
  };

  const long BL = (long)Bc * Lc;  // 4096
  const long BM = (long)Bc * Mc;  // 4096
  const long DD = (long)Dc * Dc;
  const long SL = BL * Dc;  // one psum slab (elements)
  const float QSCL = 0.125f * 1.44269504f;  // fold 1/sqrt(DH)*log2e into Q

  bf16* wT0 = (bf16*)alloc((size_t)8 * DD * 2);
  bf16* w1T = (bf16*)alloc((size_t)FFc * Dc * 2);
  bf16* w2T = (bf16*)alloc((size_t)Dc * FFc * 2);
  bf16* xb = (bf16*)alloc((size_t)BL * Dc * 2);
  bf16* memb = (bf16*)alloc((size_t)BM * Dc * 2);
  bf16* x1b = (bf16*)alloc((size_t)BL * Dc * 2);
  bf16* x2b = (bf16*)alloc((size_t)BL * Dc * 2);
  bf16* qb = (bf16*)alloc((size_t)BL * Dc * 2);  // qb,kb,vb contiguous
  bf16* kb = (bf16*)alloc((size_t)BM * Dc * 2);
  bf16* vb = (bf16*)alloc((size_t)BM * Dc * 2);
  bf16* ob = (bf16*)alloc((size_t)BL * Dc * 2);
  bf16* vtS = (bf16*)alloc((size_t)Bc * Hc * DHc * Lc * 2);
  bf16* vtC = (bf16*)alloc((size_t)Bc * Hc * DHc * Mc * 2);
  float* x1f = (float*)alloc((size_t)BL * Dc * 4);
  float* x2f = (float*)alloc((size_t)BL * Dc * 4);
  bf16* ffh = (bf16*)alloc((size_t)BL * FFc * 2);
  bf16* psum = (bf16*)alloc((size_t)4 * SL * 2);  // 4 bf16 split-K slabs

  // ---- prep: weights -> bf16 [N,K] (8 DxD batched into one launch)
  Ptrs8 srcs;
  srcs.p[0] = swq; srcs.p[1] = swk; srcs.p[2] = swv; srcs.p[3] = swo;
  srcs.p[4] = cwq; srcs.p[5] = cwk; srcs.p[6] = cwv; srcs.p[7] = cwo;
  k_transpose_w8<<<dim3(Dc / 64, Dc / 64, 8), 256, 0, stream>>>(srcs, wT0);
  k_transpose_w<<<dim3(FFc / 64, Dc / 64), 256, 0, stream>>>(w1, w1T, Dc, FFc);
  k_transpose_w<<<dim3(Dc / 64, FFc / 64), 256, 0, stream>>>(w2, w2T, FFc, Dc);
  k_f2b<<<dim3((unsigned)(BL * Dc / 4 / 256)), 256, 0, stream>>>(x, xb, BL * Dc / 4);
  k_f2b<<<dim3((unsigned)(BM * Dc / 4 / 256)), 256, 0, stream>>>(mem, memb, BM * Dc / 4);

  // ---- self-attn QKV projections (z: q,k,v); Q prescaled
  k_gemm128<<<dim3(Dc / 128, BL / 128, 3), 256, 0, stream>>>(
      xb, xb, xb, Dc, wT0, DD, qb, Dc, SL, sbq, sbk, sbv, Dc, 0, QSCL);
  k_transpose_v<<<dim3(Lc / 64, Bc * Hc), 256, 0, stream>>>(vb, vtS, Lc);
  // ---- windowed causal self-attn + ALiBi
  k_flash<1><<<dim3(Lc / 64, Bc * Hc), 256, 0, stream>>>(qb, kb, vtS, ob, Lc);
  // ---- self O-proj (split-K=2) + fused bias/residual/LN
  k_gemmsk<<<dim3(Dc / 128, BL / 128, 2), 256, 0, stream>>>(
      ob, Dc, wT0 + 3 * DD, Dc, psum, SL, 512, Dc);
  k_lnred<2><<<dim3((unsigned)BL), 256, 0, stream>>>(psum, SL, sbo, x, g1, be1,
                                                     x1f, x1b);

  // ---- cross-attn Q,K,V projections (z: q,k,v); Q prescaled
  k_gemm128<<<dim3(Dc / 128, BM / 128, 3), 256, 0, stream>>>(
      x1b, memb, memb, Dc, wT0 + 4 * DD, DD, qb, Dc, SL, cbq, cbk, cbv, Dc, 0, QSCL);
  k_transpose_v<<<dim3(Mc / 64, Bc * Hc), 256, 0, stream>>>(vb, vtC, Mc);
  // ---- fused flash cross-attention
  k_flash<0><<<dim3(Lc / 64, Bc * Hc), 256, 0, stream>>>(qb, kb, vtC, ob, Mc);
  // ---- cross O-proj (split-K=2) + fused bias/residual/LN
  k_gemmsk<<<dim3(Dc / 128, BL / 128, 2), 256, 0, stream>>>(
      ob, Dc, wT0 + 7 * DD, Dc, psum, SL, 512, Dc);
  k_lnred<2><<<dim3((unsigned)BL), 256, 0, stream>>>(psum, SL, cbo, x1f, g2, be2,
                                                     x2f, x2b);

  // ---- FFN
  k_gemm128<<<dim3(FFc / 128, BL / 128, 1), 256, 0, stream>>>(
      x2b, x2b, x2b, Dc, w1T, 0, ffh, FFc, 0, b1, b1, b1, Dc, 1, 1.0f);
  // FFN2: split-K=4 -> grid 1024
  k_gemmsk<<<dim3(Dc / 128, BL / 128, 4), 256, 0, stream>>>(
      ffh, FFc, w2T, FFc, psum, SL, 1024, Dc);
  k_lnred<4><<<dim3((unsigned)BL), 256, 0, stream>>>(psum, SL, b2, x2f, g3, be3,
                                                     out, nullptr);
}